// Round 4
// baseline (476.774 us; speedup 1.0000x reference)
//
#include <hip/hip_runtime.h>

#define NB   4
#define SXX  4096
#define SLL  256
#define DD   1024
#define HH   16
#define DHH  64
#define SKV  4352      // SX + SL
#define MKV  17408     // NB * SKV
#define NSPLIT 8

typedef __attribute__((ext_vector_type(8))) short bfrag;   // 8 bf16 (4 VGPRs), MFMA A/B frag
typedef __attribute__((ext_vector_type(4))) float facc;    // MFMA 16x16 C/D frag

__device__ __forceinline__ unsigned short f2bf(float f){
  unsigned u = __builtin_bit_cast(unsigned, f);
  u = (u + 0x7fffu + ((u >> 16) & 1u)) >> 16;   // RNE
  return (unsigned short)u;
}
__device__ __forceinline__ float bf2f(unsigned short h){
  unsigned u = ((unsigned)h) << 16;
  return __builtin_bit_cast(float, u);
}

#define GLOAD_LDS16(g, lds) __builtin_amdgcn_global_load_lds( \
    (const __attribute__((address_space(1))) unsigned int*)(const void*)(g), \
    (__attribute__((address_space(3))) unsigned int*)(void*)(lds), 16, 0, 0)

// ---- weights: in[K][N] f32 -> out[N][K] bf16 ; all three in one launch (grid.z)
__global__ void wtrans3(const float* __restrict__ Wq, const float* __restrict__ Wkv,
                        const float* __restrict__ Wo, unsigned short* __restrict__ wqt,
                        unsigned short* __restrict__ wkvt, unsigned short* __restrict__ wot){
  __shared__ float t[32][33];
  int z = blockIdx.z;
  const float* in; unsigned short* out; int N;
  if (z == 0){ in = Wq;  out = wqt;  N = DD;   }
  else if (z == 1){ in = Wkv; out = wkvt; N = 2*DD; }
  else { in = Wo;  out = wot;  N = DD;   }
  int n0 = blockIdx.x * 32, k0 = blockIdx.y * 32;
  if (n0 >= N) return;
  int tx = threadIdx.x, ty = threadIdx.y;
  #pragma unroll
  for (int i = 0; i < 4; i++)
    t[ty + 8*i][tx] = in[(size_t)(k0 + ty + 8*i) * N + n0 + tx];
  __syncthreads();
  #pragma unroll
  for (int i = 0; i < 4; i++)
    out[(size_t)(n0 + ty + 8*i) * DD + k0 + tx] = f2bf(t[tx][ty + 8*i]);
}

// ---- layernorm one row (D=1024) -> bf16 into kvin (+ optional second copy)
__global__ void lnorm(const float* __restrict__ src, const float* __restrict__ g,
                      const float* __restrict__ bt, unsigned short* __restrict__ kvin,
                      unsigned short* __restrict__ dst2, int seq, int off){
  int row = blockIdx.x;
  int b = row / seq, s = row - b*seq;
  int t = threadIdx.x;
  const float4* rp = (const float4*)(src + (size_t)row * DD);
  float4 v = rp[t];
  float sum = v.x + v.y + v.z + v.w;
  float sq  = v.x*v.x + v.y*v.y + v.z*v.z + v.w*v.w;
  #pragma unroll
  for (int o = 32; o > 0; o >>= 1){ sum += __shfl_down(sum, o); sq += __shfl_down(sq, o); }
  __shared__ float ls[8];
  int w = t >> 6, l = t & 63;
  if (l == 0){ ls[w] = sum; ls[4 + w] = sq; }
  __syncthreads();
  sum = ls[0] + ls[1] + ls[2] + ls[3];
  sq  = ls[4] + ls[5] + ls[6] + ls[7];
  float mu  = sum * (1.f/DD);
  float var = sq * (1.f/DD) - mu*mu;
  float rs  = rsqrtf(var + 1e-5f);
  float4 gv = ((const float4*)g)[t];
  float4 bv = ((const float4*)bt)[t];
  ushort4 o4;
  o4.x = f2bf((v.x - mu)*rs*gv.x + bv.x);
  o4.y = f2bf((v.y - mu)*rs*gv.y + bv.y);
  o4.z = f2bf((v.z - mu)*rs*gv.z + bv.z);
  o4.w = f2bf((v.w - mu)*rs*gv.w + bv.w);
  *(ushort4*)(kvin + (size_t)(b*SKV + off + s) * DD + t*4) = o4;
  if (dst2) *(ushort4*)(dst2 + (size_t)row * DD + t*4) = o4;
}

// ---- small GEMM (o projection): 64x64 tile, 4 waves. A[M][K], Bt[N][K] bf16 -> C f32
__global__ __launch_bounds__(256) void gemm64(const unsigned short* __restrict__ A,
    const unsigned short* __restrict__ Bt, int M, int N, int K, float* __restrict__ outF){
  __shared__ unsigned short lA[64][72];
  __shared__ unsigned short lB[64][72];
  int n0 = blockIdx.x * 64, m0 = blockIdx.y * 64;
  int t = threadIdx.x, w = t >> 6, l = t & 63;
  int wr = (w >> 1) * 32, wc = (w & 1) * 32;
  int lr = l & 15, kq = (l >> 4) * 8;
  facc acc00 = (facc)0.f, acc01 = (facc)0.f, acc10 = (facc)0.f, acc11 = (facc)0.f;
  for (int k0 = 0; k0 < K; k0 += 64){
    #pragma unroll
    for (int cc = 0; cc < 2; cc++){
      int ch = t + cc*256;
      int row = ch >> 3, cg = (ch & 7) * 8;
      *(bfrag*)&lA[row][cg] = *(const bfrag*)&A[(size_t)(m0 + row) * K + k0 + cg];
      *(bfrag*)&lB[row][cg] = *(const bfrag*)&Bt[(size_t)(n0 + row) * K + k0 + cg];
    }
    __syncthreads();
    #pragma unroll
    for (int ks = 0; ks < 2; ks++){
      bfrag a0 = *(const bfrag*)&lA[wr + lr][ks*32 + kq];
      bfrag a1 = *(const bfrag*)&lA[wr + 16 + lr][ks*32 + kq];
      bfrag b0 = *(const bfrag*)&lB[wc + lr][ks*32 + kq];
      bfrag b1 = *(const bfrag*)&lB[wc + 16 + lr][ks*32 + kq];
      acc00 = __builtin_amdgcn_mfma_f32_16x16x32_bf16(a0, b0, acc00, 0, 0, 0);
      acc01 = __builtin_amdgcn_mfma_f32_16x16x32_bf16(a0, b1, acc01, 0, 0, 0);
      acc10 = __builtin_amdgcn_mfma_f32_16x16x32_bf16(a1, b0, acc10, 0, 0, 0);
      acc11 = __builtin_amdgcn_mfma_f32_16x16x32_bf16(a1, b1, acc11, 0, 0, 0);
    }
    __syncthreads();
  }
  int rl = (l >> 4) * 4, cl = l & 15;
  facc accs[2][2] = {{acc00, acc01},{acc10, acc11}};
  #pragma unroll
  for (int mt = 0; mt < 2; mt++)
  #pragma unroll
  for (int nt = 0; nt < 2; nt++)
  #pragma unroll
  for (int j = 0; j < 4; j++){
    int r = m0 + wr + mt*16 + rl + j;
    int c = n0 + wc + nt*16 + cl;
    outF[(size_t)r * N + c] = accs[mt][nt][j];
  }
}

// ---- q GEMM with FUSED rmsnorm+gamma^2+1/8 epilogue -> qnb bf16 [B][H][SL][DH]
__global__ __launch_bounds__(256) void gemm_q(const unsigned short* __restrict__ A,
    const unsigned short* __restrict__ Bt, const float* __restrict__ gamma,
    unsigned short* __restrict__ qn){
  __shared__ char smemb[18432];          // lA/lB (2x 64x72 shorts) ; reused as Cf f32[64][66]
  unsigned short* lA = (unsigned short*)smemb;
  unsigned short* lB = lA + 64*72;
  float* Cf = (float*)smemb;             // 64*66*4 = 16896 <= 18432
  int h = blockIdx.x, n0 = h * 64, m0 = blockIdx.y * 64;
  int t = threadIdx.x, w = t >> 6, l = t & 63;
  int wr = (w >> 1) * 32, wc = (w & 1) * 32;
  int lr = l & 15, kq = (l >> 4) * 8;
  facc acc00 = (facc)0.f, acc01 = (facc)0.f, acc10 = (facc)0.f, acc11 = (facc)0.f;
  for (int k0 = 0; k0 < 1024; k0 += 64){
    #pragma unroll
    for (int cc = 0; cc < 2; cc++){
      int ch = t + cc*256;
      int row = ch >> 3, cg = (ch & 7) * 8;
      *(bfrag*)&lA[row*72 + cg] = *(const bfrag*)&A[(size_t)(m0 + row) * 1024 + k0 + cg];
      *(bfrag*)&lB[row*72 + cg] = *(const bfrag*)&Bt[(size_t)(n0 + row) * 1024 + k0 + cg];
    }
    __syncthreads();
    #pragma unroll
    for (int ks = 0; ks < 2; ks++){
      bfrag a0 = *(const bfrag*)&lA[(wr + lr)*72 + ks*32 + kq];
      bfrag a1 = *(const bfrag*)&lA[(wr + 16 + lr)*72 + ks*32 + kq];
      bfrag b0 = *(const bfrag*)&lB[(wc + lr)*72 + ks*32 + kq];
      bfrag b1 = *(const bfrag*)&lB[(wc + 16 + lr)*72 + ks*32 + kq];
      acc00 = __builtin_amdgcn_mfma_f32_16x16x32_bf16(a0, b0, acc00, 0, 0, 0);
      acc01 = __builtin_amdgcn_mfma_f32_16x16x32_bf16(a0, b1, acc01, 0, 0, 0);
      acc10 = __builtin_amdgcn_mfma_f32_16x16x32_bf16(a1, b0, acc10, 0, 0, 0);
      acc11 = __builtin_amdgcn_mfma_f32_16x16x32_bf16(a1, b1, acc11, 0, 0, 0);
    }
    __syncthreads();
  }
  int rl = (l >> 4) * 4, cl = l & 15;
  facc accs[2][2] = {{acc00, acc01},{acc10, acc11}};
  #pragma unroll
  for (int mt = 0; mt < 2; mt++)
  #pragma unroll
  for (int nt = 0; nt < 2; nt++)
  #pragma unroll
  for (int j = 0; j < 4; j++)
    Cf[(wr + mt*16 + rl + j)*66 + wc + nt*16 + cl] = accs[mt][nt][j];
  __syncthreads();
  if (t < 64){
    const float* src = &Cf[t*66];
    float ss = 0.f;
    #pragma unroll
    for (int d = 0; d < 64; d++){ float a = src[d]; ss = fmaf(a, a, ss); }
    float rv = 0.125f / fmaxf(sqrtf(ss) * 0.125f, 1e-8f);
    int r = m0 + t, b = r >> 8, sl = r & 255;
    unsigned short* dst = &qn[((size_t)(b*HH + h)*SLL + sl)*DHH];
    #pragma unroll
    for (int i = 0; i < 8; i++){
      ushort4 p; float g;
      g = gamma[i*8+0]; p.x = f2bf(src[i*8+0]*g*g*rv);
      g = gamma[i*8+1]; p.y = f2bf(src[i*8+1]*g*g*rv);
      g = gamma[i*8+2]; p.z = f2bf(src[i*8+2]*g*g*rv);
      g = gamma[i*8+3]; p.w = f2bf(src[i*8+3]*g*g*rv);
      ushort4 q;
      g = gamma[i*8+4]; q.x = f2bf(src[i*8+4]*g*g*rv);
      g = gamma[i*8+5]; q.y = f2bf(src[i*8+5]*g*g*rv);
      g = gamma[i*8+6]; q.z = f2bf(src[i*8+6]*g*g*rv);
      g = gamma[i*8+7]; q.w = f2bf(src[i*8+7]*g*g*rv);
      *(ushort4*)&dst[i*8]     = p;
      *(ushort4*)&dst[i*8 + 4] = q;
    }
  }
}

// ---- kv GEMM, R13: B DIRECT global->reg (L1/L2-resident weights), A-only LDS ring-3.
// R12 post-mortem: 256x128 with both operands in LDS is LDS-read-bound (128 b128 reads
// ~1540cy > MFMA 1240cy per K-tile per CU) -> util capped ~43%/block. Removing B's 64
// reads (B K-slice = 16KB, L1-resident after first wave; all of B = 4.2MB, L2-resident
// per XCD) makes the tile MFMA-bound. B prefetched 1 K-tile ahead into regs (~1300cy
// lookahead covers HBM 900cy); compiler manages the register-dep waits (no hand lgkm —
// R11 lesson). A keeps ring-3 gload_lds + single barrier + counted vmcnt per tile.
// vmcnt accounting (in-order retirement, m135): per tile issue order = B(j+1) 8 loads,
// A-stage(j+2) 4 loads; at end of tile j, newer-than-A(j+1) = 12 -> vmcnt(12).
__global__ __launch_bounds__(512, 2) void gemm_kv(const unsigned short* __restrict__ A,
    const unsigned short* __restrict__ Bt,
    const float* __restrict__ mask_x, const float* __restrict__ mask_lat,
    unsigned short* __restrict__ outK, unsigned short* __restrict__ outV,
    float* __restrict__ rkm){
  __shared__ alignas(16) unsigned short lds[3 * 16384];  // 98304 B: 3 A-slots (256x64 bf16)
  int bid = blockIdx.x;
  int wg = (bid & 7) * 136 + (bid >> 3);                 // 1088 = 8 * 136: bijective XCD swizzle
  int m0 = (wg >> 4) * 256, n0 = (wg & 15) * 128;
  int t = threadIdx.x, w = t >> 6, l = t & 63;
  int wm = w >> 1, wn = w & 1;                           // 4M x 2N waves, 64x64 out each
  int lr = l & 15, q2 = l >> 4;
  int r8 = l >> 3, u = l & 7;
  int swz = (u ^ (r8 & 7)) * 8;                          // pre-swizzled global source (rule #21)
  const unsigned short* Ag = A + (size_t)(m0 + w*8 + r8) * 1024 + swz;
  // B fragment base: row (n0 + wn*64 + lr), col (q2*8); frag (ks,nt) at +nt*16384+ks*32
  const unsigned short* Bg2 = Bt + (size_t)(n0 + wn*64 + lr) * 1024 + q2*8;

  facc acc[4][4];
  #pragma unroll
  for (int mt = 0; mt < 4; mt++)
  #pragma unroll
  for (int nt = 0; nt < 4; nt++) acc[mt][nt] = (facc)0.f;

#define SBAR __builtin_amdgcn_sched_barrier(0)
#define KV_BARRIER do { SBAR; __builtin_amdgcn_s_barrier(); SBAR; } while(0)
#define KV_STA(j, i) GLOAD_LDS16(Ag + (size_t)(i)*65536 + (j)*64, \
    &lds[((j) % 3)*16384 + (i)*4096 + w*512])
#define KV_LDB(dst, j) { \
    const unsigned short* pB = Bg2 + (size_t)(j)*64; \
    dst[0][0] = *(const bfrag*)(pB);              dst[0][1] = *(const bfrag*)(pB + 16384); \
    dst[0][2] = *(const bfrag*)(pB + 32768);      dst[0][3] = *(const bfrag*)(pB + 49152); \
    dst[1][0] = *(const bfrag*)(pB + 32);         dst[1][1] = *(const bfrag*)(pB + 16384 + 32); \
    dst[1][2] = *(const bfrag*)(pB + 32768 + 32); dst[1][3] = *(const bfrag*)(pB + 49152 + 32); }
#define KV_LDFA(va, j, ks) { \
    const unsigned short* pA = &lds[((j) % 3)*16384 + (wm*64 + lr)*64 + (((ks)*4 + q2) ^ (lr & 7))*8]; \
    va[0] = *(const bfrag*)(pA);        va[1] = *(const bfrag*)(pA + 1024); \
    va[2] = *(const bfrag*)(pA + 2048); va[3] = *(const bfrag*)(pA + 3072); }
#define KV_MFMA(va, vb) do { \
    __builtin_amdgcn_s_setprio(1); \
    _Pragma("unroll") \
    for (int mt = 0; mt < 4; mt++){ \
      _Pragma("unroll") \
      for (int nt = 0; nt < 4; nt++) \
        acc[mt][nt] = __builtin_amdgcn_mfma_f32_16x16x32_bf16(va[mt], vb[nt], acc[mt][nt], 0, 0, 0); } \
    __builtin_amdgcn_s_setprio(0); } while(0)

  bfrag bb[2][2][4];   // [tile parity][ks][nt] — static indexing via full unroll
  bfrag av0[4], av1[4];

  // prologue: stage A tiles 0,1 (4 loads each, in order); then B tile 0 frags (8).
  // vmcnt(12) -> A0's 4 retired (in-order); A1 + B0 stay in flight (B0 reg-dep-waited).
  KV_STA(0,0); KV_STA(0,1); KV_STA(0,2); KV_STA(0,3);
  KV_STA(1,0); KV_STA(1,1); KV_STA(1,2); KV_STA(1,3);
  KV_LDB(bb[0], 0);
  __asm__ volatile("s_waitcnt vmcnt(12)" ::: "memory");
  KV_BARRIER;

  #pragma unroll
  for (int j = 0; j < 16; j++){
    if (j < 15) KV_LDB(bb[(j+1)&1], j+1);                          // B next tile -> regs
    if (j < 14){ KV_STA(j+2,0); KV_STA(j+2,1); KV_STA(j+2,2); KV_STA(j+2,3); }
    KV_LDFA(av0, j, 0);
    KV_LDFA(av1, j, 1);                                            // both issue pre-MFMA (WAR-free)
    KV_MFMA(av0, bb[j&1][0]);
    KV_MFMA(av1, bb[j&1][1]);
    // boundary: A(j+1) guaranteed in LDS (12 newer ops = B(j+1) 8 + A(j+2) 4)
    if (j < 14)       { __asm__ volatile("s_waitcnt vmcnt(12)" ::: "memory"); }
    else if (j == 14) { __asm__ volatile("s_waitcnt vmcnt(8)" ::: "memory"); }
    KV_BARRIER;
  }
#undef KV_STA
#undef KV_LDB
#undef KV_LDFA
#undef KV_MFMA

  // epilogue: tiles never span batches (SKV = 17*256); LDS fully drained & free
  int b = m0 / SKV, s0 = m0 - b*SKV;
  if (n0 < DD){
    // K half: stage [s][c] pitch 136; per-thread one (row,head) 128B line; rkm sentinel
    #pragma unroll
    for (int mt = 0; mt < 4; mt++)
    #pragma unroll
    for (int nt = 0; nt < 4; nt++)
    #pragma unroll
    for (int j = 0; j < 4; j++)
      lds[(wm*64 + mt*16 + q2*4 + j)*136 + wn*64 + nt*16 + lr] = f2bf(acc[mt][nt][j]);
    __syncthreads();
    int s = t >> 1, hf = t & 1;
    int srow = s0 + s;
    float cm = (srow < SXX) ? mask_x[b*SXX + srow] : mask_lat[b*SLL + srow - SXX];
    const unsigned short* src = &lds[s*136 + hf*64];
    uint4 wv[8];
    #pragma unroll
    for (int i = 0; i < 8; i++) wv[i] = *(const uint4*)&src[i*8];
    float ss0 = 0.f, ss1 = 0.f;
    #pragma unroll
    for (int i = 0; i < 8; i++){
      const unsigned short* pp = (const unsigned short*)&wv[i];
      #pragma unroll
      for (int e = 0; e < 4; e++){
        float a = bf2f(pp[e]);     ss0 = fmaf(a, a, ss0);
        float c = bf2f(pp[e + 4]); ss1 = fmaf(c, c, ss1);
      }
    }
    float rv = 1.f / fmaxf(sqrtf(ss0 + ss1) * 0.125f, 1e-8f);
    int h = (n0 >> 6) + hf;
    unsigned short* dst = &outK[((size_t)(b*HH + h)*SKV + srow)*DHH];
    #pragma unroll
    for (int i = 0; i < 8; i++)
      *(uint4*)&dst[i*8] = wv[i];
    rkm[((size_t)(b*HH + h))*SKV + srow] = (cm != 0.f) ? rv : -1.f;
  } else {
    // V half: stage [c][s] pitch 264 (j contiguous -> ushort4 writes), 128B lines to vT
    #pragma unroll
    for (int mt = 0; mt < 4; mt++)
    #pragma unroll
    for (int nt = 0; nt < 4; nt++){
      ushort4 p;
      p.x = f2bf(acc[mt][nt][0]); p.y = f2bf(acc[mt][nt][1]);
      p.z = f2bf(acc[mt][nt][2]); p.w = f2bf(acc[mt][nt][3]);
      *(ushort4*)&lds[(wn*64 + nt*16 + lr)*264 + wm*64 + mt*16 + q2*4] = p;
    }
    __syncthreads();
    int c = t >> 2, sq = t & 3;
    int hh = ((n0 - DD) >> 6) + (c >> 6), d = c & 63;
    const unsigned short* src = &lds[c*264 + sq*64];
    unsigned short* dst = &outV[((size_t)(b*HH + hh)*DHH + d)*SKV + s0 + sq*64];
    #pragma unroll
    for (int i = 0; i < 8; i++)
      *(uint4*)&dst[i*8] = *(const uint4*)&src[i*8];
  }
}

// ---- flash attention, split-KV, 2 q-tiles/block, fixed-max softmax (s in [-8,8]).
// rkm carries the kv-mask sentinel; V fragments issued right after QK MFMAs to overlap.
__global__ __launch_bounds__(256) void attn(const unsigned short* __restrict__ qn,
    const unsigned short* __restrict__ kbuf, const unsigned short* __restrict__ vT,
    const float* __restrict__ rkm, const float* __restrict__ mask_lat,
    float* __restrict__ Opart, float* __restrict__ lpart){
  int qt = blockIdx.x, bh = blockIdx.y, split = blockIdx.z;
  int b = bh >> 4;
  __shared__ unsigned short lP[4][2][16][68];   // per-wave, per-tile P staging
  int t = threadIdx.x, w = t >> 6, l = t & 63;
  int lr = l & 15, q2 = l >> 4, kq = q2 * 8;
  int q0 = qt * 128;
  bfrag aq0[2], aq1[2];
  float rm[2][4];
  #pragma unroll
  for (int tt = 0; tt < 2; tt++){
    const unsigned short* qbase = qn + ((size_t)bh * SLL + q0 + tt*64 + w*16 + lr) * DHH;
    aq0[tt] = *(const bfrag*)&qbase[kq];
    aq1[tt] = *(const bfrag*)&qbase[32 + kq];
    #pragma unroll
    for (int j = 0; j < 4; j++) rm[tt][j] = mask_lat[b*SLL + q0 + tt*64 + w*16 + q2*4 + j];
  }
  facc O[2][4];
  #pragma unroll
  for (int tt = 0; tt < 2; tt++)
  #pragma unroll
  for (int nt = 0; nt < 4; nt++) O[tt][nt] = (facc)0.f;
  float lsum[2][4];
  #pragma unroll
  for (int tt = 0; tt < 2; tt++)
  #pragma unroll
  for (int j = 0; j < 4; j++) lsum[tt][j] = 0.f;

  int t0 = (split * 68) / NSPLIT, t1 = ((split + 1) * 68) / NSPLIT;
  for (int kt = t0; kt < t1; kt++){
    int key0 = kt * 64;
    const unsigned short* kb = kbuf + ((size_t)bh * SKV + key0) * DHH;
    bfrag bk0[4], bk1[4]; float rk[4];
    #pragma unroll
    for (int nt = 0; nt < 4; nt++){
      bk0[nt] = *(const bfrag*)&kb[(nt*16 + lr)*DHH + kq];
      bk1[nt] = *(const bfrag*)&kb[(nt*16 + lr)*DHH + 32 + kq];
      rk[nt]  = rkm[(size_t)bh*SKV + key0 + nt*16 + lr];   // <0 => masked key
    }
    facc S[2][4];
    #pragma unroll
    for (int tt = 0; tt < 2; tt++)
    #pragma unroll
    for (int nt = 0; nt < 4; nt++){
      S[tt][nt] = (facc)0.f;
      S[tt][nt] = __builtin_amdgcn_mfma_f32_16x16x32_bf16(aq0[tt], bk0[nt], S[tt][nt], 0, 0, 0);
      S[tt][nt] = __builtin_amdgcn_mfma_f32_16x16x32_bf16(aq1[tt], bk1[nt], S[tt][nt], 0, 0, 0);
    }
    // V fragments: independent of P -> issue now, consumed after softmax
    const unsigned short* vb = vT + (size_t)bh * DHH * SKV + key0;
    bfrag bv0[4], bv1[4];
    #pragma unroll
    for (int nt = 0; nt < 4; nt++){
      bv0[nt] = *(const bfrag*)&vb[(size_t)(nt*16 + lr)*SKV + kq];
      bv1[nt] = *(const bfrag*)&vb[(size_t)(nt*16 + lr)*SKV + 32 + kq];
    }
    #pragma unroll
    for (int tt = 0; tt < 2; tt++){
      #pragma unroll
      for (int j = 0; j < 4; j++){
        float rs_ = 0.f;
        #pragma unroll
        for (int nt = 0; nt < 4; nt++){
          float x = S[tt][nt][j] * rk[nt];
          float sv = (rk[nt] >= 0.f && rm[tt][j] != 0.f) ? x : -3.0e38f;
          float p = __expf(sv - 8.0f);
          rs_ += p;
          lP[w][tt][q2*4 + j][nt*16 + lr] = f2bf(p);
        }
        lsum[tt][j] += rs_;   // per-lane partial (16-lane reduce deferred)
      }
    }
    __asm__ volatile("s_waitcnt lgkmcnt(0)" ::: "memory");   // wave-private LDS round trip
    bfrag ap0[2], ap1[2];
    #pragma unroll
    for (int tt = 0; tt < 2; tt++){
      ap0[tt] = *(const bfrag*)&lP[w][tt][lr][kq];
      ap1[tt] = *(const bfrag*)&lP[w][tt][lr][32 + kq];
    }
    #pragma unroll
    for (int nt = 0; nt < 4; nt++){
      #pragma unroll
      for (int tt = 0; tt < 2; tt++){
        O[tt][nt] = __builtin_amdgcn_mfma_f32_16x16x32_bf16(ap0[tt], bv0[nt], O[tt][nt], 0, 0, 0);
        O[tt][nt] = __builtin_amdgcn_mfma_f32_16x16x32_bf16(ap1[tt], bv1[nt], O[tt][nt], 0, 0, 0);
      }
    }
  }
  #pragma unroll
  for (int tt = 0; tt < 2; tt++)
  #pragma unroll
  for (int j = 0; j < 4; j++){
    float L = lsum[tt][j];
    L += __shfl_xor(L, 1); L += __shfl_xor(L, 2);
    L += __shfl_xor(L, 4); L += __shfl_xor(L, 8);
    int srow = q0 + tt*64 + w*16 + q2*4 + j;
    size_t obase = (((size_t)split*64 + bh)*SLL + srow)*DHH;
    #pragma unroll
    for (int nt = 0; nt < 4; nt++)
      Opart[obase + nt*16 + lr] = O[tt][nt][j];
    if (lr == 0)
      lpart[((size_t)split*64 + bh)*SLL + srow] = L;
  }
}

// ---- combine partials across splits (fixed-max: plain sums) -> ybuf bf16 [B][SL][D]
__global__ __launch_bounds__(256) void attn_combine(const float* __restrict__ Opart,
    const float* __restrict__ lpart, unsigned short* __restrict__ ybuf){
  int t = threadIdx.x, w = t >> 6, l = t & 63;
  int idx = blockIdx.x * 4 + w;
  int bh = idx >> 8, srow = idx & 255;
  int b = bh >> 4, h = bh & 15;
  float L = 0.f, acc = 0.f;
  #pragma unroll
  for (int s = 0; s < NSPLIT; s++){
    L   += lpart[((size_t)s*64 + bh)*SLL + srow];
    acc += Opart[(((size_t)s*64 + bh)*SLL + srow)*DHH + l];
  }
  ybuf[((size_t)b*SLL + srow)*DD + h*DHH + l] = f2bf(acc / L);
}

extern "C" void kernel_launch(void* const* d_in, const int* in_sizes, int n_in,
                              void* d_out, int out_size, void* d_ws, size_t ws_size,
                              hipStream_t stream) {
  const float* x        = (const float*)d_in[0];
  const float* latents  = (const float*)d_in[1];
  const float* mask_x   = (const float*)d_in[2];
  const float* mask_lat = (const float*)d_in[3];
  const float* ln_x_g   = (const float*)d_in[4];
  const float* ln_x_b   = (const float*)d_in[5];
  const float* ln_l_g   = (const float*)d_in[6];
  const float* ln_l_b   = (const float*)d_in[7];
  const float* Wq       = (const float*)d_in[8];
  const float* Wkv      = (const float*)d_in[9];
  const float* qk_gamma = (const float*)d_in[10];
  const float* Wo       = (const float*)d_in[11];
  float* out = (float*)d_out;

  // ws layout (~127 MB). Opart/lpart ALIAS kvin/lnlat (dead once attn runs).
  char* wsb = (char*)d_ws;
  unsigned short* kvin  = (unsigned short*)(wsb + 0);          // [MKV][D] bf16       35651584
  unsigned short* lnlat = (unsigned short*)(wsb + 35651584);   // [B*SL][D] bf16       2097152
  unsigned short* wqt   = (unsigned short*)(wsb + 37748736);   // [D][D] bf16          2097152
  unsigned short* wkvt  = (unsigned short*)(wsb + 39845888);   // [2D][D] bf16         4194304
  unsigned short* wot   = (unsigned short*)(wsb + 44040192);   // [D][D] bf16          2097152
  unsigned short* qnb   = (unsigned short*)(wsb + 50331648);   // [B][H][SL][DH]       2097152
  unsigned short* kbuf  = (unsigned short*)(wsb + 52428800);   // [B][H][SKV][DH]     35651584
  unsigned short* vT    = (unsigned short*)(wsb + 88080384);   // [B][H][DH][SKV]     35651584
  float*          rkm   = (float*)(wsb + 123731968);           // [B*H*SKV] f32        1114112
  unsigned short* ybuf  = (unsigned short*)(wsb + 124846080);  // [B*SL][D] bf16       2097152
  float*          Opart = (float*)(wsb + 0);                   // [8][64][256][64] f32 33554432 (alias kvin)
  float*          lpart = (float*)(wsb + 35651584);            // [8][64][256] f32      524288 (alias lnlat)

  wtrans3<<<dim3(64, 32, 3), dim3(32, 8), 0, stream>>>(Wq, Wkv, Wo, wqt, wkvt, wot);

  lnorm<<<NB*SXX, 256, 0, stream>>>(x,       ln_x_g, ln_x_b, kvin, nullptr, SXX, 0);
  lnorm<<<NB*SLL, 256, 0, stream>>>(latents, ln_l_g, ln_l_b, kvin, lnlat,   SLL, SXX);

  gemm_q<<<dim3(16, 16), 256, 0, stream>>>(lnlat, wqt, qk_gamma, qnb);
  gemm_kv<<<dim3(1088), 512, 0, stream>>>(kvin, wkvt, mask_x, mask_lat, kbuf, vT, rkm);

  attn<<<dim3(SLL/128, NB*HH, NSPLIT), 256, 0, stream>>>(qnb, kbuf, vT, rkm, mask_lat, Opart, lpart);
  attn_combine<<<(NB*HH*SLL)/4, 256, 0, stream>>>(Opart, lpart, ybuf);

  gemm64<<<dim3(DD/64, (NB*SLL)/64), 256, 0, stream>>>(ybuf, wot, NB*SLL, DD, DD, out);
}

// Round 5
// 354.543 us; speedup vs baseline: 1.3448x; 1.3448x over previous
//
#include <hip/hip_runtime.h>

#define NB   4
#define SXX  4096
#define SLL  256
#define DD   1024
#define HH   16
#define DHH  64
#define SKV  4352      // SX + SL
#define MKV  17408     // NB * SKV
#define NSPLIT 8

typedef __attribute__((ext_vector_type(8))) short bfrag;   // 8 bf16 (4 VGPRs), MFMA A/B frag
typedef __attribute__((ext_vector_type(4))) float facc;    // MFMA 16x16 C/D frag

__device__ __forceinline__ unsigned short f2bf(float f){
  unsigned u = __builtin_bit_cast(unsigned, f);
  u = (u + 0x7fffu + ((u >> 16) & 1u)) >> 16;   // RNE
  return (unsigned short)u;
}
__device__ __forceinline__ float bf2f(unsigned short h){
  unsigned u = ((unsigned)h) << 16;
  return __builtin_bit_cast(float, u);
}

#define GLOAD_LDS16(g, lds) __builtin_amdgcn_global_load_lds( \
    (const __attribute__((address_space(1))) unsigned int*)(const void*)(g), \
    (__attribute__((address_space(3))) unsigned int*)(void*)(lds), 16, 0, 0)

// ---- weights: in[K][N] f32 -> out[N][K] bf16 ; all three in one launch (grid.z)
__global__ void wtrans3(const float* __restrict__ Wq, const float* __restrict__ Wkv,
                        const float* __restrict__ Wo, unsigned short* __restrict__ wqt,
                        unsigned short* __restrict__ wkvt, unsigned short* __restrict__ wot){
  __shared__ float t[32][33];
  int z = blockIdx.z;
  const float* in; unsigned short* out; int N;
  if (z == 0){ in = Wq;  out = wqt;  N = DD;   }
  else if (z == 1){ in = Wkv; out = wkvt; N = 2*DD; }
  else { in = Wo;  out = wot;  N = DD;   }
  int n0 = blockIdx.x * 32, k0 = blockIdx.y * 32;
  if (n0 >= N) return;
  int tx = threadIdx.x, ty = threadIdx.y;
  #pragma unroll
  for (int i = 0; i < 4; i++)
    t[ty + 8*i][tx] = in[(size_t)(k0 + ty + 8*i) * N + n0 + tx];
  __syncthreads();
  #pragma unroll
  for (int i = 0; i < 4; i++)
    out[(size_t)(n0 + ty + 8*i) * DD + k0 + tx] = f2bf(t[tx][ty + 8*i]);
}

// ---- layernorm one row (D=1024) -> bf16 into kvin (+ optional second copy)
__global__ void lnorm(const float* __restrict__ src, const float* __restrict__ g,
                      const float* __restrict__ bt, unsigned short* __restrict__ kvin,
                      unsigned short* __restrict__ dst2, int seq, int off){
  int row = blockIdx.x;
  int b = row / seq, s = row - b*seq;
  int t = threadIdx.x;
  const float4* rp = (const float4*)(src + (size_t)row * DD);
  float4 v = rp[t];
  float sum = v.x + v.y + v.z + v.w;
  float sq  = v.x*v.x + v.y*v.y + v.z*v.z + v.w*v.w;
  #pragma unroll
  for (int o = 32; o > 0; o >>= 1){ sum += __shfl_down(sum, o); sq += __shfl_down(sq, o); }
  __shared__ float ls[8];
  int w = t >> 6, l = t & 63;
  if (l == 0){ ls[w] = sum; ls[4 + w] = sq; }
  __syncthreads();
  sum = ls[0] + ls[1] + ls[2] + ls[3];
  sq  = ls[4] + ls[5] + ls[6] + ls[7];
  float mu  = sum * (1.f/DD);
  float var = sq * (1.f/DD) - mu*mu;
  float rs  = rsqrtf(var + 1e-5f);
  float4 gv = ((const float4*)g)[t];
  float4 bv = ((const float4*)bt)[t];
  ushort4 o4;
  o4.x = f2bf((v.x - mu)*rs*gv.x + bv.x);
  o4.y = f2bf((v.y - mu)*rs*gv.y + bv.y);
  o4.z = f2bf((v.z - mu)*rs*gv.z + bv.z);
  o4.w = f2bf((v.w - mu)*rs*gv.w + bv.w);
  *(ushort4*)(kvin + (size_t)(b*SKV + off + s) * DD + t*4) = o4;
  if (dst2) *(ushort4*)(dst2 + (size_t)row * DD + t*4) = o4;
}

// ---- small GEMM (o projection): 64x64 tile, 4 waves. A[M][K], Bt[N][K] bf16 -> C f32
__global__ __launch_bounds__(256) void gemm64(const unsigned short* __restrict__ A,
    const unsigned short* __restrict__ Bt, int M, int N, int K, float* __restrict__ outF){
  __shared__ unsigned short lA[64][72];
  __shared__ unsigned short lB[64][72];
  int n0 = blockIdx.x * 64, m0 = blockIdx.y * 64;
  int t = threadIdx.x, w = t >> 6, l = t & 63;
  int wr = (w >> 1) * 32, wc = (w & 1) * 32;
  int lr = l & 15, kq = (l >> 4) * 8;
  facc acc00 = (facc)0.f, acc01 = (facc)0.f, acc10 = (facc)0.f, acc11 = (facc)0.f;
  for (int k0 = 0; k0 < K; k0 += 64){
    #pragma unroll
    for (int cc = 0; cc < 2; cc++){
      int ch = t + cc*256;
      int row = ch >> 3, cg = (ch & 7) * 8;
      *(bfrag*)&lA[row][cg] = *(const bfrag*)&A[(size_t)(m0 + row) * K + k0 + cg];
      *(bfrag*)&lB[row][cg] = *(const bfrag*)&Bt[(size_t)(n0 + row) * K + k0 + cg];
    }
    __syncthreads();
    #pragma unroll
    for (int ks = 0; ks < 2; ks++){
      bfrag a0 = *(const bfrag*)&lA[wr + lr][ks*32 + kq];
      bfrag a1 = *(const bfrag*)&lA[wr + 16 + lr][ks*32 + kq];
      bfrag b0 = *(const bfrag*)&lB[wc + lr][ks*32 + kq];
      bfrag b1 = *(const bfrag*)&lB[wc + 16 + lr][ks*32 + kq];
      acc00 = __builtin_amdgcn_mfma_f32_16x16x32_bf16(a0, b0, acc00, 0, 0, 0);
      acc01 = __builtin_amdgcn_mfma_f32_16x16x32_bf16(a0, b1, acc01, 0, 0, 0);
      acc10 = __builtin_amdgcn_mfma_f32_16x16x32_bf16(a1, b0, acc10, 0, 0, 0);
      acc11 = __builtin_amdgcn_mfma_f32_16x16x32_bf16(a1, b1, acc11, 0, 0, 0);
    }
    __syncthreads();
  }
  int rl = (l >> 4) * 4, cl = l & 15;
  facc accs[2][2] = {{acc00, acc01},{acc10, acc11}};
  #pragma unroll
  for (int mt = 0; mt < 2; mt++)
  #pragma unroll
  for (int nt = 0; nt < 2; nt++)
  #pragma unroll
  for (int j = 0; j < 4; j++){
    int r = m0 + wr + mt*16 + rl + j;
    int c = n0 + wc + nt*16 + cl;
    outF[(size_t)r * N + c] = accs[mt][nt][j];
  }
}

// ---- q GEMM with FUSED rmsnorm+gamma^2+1/8 epilogue -> qnb bf16 [B][H][SL][DH]
__global__ __launch_bounds__(256) void gemm_q(const unsigned short* __restrict__ A,
    const unsigned short* __restrict__ Bt, const float* __restrict__ gamma,
    unsigned short* __restrict__ qn){
  __shared__ char smemb[18432];          // lA/lB (2x 64x72 shorts) ; reused as Cf f32[64][66]
  unsigned short* lA = (unsigned short*)smemb;
  unsigned short* lB = lA + 64*72;
  float* Cf = (float*)smemb;             // 64*66*4 = 16896 <= 18432
  int h = blockIdx.x, n0 = h * 64, m0 = blockIdx.y * 64;
  int t = threadIdx.x, w = t >> 6, l = t & 63;
  int wr = (w >> 1) * 32, wc = (w & 1) * 32;
  int lr = l & 15, kq = (l >> 4) * 8;
  facc acc00 = (facc)0.f, acc01 = (facc)0.f, acc10 = (facc)0.f, acc11 = (facc)0.f;
  for (int k0 = 0; k0 < 1024; k0 += 64){
    #pragma unroll
    for (int cc = 0; cc < 2; cc++){
      int ch = t + cc*256;
      int row = ch >> 3, cg = (ch & 7) * 8;
      *(bfrag*)&lA[row*72 + cg] = *(const bfrag*)&A[(size_t)(m0 + row) * 1024 + k0 + cg];
      *(bfrag*)&lB[row*72 + cg] = *(const bfrag*)&Bt[(size_t)(n0 + row) * 1024 + k0 + cg];
    }
    __syncthreads();
    #pragma unroll
    for (int ks = 0; ks < 2; ks++){
      bfrag a0 = *(const bfrag*)&lA[(wr + lr)*72 + ks*32 + kq];
      bfrag a1 = *(const bfrag*)&lA[(wr + 16 + lr)*72 + ks*32 + kq];
      bfrag b0 = *(const bfrag*)&lB[(wc + lr)*72 + ks*32 + kq];
      bfrag b1 = *(const bfrag*)&lB[(wc + 16 + lr)*72 + ks*32 + kq];
      acc00 = __builtin_amdgcn_mfma_f32_16x16x32_bf16(a0, b0, acc00, 0, 0, 0);
      acc01 = __builtin_amdgcn_mfma_f32_16x16x32_bf16(a0, b1, acc01, 0, 0, 0);
      acc10 = __builtin_amdgcn_mfma_f32_16x16x32_bf16(a1, b0, acc10, 0, 0, 0);
      acc11 = __builtin_amdgcn_mfma_f32_16x16x32_bf16(a1, b1, acc11, 0, 0, 0);
    }
    __syncthreads();
  }
  int rl = (l >> 4) * 4, cl = l & 15;
  facc accs[2][2] = {{acc00, acc01},{acc10, acc11}};
  #pragma unroll
  for (int mt = 0; mt < 2; mt++)
  #pragma unroll
  for (int nt = 0; nt < 2; nt++)
  #pragma unroll
  for (int j = 0; j < 4; j++)
    Cf[(wr + mt*16 + rl + j)*66 + wc + nt*16 + cl] = accs[mt][nt][j];
  __syncthreads();
  if (t < 64){
    const float* src = &Cf[t*66];
    float ss = 0.f;
    #pragma unroll
    for (int d = 0; d < 64; d++){ float a = src[d]; ss = fmaf(a, a, ss); }
    float rv = 0.125f / fmaxf(sqrtf(ss) * 0.125f, 1e-8f);
    int r = m0 + t, b = r >> 8, sl = r & 255;
    unsigned short* dst = &qn[((size_t)(b*HH + h)*SLL + sl)*DHH];
    #pragma unroll
    for (int i = 0; i < 8; i++){
      ushort4 p; float g;
      g = gamma[i*8+0]; p.x = f2bf(src[i*8+0]*g*g*rv);
      g = gamma[i*8+1]; p.y = f2bf(src[i*8+1]*g*g*rv);
      g = gamma[i*8+2]; p.z = f2bf(src[i*8+2]*g*g*rv);
      g = gamma[i*8+3]; p.w = f2bf(src[i*8+3]*g*g*rv);
      ushort4 q;
      g = gamma[i*8+4]; q.x = f2bf(src[i*8+4]*g*g*rv);
      g = gamma[i*8+5]; q.y = f2bf(src[i*8+5]*g*g*rv);
      g = gamma[i*8+6]; q.z = f2bf(src[i*8+6]*g*g*rv);
      g = gamma[i*8+7]; q.w = f2bf(src[i*8+7]*g*g*rv);
      *(ushort4*)&dst[i*8]     = p;
      *(ushort4*)&dst[i*8 + 4] = q;
    }
  }
}

// ---- kv GEMM, R12 (proven 97us): 256x128 tile, ring-of-3 LDS, ONE barrier + ONE
// counted vmcnt per K-tile. Wave-skew inside the barrier interval overlaps LDS reads
// of one wave with MFMAs of another; compiler emits its own fine-grained lgkmcnt.
// R13 (B global->reg) regressed 2.2x: 16-cache-line fragment loads choke the TA and
// serialize with A-staging DMA in the vmcnt queue. Reverted verbatim.
__global__ __launch_bounds__(512, 2) void gemm_kv(const unsigned short* __restrict__ A,
    const unsigned short* __restrict__ Bt,
    const float* __restrict__ mask_x, const float* __restrict__ mask_lat,
    unsigned short* __restrict__ outK, unsigned short* __restrict__ outV,
    float* __restrict__ rkm){
  __shared__ alignas(16) unsigned short lds[3 * 24576];  // 147456 B: 3 slots (A 16384 + B 8192 shorts)
  int bid = blockIdx.x;
  int wg = (bid & 7) * 136 + (bid >> 3);                 // 1088 = 8 * 136: bijective XCD swizzle
  int m0 = (wg >> 4) * 256, n0 = (wg & 15) * 128;
  int t = threadIdx.x, w = t >> 6, l = t & 63;
  int wm = w >> 1, wn = w & 1;                           // 4M x 2N waves, 64x64 out each
  int lr = l & 15, q2 = l >> 4;
  int r8 = l >> 3, u = l & 7;
  int swz = (u ^ (r8 & 7)) * 8;                          // pre-swizzled global source (rule #21)
  const unsigned short* Ag = A  + (size_t)(m0 + w*8 + r8) * 1024 + swz;
  const unsigned short* Bg = Bt + (size_t)(n0 + w*8 + r8) * 1024 + swz;

  facc acc[4][4];
  #pragma unroll
  for (int mt = 0; mt < 4; mt++)
  #pragma unroll
  for (int nt = 0; nt < 4; nt++) acc[mt][nt] = (facc)0.f;

#define SBAR __builtin_amdgcn_sched_barrier(0)
#define KV_BARRIER do { SBAR; __builtin_amdgcn_s_barrier(); SBAR; } while(0)
#define KV_STA(j, i) GLOAD_LDS16(Ag + (size_t)(i)*65536 + (j)*64, \
    &lds[((j) % 3)*24576 + (i)*4096 + w*512])
#define KV_STB(j, i) GLOAD_LDS16(Bg + (size_t)(i)*65536 + (j)*64, \
    &lds[((j) % 3)*24576 + 16384 + (i)*4096 + w*512])
#define KV_LDF(va, vb, j, ks) { \
    const unsigned short* pA = &lds[((j) % 3)*24576 + (wm*64 + lr)*64 + (((ks)*4 + q2) ^ (lr & 7))*8]; \
    const unsigned short* pB = &lds[((j) % 3)*24576 + 16384 + (wn*64 + lr)*64 + (((ks)*4 + q2) ^ (lr & 7))*8]; \
    va[0] = *(const bfrag*)(pA);        va[1] = *(const bfrag*)(pA + 1024); \
    va[2] = *(const bfrag*)(pA + 2048); va[3] = *(const bfrag*)(pA + 3072); \
    vb[0] = *(const bfrag*)(pB);        vb[1] = *(const bfrag*)(pB + 1024); \
    vb[2] = *(const bfrag*)(pB + 2048); vb[3] = *(const bfrag*)(pB + 3072); }
#define KV_MFMA(va, vb) do { \
    __builtin_amdgcn_s_setprio(1); \
    _Pragma("unroll") \
    for (int mt = 0; mt < 4; mt++){ \
      _Pragma("unroll") \
      for (int nt = 0; nt < 4; nt++) \
        acc[mt][nt] = __builtin_amdgcn_mfma_f32_16x16x32_bf16(va[mt], vb[nt], acc[mt][nt], 0, 0, 0); } \
    __builtin_amdgcn_s_setprio(0); } while(0)

  // prologue: stage tiles 0,1 (6 loads each); wait tile 0, keep tile 1 in flight
  KV_STA(0,0); KV_STA(0,1); KV_STA(0,2); KV_STA(0,3); KV_STB(0,0); KV_STB(0,1);
  KV_STA(1,0); KV_STA(1,1); KV_STA(1,2); KV_STA(1,3); KV_STB(1,0); KV_STB(1,1);
  __asm__ volatile("s_waitcnt vmcnt(6)" ::: "memory");
  KV_BARRIER;

  bfrag av[4], bv[4];
  #pragma unroll
  for (int j = 0; j < 16; j++){
    // half 1: ks=0 fragments + first half of tile j+2 staging + MFMA cluster
    KV_LDF(av, bv, j, 0);
    if (j < 14){ KV_STA(j+2, 0); KV_STA(j+2, 1); KV_STB(j+2, 0); }
    KV_MFMA(av, bv);
    // half 2: ks=1 fragments + second half of tile j+2 staging + MFMA cluster
    KV_LDF(av, bv, j, 1);
    if (j < 14){ KV_STA(j+2, 2); KV_STA(j+2, 3); KV_STB(j+2, 1); }
    KV_MFMA(av, bv);
    // single boundary: tile j+1 guaranteed in LDS (6 in flight = tile j+2's)
    if (j < 14)       { __asm__ volatile("s_waitcnt vmcnt(6)" ::: "memory"); }
    else if (j == 14) { __asm__ volatile("s_waitcnt vmcnt(0)" ::: "memory"); }
    KV_BARRIER;
  }
#undef KV_STA
#undef KV_STB
#undef KV_LDF
#undef KV_MFMA

  // epilogue: tiles never span batches (SKV = 17*256); LDS fully drained & free
  int b = m0 / SKV, s0 = m0 - b*SKV;
  if (n0 < DD){
    // K half: stage [s][c] pitch 136; per-thread one (row,head) 128B line; rkm sentinel
    #pragma unroll
    for (int mt = 0; mt < 4; mt++)
    #pragma unroll
    for (int nt = 0; nt < 4; nt++)
    #pragma unroll
    for (int j = 0; j < 4; j++)
      lds[(wm*64 + mt*16 + q2*4 + j)*136 + wn*64 + nt*16 + lr] = f2bf(acc[mt][nt][j]);
    __syncthreads();
    int s = t >> 1, hf = t & 1;
    int srow = s0 + s;
    float cm = (srow < SXX) ? mask_x[b*SXX + srow] : mask_lat[b*SLL + srow - SXX];
    const unsigned short* src = &lds[s*136 + hf*64];
    uint4 wv[8];
    #pragma unroll
    for (int i = 0; i < 8; i++) wv[i] = *(const uint4*)&src[i*8];
    float ss0 = 0.f, ss1 = 0.f;
    #pragma unroll
    for (int i = 0; i < 8; i++){
      const unsigned short* pp = (const unsigned short*)&wv[i];
      #pragma unroll
      for (int e = 0; e < 4; e++){
        float a = bf2f(pp[e]);     ss0 = fmaf(a, a, ss0);
        float c = bf2f(pp[e + 4]); ss1 = fmaf(c, c, ss1);
      }
    }
    float rv = 1.f / fmaxf(sqrtf(ss0 + ss1) * 0.125f, 1e-8f);
    int h = (n0 >> 6) + hf;
    unsigned short* dst = &outK[((size_t)(b*HH + h)*SKV + srow)*DHH];
    #pragma unroll
    for (int i = 0; i < 8; i++)
      *(uint4*)&dst[i*8] = wv[i];
    rkm[((size_t)(b*HH + h))*SKV + srow] = (cm != 0.f) ? rv : -1.f;
  } else {
    // V half: stage [c][s] pitch 264 (j contiguous -> ushort4 writes), 128B lines to vT
    #pragma unroll
    for (int mt = 0; mt < 4; mt++)
    #pragma unroll
    for (int nt = 0; nt < 4; nt++){
      ushort4 p;
      p.x = f2bf(acc[mt][nt][0]); p.y = f2bf(acc[mt][nt][1]);
      p.z = f2bf(acc[mt][nt][2]); p.w = f2bf(acc[mt][nt][3]);
      *(ushort4*)&lds[(wn*64 + nt*16 + lr)*264 + wm*64 + mt*16 + q2*4] = p;
    }
    __syncthreads();
    int c = t >> 2, sq = t & 3;
    int hh = ((n0 - DD) >> 6) + (c >> 6), d = c & 63;
    const unsigned short* src = &lds[c*264 + sq*64];
    unsigned short* dst = &outV[((size_t)(b*HH + hh)*DHH + d)*SKV + s0 + sq*64];
    #pragma unroll
    for (int i = 0; i < 8; i++)
      *(uint4*)&dst[i*8] = *(const uint4*)&src[i*8];
  }
}

// ---- flash attention, R14: FUSED q-tiles — one block covers all SL=256 q-rows
// (tt=0..3 sub-tiles of 64), so each K/V slice is fetched ONCE instead of twice
// (KV traffic 142MB -> 71MB). S computed per-tt sequentially to cap VGPR (~250).
// split-KV over NSPLIT=8; fixed-max softmax (s in [-8,8]); rkm mask sentinel.
__global__ __launch_bounds__(256) void attn(const unsigned short* __restrict__ qn,
    const unsigned short* __restrict__ kbuf, const unsigned short* __restrict__ vT,
    const float* __restrict__ rkm, const float* __restrict__ mask_lat,
    float* __restrict__ Opart, float* __restrict__ lpart){
  int bh = blockIdx.y, split = blockIdx.z;
  int b = bh >> 4;
  __shared__ unsigned short lP[4][4][16][68];   // per-wave, per-tt P staging (34816 B)
  int t = threadIdx.x, w = t >> 6, l = t & 63;
  int lr = l & 15, q2 = l >> 4, kq = q2 * 8;
  bfrag aq0[4], aq1[4];
  float rm[4][4];
  #pragma unroll
  for (int tt = 0; tt < 4; tt++){
    const unsigned short* qbase = qn + ((size_t)bh * SLL + tt*64 + w*16 + lr) * DHH;
    aq0[tt] = *(const bfrag*)&qbase[kq];
    aq1[tt] = *(const bfrag*)&qbase[32 + kq];
    #pragma unroll
    for (int j = 0; j < 4; j++) rm[tt][j] = mask_lat[b*SLL + tt*64 + w*16 + q2*4 + j];
  }
  facc O[4][4];
  #pragma unroll
  for (int tt = 0; tt < 4; tt++)
  #pragma unroll
  for (int nt = 0; nt < 4; nt++) O[tt][nt] = (facc)0.f;
  float lsum[4][4];
  #pragma unroll
  for (int tt = 0; tt < 4; tt++)
  #pragma unroll
  for (int j = 0; j < 4; j++) lsum[tt][j] = 0.f;

  int t0 = (split * 68) / NSPLIT, t1 = ((split + 1) * 68) / NSPLIT;
  for (int kt = t0; kt < t1; kt++){
    int key0 = kt * 64;
    const unsigned short* kb = kbuf + ((size_t)bh * SKV + key0) * DHH;
    bfrag bk0[4], bk1[4]; float rk[4];
    #pragma unroll
    for (int nt = 0; nt < 4; nt++){
      bk0[nt] = *(const bfrag*)&kb[(nt*16 + lr)*DHH + kq];
      bk1[nt] = *(const bfrag*)&kb[(nt*16 + lr)*DHH + 32 + kq];
      rk[nt]  = rkm[(size_t)bh*SKV + key0 + nt*16 + lr];   // <0 => masked key
    }
    // V fragments: independent of P -> issue now, consumed after softmax
    const unsigned short* vb = vT + (size_t)bh * DHH * SKV + key0;
    bfrag bv0[4], bv1[4];
    #pragma unroll
    for (int nt = 0; nt < 4; nt++){
      bv0[nt] = *(const bfrag*)&vb[(size_t)(nt*16 + lr)*SKV + kq];
      bv1[nt] = *(const bfrag*)&vb[(size_t)(nt*16 + lr)*SKV + 32 + kq];
    }
    // per-tt: QK MFMAs -> softmax -> stage P (sequential tt keeps VGPR peak low)
    #pragma unroll
    for (int tt = 0; tt < 4; tt++){
      facc S[4];
      #pragma unroll
      for (int nt = 0; nt < 4; nt++){
        S[nt] = (facc)0.f;
        S[nt] = __builtin_amdgcn_mfma_f32_16x16x32_bf16(aq0[tt], bk0[nt], S[nt], 0, 0, 0);
        S[nt] = __builtin_amdgcn_mfma_f32_16x16x32_bf16(aq1[tt], bk1[nt], S[nt], 0, 0, 0);
      }
      #pragma unroll
      for (int j = 0; j < 4; j++){
        float rs_ = 0.f;
        #pragma unroll
        for (int nt = 0; nt < 4; nt++){
          float x = S[nt][j] * rk[nt];
          float sv = (rk[nt] >= 0.f && rm[tt][j] != 0.f) ? x : -3.0e38f;
          float p = __expf(sv - 8.0f);
          rs_ += p;
          lP[w][tt][q2*4 + j][nt*16 + lr] = f2bf(p);
        }
        lsum[tt][j] += rs_;   // per-lane partial (16-lane reduce deferred)
      }
    }
    __asm__ volatile("s_waitcnt lgkmcnt(0)" ::: "memory");   // wave-private LDS round trip
    #pragma unroll
    for (int tt = 0; tt < 4; tt++){
      bfrag ap0 = *(const bfrag*)&lP[w][tt][lr][kq];
      bfrag ap1 = *(const bfrag*)&lP[w][tt][lr][32 + kq];
      #pragma unroll
      for (int nt = 0; nt < 4; nt++){
        O[tt][nt] = __builtin_amdgcn_mfma_f32_16x16x32_bf16(ap0, bv0[nt], O[tt][nt], 0, 0, 0);
        O[tt][nt] = __builtin_amdgcn_mfma_f32_16x16x32_bf16(ap1, bv1[nt], O[tt][nt], 0, 0, 0);
      }
    }
  }
  #pragma unroll
  for (int tt = 0; tt < 4; tt++)
  #pragma unroll
  for (int j = 0; j < 4; j++){
    float L = lsum[tt][j];
    L += __shfl_xor(L, 1); L += __shfl_xor(L, 2);
    L += __shfl_xor(L, 4); L += __shfl_xor(L, 8);
    int srow = tt*64 + w*16 + q2*4 + j;
    size_t obase = (((size_t)split*64 + bh)*SLL + srow)*DHH;
    #pragma unroll
    for (int nt = 0; nt < 4; nt++)
      Opart[obase + nt*16 + lr] = O[tt][nt][j];
    if (lr == 0)
      lpart[((size_t)split*64 + bh)*SLL + srow] = L;
  }
}

// ---- combine partials across splits (fixed-max: plain sums) -> ybuf bf16 [B][SL][D]
__global__ __launch_bounds__(256) void attn_combine(const float* __restrict__ Opart,
    const float* __restrict__ lpart, unsigned short* __restrict__ ybuf){
  int t = threadIdx.x, w = t >> 6, l = t & 63;
  int idx = blockIdx.x * 4 + w;
  int bh = idx >> 8, srow = idx & 255;
  int b = bh >> 4, h = bh & 15;
  float L = 0.f, acc = 0.f;
  #pragma unroll
  for (int s = 0; s < NSPLIT; s++){
    L   += lpart[((size_t)s*64 + bh)*SLL + srow];
    acc += Opart[(((size_t)s*64 + bh)*SLL + srow)*DHH + l];
  }
  ybuf[((size_t)b*SLL + srow)*DD + h*DHH + l] = f2bf(acc / L);
}

extern "C" void kernel_launch(void* const* d_in, const int* in_sizes, int n_in,
                              void* d_out, int out_size, void* d_ws, size_t ws_size,
                              hipStream_t stream) {
  const float* x        = (const float*)d_in[0];
  const float* latents  = (const float*)d_in[1];
  const float* mask_x   = (const float*)d_in[2];
  const float* mask_lat = (const float*)d_in[3];
  const float* ln_x_g   = (const float*)d_in[4];
  const float* ln_x_b   = (const float*)d_in[5];
  const float* ln_l_g   = (const float*)d_in[6];
  const float* ln_l_b   = (const float*)d_in[7];
  const float* Wq       = (const float*)d_in[8];
  const float* Wkv      = (const float*)d_in[9];
  const float* qk_gamma = (const float*)d_in[10];
  const float* Wo       = (const float*)d_in[11];
  float* out = (float*)d_out;

  // ws layout (~127 MB). Opart/lpart ALIAS kvin/lnlat (dead once attn runs).
  char* wsb = (char*)d_ws;
  unsigned short* kvin  = (unsigned short*)(wsb + 0);          // [MKV][D] bf16       35651584
  unsigned short* lnlat = (unsigned short*)(wsb + 35651584);   // [B*SL][D] bf16       2097152
  unsigned short* wqt   = (unsigned short*)(wsb + 37748736);   // [D][D] bf16          2097152
  unsigned short* wkvt  = (unsigned short*)(wsb + 39845888);   // [2D][D] bf16         4194304
  unsigned short* wot   = (unsigned short*)(wsb + 44040192);   // [D][D] bf16          2097152
  unsigned short* qnb   = (unsigned short*)(wsb + 50331648);   // [B][H][SL][DH]       2097152
  unsigned short* kbuf  = (unsigned short*)(wsb + 52428800);   // [B][H][SKV][DH]     35651584
  unsigned short* vT    = (unsigned short*)(wsb + 88080384);   // [B][H][DH][SKV]     35651584
  float*          rkm   = (float*)(wsb + 123731968);           // [B*H*SKV] f32        1114112
  unsigned short* ybuf  = (unsigned short*)(wsb + 124846080);  // [B*SL][D] bf16       2097152
  float*          Opart = (float*)(wsb + 0);                   // [8][64][256][64] f32 33554432 (alias kvin)
  float*          lpart = (float*)(wsb + 35651584);            // [8][64][256] f32      524288 (alias lnlat)

  wtrans3<<<dim3(64, 32, 3), dim3(32, 8), 0, stream>>>(Wq, Wkv, Wo, wqt, wkvt, wot);

  lnorm<<<NB*SXX, 256, 0, stream>>>(x,       ln_x_g, ln_x_b, kvin, nullptr, SXX, 0);
  lnorm<<<NB*SLL, 256, 0, stream>>>(latents, ln_l_g, ln_l_b, kvin, lnlat,   SLL, SXX);

  gemm_q<<<dim3(16, 16), 256, 0, stream>>>(lnlat, wqt, qk_gamma, qnb);
  gemm_kv<<<dim3(1088), 512, 0, stream>>>(kvin, wkvt, mask_x, mask_lat, kbuf, vT, rkm);

  attn<<<dim3(1, NB*HH, NSPLIT), 256, 0, stream>>>(qnb, kbuf, vT, rkm, mask_lat, Opart, lpart);
  attn_combine<<<(NB*HH*SLL)/4, 256, 0, stream>>>(Opart, lpart, ybuf);

  gemm64<<<dim3(DD/64, (NB*SLL)/64), 256, 0, stream>>>(ybuf, wot, NB*SLL, DD, DD, out);
}

// Round 6
// 352.340 us; speedup vs baseline: 1.3532x; 1.0063x over previous
//
#include <hip/hip_runtime.h>

#define NB   4
#define SXX  4096
#define SLL  256
#define DD   1024
#define HH   16
#define DHH  64
#define SKV  4352      // SX + SL
#define MKV  17408     // NB * SKV
#define NSPLIT 8

typedef __attribute__((ext_vector_type(8))) short bfrag;   // 8 bf16 (4 VGPRs), MFMA A/B frag
typedef __attribute__((ext_vector_type(4))) float facc;    // MFMA 16x16 C/D frag

__device__ __forceinline__ unsigned short f2bf(float f){
  unsigned u = __builtin_bit_cast(unsigned, f);
  u = (u + 0x7fffu + ((u >> 16) & 1u)) >> 16;   // RNE
  return (unsigned short)u;
}
__device__ __forceinline__ float bf2f(unsigned short h){
  unsigned u = ((unsigned)h) << 16;
  return __builtin_bit_cast(float, u);
}

#define GLOAD_LDS16(g, lds) __builtin_amdgcn_global_load_lds( \
    (const __attribute__((address_space(1))) unsigned int*)(const void*)(g), \
    (__attribute__((address_space(3))) unsigned int*)(void*)(lds), 16, 0, 0)

// ---- weights: in[K][N] f32 -> out[N][K] bf16 ; all three in one launch (grid.z)
__global__ void wtrans3(const float* __restrict__ Wq, const float* __restrict__ Wkv,
                        const float* __restrict__ Wo, unsigned short* __restrict__ wqt,
                        unsigned short* __restrict__ wkvt, unsigned short* __restrict__ wot){
  __shared__ float t[32][33];
  int z = blockIdx.z;
  const float* in; unsigned short* out; int N;
  if (z == 0){ in = Wq;  out = wqt;  N = DD;   }
  else if (z == 1){ in = Wkv; out = wkvt; N = 2*DD; }
  else { in = Wo;  out = wot;  N = DD;   }
  int n0 = blockIdx.x * 32, k0 = blockIdx.y * 32;
  if (n0 >= N) return;
  int tx = threadIdx.x, ty = threadIdx.y;
  #pragma unroll
  for (int i = 0; i < 4; i++)
    t[ty + 8*i][tx] = in[(size_t)(k0 + ty + 8*i) * N + n0 + tx];
  __syncthreads();
  #pragma unroll
  for (int i = 0; i < 4; i++)
    out[(size_t)(n0 + ty + 8*i) * DD + k0 + tx] = f2bf(t[tx][ty + 8*i]);
}

// ---- layernorm one row (D=1024) -> bf16 into kvin (+ optional second copy)
__global__ void lnorm(const float* __restrict__ src, const float* __restrict__ g,
                      const float* __restrict__ bt, unsigned short* __restrict__ kvin,
                      unsigned short* __restrict__ dst2, int seq, int off){
  int row = blockIdx.x;
  int b = row / seq, s = row - b*seq;
  int t = threadIdx.x;
  const float4* rp = (const float4*)(src + (size_t)row * DD);
  float4 v = rp[t];
  float sum = v.x + v.y + v.z + v.w;
  float sq  = v.x*v.x + v.y*v.y + v.z*v.z + v.w*v.w;
  #pragma unroll
  for (int o = 32; o > 0; o >>= 1){ sum += __shfl_down(sum, o); sq += __shfl_down(sq, o); }
  __shared__ float ls[8];
  int w = t >> 6, l = t & 63;
  if (l == 0){ ls[w] = sum; ls[4 + w] = sq; }
  __syncthreads();
  sum = ls[0] + ls[1] + ls[2] + ls[3];
  sq  = ls[4] + ls[5] + ls[6] + ls[7];
  float mu  = sum * (1.f/DD);
  float var = sq * (1.f/DD) - mu*mu;
  float rs  = rsqrtf(var + 1e-5f);
  float4 gv = ((const float4*)g)[t];
  float4 bv = ((const float4*)bt)[t];
  ushort4 o4;
  o4.x = f2bf((v.x - mu)*rs*gv.x + bv.x);
  o4.y = f2bf((v.y - mu)*rs*gv.y + bv.y);
  o4.z = f2bf((v.z - mu)*rs*gv.z + bv.z);
  o4.w = f2bf((v.w - mu)*rs*gv.w + bv.w);
  *(ushort4*)(kvin + (size_t)(b*SKV + off + s) * DD + t*4) = o4;
  if (dst2) *(ushort4*)(dst2 + (size_t)row * DD + t*4) = o4;
}

// ---- small GEMM (o projection): 64x64 tile, 4 waves. A[M][K], Bt[N][K] bf16 -> C f32
__global__ __launch_bounds__(256) void gemm64(const unsigned short* __restrict__ A,
    const unsigned short* __restrict__ Bt, int M, int N, int K, float* __restrict__ outF){
  __shared__ unsigned short lA[64][72];
  __shared__ unsigned short lB[64][72];
  int n0 = blockIdx.x * 64, m0 = blockIdx.y * 64;
  int t = threadIdx.x, w = t >> 6, l = t & 63;
  int wr = (w >> 1) * 32, wc = (w & 1) * 32;
  int lr = l & 15, kq = (l >> 4) * 8;
  facc acc00 = (facc)0.f, acc01 = (facc)0.f, acc10 = (facc)0.f, acc11 = (facc)0.f;
  for (int k0 = 0; k0 < K; k0 += 64){
    #pragma unroll
    for (int cc = 0; cc < 2; cc++){
      int ch = t + cc*256;
      int row = ch >> 3, cg = (ch & 7) * 8;
      *(bfrag*)&lA[row][cg] = *(const bfrag*)&A[(size_t)(m0 + row) * K + k0 + cg];
      *(bfrag*)&lB[row][cg] = *(const bfrag*)&Bt[(size_t)(n0 + row) * K + k0 + cg];
    }
    __syncthreads();
    #pragma unroll
    for (int ks = 0; ks < 2; ks++){
      bfrag a0 = *(const bfrag*)&lA[wr + lr][ks*32 + kq];
      bfrag a1 = *(const bfrag*)&lA[wr + 16 + lr][ks*32 + kq];
      bfrag b0 = *(const bfrag*)&lB[wc + lr][ks*32 + kq];
      bfrag b1 = *(const bfrag*)&lB[wc + 16 + lr][ks*32 + kq];
      acc00 = __builtin_amdgcn_mfma_f32_16x16x32_bf16(a0, b0, acc00, 0, 0, 0);
      acc01 = __builtin_amdgcn_mfma_f32_16x16x32_bf16(a0, b1, acc01, 0, 0, 0);
      acc10 = __builtin_amdgcn_mfma_f32_16x16x32_bf16(a1, b0, acc10, 0, 0, 0);
      acc11 = __builtin_amdgcn_mfma_f32_16x16x32_bf16(a1, b1, acc11, 0, 0, 0);
    }
    __syncthreads();
  }
  int rl = (l >> 4) * 4, cl = l & 15;
  facc accs[2][2] = {{acc00, acc01},{acc10, acc11}};
  #pragma unroll
  for (int mt = 0; mt < 2; mt++)
  #pragma unroll
  for (int nt = 0; nt < 2; nt++)
  #pragma unroll
  for (int j = 0; j < 4; j++){
    int r = m0 + wr + mt*16 + rl + j;
    int c = n0 + wc + nt*16 + cl;
    outF[(size_t)r * N + c] = accs[mt][nt][j];
  }
}

// ---- q GEMM with FUSED rmsnorm+gamma^2+1/8 epilogue -> qnb bf16 [B][H][SL][DH]
__global__ __launch_bounds__(256) void gemm_q(const unsigned short* __restrict__ A,
    const unsigned short* __restrict__ Bt, const float* __restrict__ gamma,
    unsigned short* __restrict__ qn){
  __shared__ char smemb[18432];          // lA/lB (2x 64x72 shorts) ; reused as Cf f32[64][66]
  unsigned short* lA = (unsigned short*)smemb;
  unsigned short* lB = lA + 64*72;
  float* Cf = (float*)smemb;             // 64*66*4 = 16896 <= 18432
  int h = blockIdx.x, n0 = h * 64, m0 = blockIdx.y * 64;
  int t = threadIdx.x, w = t >> 6, l = t & 63;
  int wr = (w >> 1) * 32, wc = (w & 1) * 32;
  int lr = l & 15, kq = (l >> 4) * 8;
  facc acc00 = (facc)0.f, acc01 = (facc)0.f, acc10 = (facc)0.f, acc11 = (facc)0.f;
  for (int k0 = 0; k0 < 1024; k0 += 64){
    #pragma unroll
    for (int cc = 0; cc < 2; cc++){
      int ch = t + cc*256;
      int row = ch >> 3, cg = (ch & 7) * 8;
      *(bfrag*)&lA[row*72 + cg] = *(const bfrag*)&A[(size_t)(m0 + row) * 1024 + k0 + cg];
      *(bfrag*)&lB[row*72 + cg] = *(const bfrag*)&Bt[(size_t)(n0 + row) * 1024 + k0 + cg];
    }
    __syncthreads();
    #pragma unroll
    for (int ks = 0; ks < 2; ks++){
      bfrag a0 = *(const bfrag*)&lA[(wr + lr)*72 + ks*32 + kq];
      bfrag a1 = *(const bfrag*)&lA[(wr + 16 + lr)*72 + ks*32 + kq];
      bfrag b0 = *(const bfrag*)&lB[(wc + lr)*72 + ks*32 + kq];
      bfrag b1 = *(const bfrag*)&lB[(wc + 16 + lr)*72 + ks*32 + kq];
      acc00 = __builtin_amdgcn_mfma_f32_16x16x32_bf16(a0, b0, acc00, 0, 0, 0);
      acc01 = __builtin_amdgcn_mfma_f32_16x16x32_bf16(a0, b1, acc01, 0, 0, 0);
      acc10 = __builtin_amdgcn_mfma_f32_16x16x32_bf16(a1, b0, acc10, 0, 0, 0);
      acc11 = __builtin_amdgcn_mfma_f32_16x16x32_bf16(a1, b1, acc11, 0, 0, 0);
    }
    __syncthreads();
  }
  int rl = (l >> 4) * 4, cl = l & 15;
  facc accs[2][2] = {{acc00, acc01},{acc10, acc11}};
  #pragma unroll
  for (int mt = 0; mt < 2; mt++)
  #pragma unroll
  for (int nt = 0; nt < 2; nt++)
  #pragma unroll
  for (int j = 0; j < 4; j++)
    Cf[(wr + mt*16 + rl + j)*66 + wc + nt*16 + cl] = accs[mt][nt][j];
  __syncthreads();
  if (t < 64){
    const float* src = &Cf[t*66];
    float ss = 0.f;
    #pragma unroll
    for (int d = 0; d < 64; d++){ float a = src[d]; ss = fmaf(a, a, ss); }
    float rv = 0.125f / fmaxf(sqrtf(ss) * 0.125f, 1e-8f);
    int r = m0 + t, b = r >> 8, sl = r & 255;
    unsigned short* dst = &qn[((size_t)(b*HH + h)*SLL + sl)*DHH];
    #pragma unroll
    for (int i = 0; i < 8; i++){
      ushort4 p; float g;
      g = gamma[i*8+0]; p.x = f2bf(src[i*8+0]*g*g*rv);
      g = gamma[i*8+1]; p.y = f2bf(src[i*8+1]*g*g*rv);
      g = gamma[i*8+2]; p.z = f2bf(src[i*8+2]*g*g*rv);
      g = gamma[i*8+3]; p.w = f2bf(src[i*8+3]*g*g*rv);
      ushort4 q;
      g = gamma[i*8+4]; q.x = f2bf(src[i*8+4]*g*g*rv);
      g = gamma[i*8+5]; q.y = f2bf(src[i*8+5]*g*g*rv);
      g = gamma[i*8+6]; q.z = f2bf(src[i*8+6]*g*g*rv);
      g = gamma[i*8+7]; q.w = f2bf(src[i*8+7]*g*g*rv);
      *(ushort4*)&dst[i*8]     = p;
      *(ushort4*)&dst[i*8 + 4] = q;
    }
  }
}

// ---- kv GEMM, R15: m201-faithful 256x256 8-phase port. 512 thr (2M x 4N waves,
// 128x64 out each, frag strips INTERLEAVED: frag mt at row mt*32+wm*16 so each phase
// quadrant (mh,ks) consumes exactly one physical A-half). 2-buffer LDS (128 KB).
// Per K-tile: 4 phases = {8 ds_read ; stage 1 half-tile (2 gload_lds) ; barrier ;
// lgkmcnt(0)+sched_barrier ; setprio1 + 16 MFMA + setprio0 ; [vmcnt(2) at p3] ; barrier}.
// Staging schedule (provably race-free, same-buf write only at p3 after last read at p2):
//   p0: Ah1(tj+1)  p1: Bh0(tj+1)  p2: Bh1(tj+1)  p3: Ah0(tj+2) + vmcnt(2).
// vmcnt(2) leaves only Ah0(tj+2) in flight -> tile tj+1 fully landed; never drains
// until tile 14. Accumulation order bitwise-identical to R12 (ks0 then ks1 per tile).
__global__ __launch_bounds__(512, 2) void gemm_kv(const unsigned short* __restrict__ A,
    const unsigned short* __restrict__ Bt,
    const float* __restrict__ mask_x, const float* __restrict__ mask_lat,
    unsigned short* __restrict__ outK, unsigned short* __restrict__ outV,
    float* __restrict__ rkm){
  __shared__ alignas(16) unsigned short lds[65536];      // 131072 B: 2 bufs x (A 16384 + B 16384 shorts)
  int bid = blockIdx.x;
  int wg = (bid & 7) * 68 + (bid >> 3);                  // 544 = 8 * 68: bijective XCD swizzle
  int m0 = (wg >> 3) * 256, n0 = (wg & 7) * 256;
  int t = threadIdx.x, w = t >> 6, l = t & 63;
  int wm = w >> 2, wn = w & 3;                           // 2M x 4N waves
  int lr = l & 15, q2 = l >> 4;
  int r8 = l >> 3, u = l & 7;
  int swz = (u ^ r8) * 8;                                // pre-swizzled global source (rule #21)
  const unsigned short* Ag = A  + (size_t)(m0 + w*8 + r8) * 1024 + swz;
  const unsigned short* Bg = Bt + (size_t)(n0 + w*8 + r8) * 1024 + swz;

  facc acc[8][4];
  #pragma unroll
  for (int mt = 0; mt < 8; mt++)
  #pragma unroll
  for (int nt = 0; nt < 4; nt++) acc[mt][nt] = (facc)0.f;

#define SBAR __builtin_amdgcn_sched_barrier(0)
#define BAR  __builtin_amdgcn_s_barrier()
// stage one half (128 rows x 128 B) of A or B of tile tj: 2 sweeps x (512 thr x 16 B)
#define ST_A(tj, h, sw) GLOAD_LDS16(Ag + (size_t)((h)*128 + (sw)*64)*1024 + (tj)*64, \
    &lds[((tj)&1)*32768 + ((h)*128 + (sw)*64 + w*8)*64])
#define ST_B(tj, h, sw) GLOAD_LDS16(Bg + (size_t)((h)*128 + (sw)*64)*1024 + (tj)*64, \
    &lds[((tj)&1)*32768 + 16384 + ((h)*128 + (sw)*64 + w*8)*64])
#define ST_AH(tj, h) do{ ST_A(tj, h, 0); ST_A(tj, h, 1); }while(0)
#define ST_BH(tj, h) do{ ST_B(tj, h, 0); ST_B(tj, h, 1); }while(0)
// fragment loads for phase (mh, ks): 4 A-frags (rows mh*128 + i*32 + wm*16) + 4 B-frags
#define LDF(tj, mh, ks) { \
    int cs = (((ks)*4 + q2) ^ (lr & 7)) * 8; \
    const unsigned short* pA = &lds[((tj)&1)*32768 + ((mh)*128 + wm*16 + lr)*64 + cs]; \
    const unsigned short* pB = &lds[((tj)&1)*32768 + 16384 + (wn*16 + lr)*64 + cs]; \
    av[0] = *(const bfrag*)(pA);        av[1] = *(const bfrag*)(pA + 2048); \
    av[2] = *(const bfrag*)(pA + 4096); av[3] = *(const bfrag*)(pA + 6144); \
    bv[0] = *(const bfrag*)(pB);        bv[1] = *(const bfrag*)(pB + 4096); \
    bv[2] = *(const bfrag*)(pB + 8192); bv[3] = *(const bfrag*)(pB + 12288); }
#define MFMA_Q(mh) do { \
    __builtin_amdgcn_s_setprio(1); \
    _Pragma("unroll") \
    for (int i = 0; i < 4; i++){ \
      _Pragma("unroll") \
      for (int nt = 0; nt < 4; nt++) \
        acc[(mh)*4 + i][nt] = __builtin_amdgcn_mfma_f32_16x16x32_bf16(av[i], bv[nt], acc[(mh)*4 + i][nt], 0, 0, 0); } \
    __builtin_amdgcn_s_setprio(0); } while(0)
#define LGKM0 do{ __asm__ volatile("s_waitcnt lgkmcnt(0)" ::: "memory"); SBAR; }while(0)

  // prologue: tile 0 fully + Ah0(1); vmcnt(2) -> tile 0 landed, Ah0(1) in flight
  ST_AH(0,0); ST_AH(0,1); ST_BH(0,0); ST_BH(0,1); ST_AH(1,0);
  __asm__ volatile("s_waitcnt vmcnt(2)" ::: "memory");
  BAR;

  bfrag av[4], bv[4];
  #pragma unroll
  for (int tj = 0; tj < 16; tj++){
    // p0: (mh0, ks0)
    LDF(tj, 0, 0);
    if (tj + 1 < 16) ST_AH(tj+1, 1);
    BAR; LGKM0;
    MFMA_Q(0);
    BAR;
    // p1: (mh1, ks0)
    LDF(tj, 1, 0);
    if (tj + 1 < 16) ST_BH(tj+1, 0);
    BAR; LGKM0;
    MFMA_Q(1);
    BAR;
    // p2: (mh0, ks1)
    LDF(tj, 0, 1);
    if (tj + 1 < 16) ST_BH(tj+1, 1);
    BAR; LGKM0;
    MFMA_Q(0);
    BAR;
    // p3: (mh1, ks1) ; stage Ah0(tj+2) into same buf (Ah0's last read was p2)
    LDF(tj, 1, 1);
    if (tj + 2 < 16) ST_AH(tj+2, 0);
    BAR; LGKM0;
    MFMA_Q(1);
    if (tj <= 13)      { __asm__ volatile("s_waitcnt vmcnt(2)" ::: "memory"); }
    else if (tj == 14) { __asm__ volatile("s_waitcnt vmcnt(0)" ::: "memory"); }
    BAR;
  }
#undef ST_A
#undef ST_B
#undef ST_AH
#undef ST_BH
#undef LDF
#undef MFMA_Q
#undef LGKM0

  // epilogue: out rows m0 + mt*32 + wm*16 + q2*4 + j ; cols n0 + nt*64 + wn*16 + lr.
  // Two 128-col passes (LDS can't hold padded 256x256). Tiles never span batches.
  int b = m0 / SKV, s0 = m0 - b*SKV;
  if (n0 < DD){
    // K half: per pass stage [s][c] pitch 136; rms over each 64-col head seg; rkm sentinel
    #pragma unroll
    for (int ch = 0; ch < 2; ch++){
      if (ch) __syncthreads();
      #pragma unroll
      for (int mt = 0; mt < 8; mt++)
      #pragma unroll
      for (int k = 0; k < 2; k++){
        int nt = ch*2 + k;
        #pragma unroll
        for (int j = 0; j < 4; j++)
          lds[(mt*32 + wm*16 + q2*4 + j)*136 + k*64 + wn*16 + lr] = f2bf(acc[mt][nt][j]);
      }
      __syncthreads();
      int s = t >> 1, hf = t & 1;
      int srow = s0 + s;
      float cm = (srow < SXX) ? mask_x[b*SXX + srow] : mask_lat[b*SLL + srow - SXX];
      const unsigned short* src = &lds[s*136 + hf*64];
      uint4 wv[8];
      #pragma unroll
      for (int i = 0; i < 8; i++) wv[i] = *(const uint4*)&src[i*8];
      float ss0 = 0.f, ss1 = 0.f;
      #pragma unroll
      for (int i = 0; i < 8; i++){
        const unsigned short* pp = (const unsigned short*)&wv[i];
        #pragma unroll
        for (int e = 0; e < 4; e++){
          float a = bf2f(pp[e]);     ss0 = fmaf(a, a, ss0);
          float c = bf2f(pp[e + 4]); ss1 = fmaf(c, c, ss1);
        }
      }
      float rv = 1.f / fmaxf(sqrtf(ss0 + ss1) * 0.125f, 1e-8f);
      int h = (n0 >> 6) + ch*2 + hf;
      unsigned short* dst = &outK[((size_t)(b*HH + h)*SKV + srow)*DHH];
      #pragma unroll
      for (int i = 0; i < 8; i++)
        *(uint4*)&dst[i*8] = wv[i];
      rkm[((size_t)(b*HH + h))*SKV + srow] = (cm != 0.f) ? rv : -1.f;
    }
  } else {
    // V half: per pass stage transposed [c][s] pitch 264; 128B lines to vT
    #pragma unroll
    for (int ch = 0; ch < 2; ch++){
      if (ch) __syncthreads();
      #pragma unroll
      for (int mt = 0; mt < 8; mt++)
      #pragma unroll
      for (int k = 0; k < 2; k++){
        int nt = ch*2 + k;
        ushort4 p;
        p.x = f2bf(acc[mt][nt][0]); p.y = f2bf(acc[mt][nt][1]);
        p.z = f2bf(acc[mt][nt][2]); p.w = f2bf(acc[mt][nt][3]);
        *(ushort4*)&lds[(k*64 + wn*16 + lr)*264 + mt*32 + wm*16 + q2*4] = p;
      }
      __syncthreads();
      int c = t >> 2, sq = t & 3;
      int gcol = (n0 - DD) + ch*128 + c;
      int hh = gcol >> 6, d = gcol & 63;
      const unsigned short* src = &lds[c*264 + sq*64];
      unsigned short* dst = &outV[((size_t)(b*HH + hh)*DHH + d)*SKV + s0 + sq*64];
      #pragma unroll
      for (int i = 0; i < 8; i++)
        *(uint4*)&dst[i*8] = *(const uint4*)&src[i*8];
    }
  }
}

// ---- flash attention, R14: FUSED q-tiles — one block covers all SL=256 q-rows
// (tt=0..3 sub-tiles of 64), so each K/V slice is fetched ONCE instead of twice.
// split-KV over NSPLIT=8; fixed-max softmax (s in [-8,8]); rkm mask sentinel.
__global__ __launch_bounds__(256) void attn(const unsigned short* __restrict__ qn,
    const unsigned short* __restrict__ kbuf, const unsigned short* __restrict__ vT,
    const float* __restrict__ rkm, const float* __restrict__ mask_lat,
    float* __restrict__ Opart, float* __restrict__ lpart){
  int bh = blockIdx.y, split = blockIdx.z;
  int b = bh >> 4;
  __shared__ unsigned short lP[4][4][16][68];   // per-wave, per-tt P staging (34816 B)
  int t = threadIdx.x, w = t >> 6, l = t & 63;
  int lr = l & 15, q2 = l >> 4, kq = q2 * 8;
  bfrag aq0[4], aq1[4];
  float rm[4][4];
  #pragma unroll
  for (int tt = 0; tt < 4; tt++){
    const unsigned short* qbase = qn + ((size_t)bh * SLL + tt*64 + w*16 + lr) * DHH;
    aq0[tt] = *(const bfrag*)&qbase[kq];
    aq1[tt] = *(const bfrag*)&qbase[32 + kq];
    #pragma unroll
    for (int j = 0; j < 4; j++) rm[tt][j] = mask_lat[b*SLL + tt*64 + w*16 + q2*4 + j];
  }
  facc O[4][4];
  #pragma unroll
  for (int tt = 0; tt < 4; tt++)
  #pragma unroll
  for (int nt = 0; nt < 4; nt++) O[tt][nt] = (facc)0.f;
  float lsum[4][4];
  #pragma unroll
  for (int tt = 0; tt < 4; tt++)
  #pragma unroll
  for (int j = 0; j < 4; j++) lsum[tt][j] = 0.f;

  int t0 = (split * 68) / NSPLIT, t1 = ((split + 1) * 68) / NSPLIT;
  for (int kt = t0; kt < t1; kt++){
    int key0 = kt * 64;
    const unsigned short* kb = kbuf + ((size_t)bh * SKV + key0) * DHH;
    bfrag bk0[4], bk1[4]; float rk[4];
    #pragma unroll
    for (int nt = 0; nt < 4; nt++){
      bk0[nt] = *(const bfrag*)&kb[(nt*16 + lr)*DHH + kq];
      bk1[nt] = *(const bfrag*)&kb[(nt*16 + lr)*DHH + 32 + kq];
      rk[nt]  = rkm[(size_t)bh*SKV + key0 + nt*16 + lr];   // <0 => masked key
    }
    // V fragments: independent of P -> issue now, consumed after softmax
    const unsigned short* vb = vT + (size_t)bh * DHH * SKV + key0;
    bfrag bv0[4], bv1[4];
    #pragma unroll
    for (int nt = 0; nt < 4; nt++){
      bv0[nt] = *(const bfrag*)&vb[(size_t)(nt*16 + lr)*SKV + kq];
      bv1[nt] = *(const bfrag*)&vb[(size_t)(nt*16 + lr)*SKV + 32 + kq];
    }
    // per-tt: QK MFMAs -> softmax -> stage P (sequential tt keeps VGPR peak low)
    #pragma unroll
    for (int tt = 0; tt < 4; tt++){
      facc S[4];
      #pragma unroll
      for (int nt = 0; nt < 4; nt++){
        S[nt] = (facc)0.f;
        S[nt] = __builtin_amdgcn_mfma_f32_16x16x32_bf16(aq0[tt], bk0[nt], S[nt], 0, 0, 0);
        S[nt] = __builtin_amdgcn_mfma_f32_16x16x32_bf16(aq1[tt], bk1[nt], S[nt], 0, 0, 0);
      }
      #pragma unroll
      for (int j = 0; j < 4; j++){
        float rs_ = 0.f;
        #pragma unroll
        for (int nt = 0; nt < 4; nt++){
          float x = S[nt][j] * rk[nt];
          float sv = (rk[nt] >= 0.f && rm[tt][j] != 0.f) ? x : -3.0e38f;
          float p = __expf(sv - 8.0f);
          rs_ += p;
          lP[w][tt][q2*4 + j][nt*16 + lr] = f2bf(p);
        }
        lsum[tt][j] += rs_;   // per-lane partial (16-lane reduce deferred)
      }
    }
    __asm__ volatile("s_waitcnt lgkmcnt(0)" ::: "memory");   // wave-private LDS round trip
    #pragma unroll
    for (int tt = 0; tt < 4; tt++){
      bfrag ap0 = *(const bfrag*)&lP[w][tt][lr][kq];
      bfrag ap1 = *(const bfrag*)&lP[w][tt][lr][32 + kq];
      #pragma unroll
      for (int nt = 0; nt < 4; nt++){
        O[tt][nt] = __builtin_amdgcn_mfma_f32_16x16x32_bf16(ap0, bv0[nt], O[tt][nt], 0, 0, 0);
        O[tt][nt] = __builtin_amdgcn_mfma_f32_16x16x32_bf16(ap1, bv1[nt], O[tt][nt], 0, 0, 0);
      }
    }
  }
  #pragma unroll
  for (int tt = 0; tt < 4; tt++)
  #pragma unroll
  for (int j = 0; j < 4; j++){
    float L = lsum[tt][j];
    L += __shfl_xor(L, 1); L += __shfl_xor(L, 2);
    L += __shfl_xor(L, 4); L += __shfl_xor(L, 8);
    int srow = tt*64 + w*16 + q2*4 + j;
    size_t obase = (((size_t)split*64 + bh)*SLL + srow)*DHH;
    #pragma unroll
    for (int nt = 0; nt < 4; nt++)
      Opart[obase + nt*16 + lr] = O[tt][nt][j];
    if (lr == 0)
      lpart[((size_t)split*64 + bh)*SLL + srow] = L;
  }
}

// ---- combine partials across splits (fixed-max: plain sums) -> ybuf bf16 [B][SL][D]
__global__ __launch_bounds__(256) void attn_combine(const float* __restrict__ Opart,
    const float* __restrict__ lpart, unsigned short* __restrict__ ybuf){
  int t = threadIdx.x, w = t >> 6, l = t & 63;
  int idx = blockIdx.x * 4 + w;
  int bh = idx >> 8, srow = idx & 255;
  int b = bh >> 4, h = bh & 15;
  float L = 0.f, acc = 0.f;
  #pragma unroll
  for (int s = 0; s < NSPLIT; s++){
    L   += lpart[((size_t)s*64 + bh)*SLL + srow];
    acc += Opart[(((size_t)s*64 + bh)*SLL + srow)*DHH + l];
  }
  ybuf[((size_t)b*SLL + srow)*DD + h*DHH + l] = f2bf(acc / L);
}

extern "C" void kernel_launch(void* const* d_in, const int* in_sizes, int n_in,
                              void* d_out, int out_size, void* d_ws, size_t ws_size,
                              hipStream_t stream) {
  const float* x        = (const float*)d_in[0];
  const float* latents  = (const float*)d_in[1];
  const float* mask_x   = (const float*)d_in[2];
  const float* mask_lat = (const float*)d_in[3];
  const float* ln_x_g   = (const float*)d_in[4];
  const float* ln_x_b   = (const float*)d_in[5];
  const float* ln_l_g   = (const float*)d_in[6];
  const float* ln_l_b   = (const float*)d_in[7];
  const float* Wq       = (const float*)d_in[8];
  const float* Wkv      = (const float*)d_in[9];
  const float* qk_gamma = (const float*)d_in[10];
  const float* Wo       = (const float*)d_in[11];
  float* out = (float*)d_out;

  // ws layout (~127 MB). Opart/lpart ALIAS kvin/lnlat (dead once attn runs).
  char* wsb = (char*)d_ws;
  unsigned short* kvin  = (unsigned short*)(wsb + 0);          // [MKV][D] bf16       35651584
  unsigned short* lnlat = (unsigned short*)(wsb + 35651584);   // [B*SL][D] bf16       2097152
  unsigned short* wqt   = (unsigned short*)(wsb + 37748736);   // [D][D] bf16          2097152
  unsigned short* wkvt  = (unsigned short*)(wsb + 39845888);   // [2D][D] bf16         4194304
  unsigned short* wot   = (unsigned short*)(wsb + 44040192);   // [D][D] bf16          2097152
  unsigned short* qnb   = (unsigned short*)(wsb + 50331648);   // [B][H][SL][DH]       2097152
  unsigned short* kbuf  = (unsigned short*)(wsb + 52428800);   // [B][H][SKV][DH]     35651584
  unsigned short* vT    = (unsigned short*)(wsb + 88080384);   // [B][H][DH][SKV]     35651584
  float*          rkm   = (float*)(wsb + 123731968);           // [B*H*SKV] f32        1114112
  unsigned short* ybuf  = (unsigned short*)(wsb + 124846080);  // [B*SL][D] bf16       2097152
  float*          Opart = (float*)(wsb + 0);                   // [8][64][256][64] f32 33554432 (alias kvin)
  float*          lpart = (float*)(wsb + 35651584);            // [8][64][256] f32      524288 (alias lnlat)

  wtrans3<<<dim3(64, 32, 3), dim3(32, 8), 0, stream>>>(Wq, Wkv, Wo, wqt, wkvt, wot);

  lnorm<<<NB*SXX, 256, 0, stream>>>(x,       ln_x_g, ln_x_b, kvin, nullptr, SXX, 0);
  lnorm<<<NB*SLL, 256, 0, stream>>>(latents, ln_l_g, ln_l_b, kvin, lnlat,   SLL, SXX);

  gemm_q<<<dim3(16, 16), 256, 0, stream>>>(lnlat, wqt, qk_gamma, qnb);
  gemm_kv<<<dim3(544), 512, 0, stream>>>(kvin, wkvt, mask_x, mask_lat, kbuf, vT, rkm);

  attn<<<dim3(1, NB*HH, NSPLIT), 256, 0, stream>>>(qnb, kbuf, vT, rkm, mask_lat, Opart, lpart);
  attn_combine<<<(NB*HH*SLL)/4, 256, 0, stream>>>(Opart, lpart, ybuf);

  gemm64<<<dim3(DD/64, (NB*SLL)/64), 256, 0, stream>>>(ybuf, wot, NB*SLL, DD, DD, out);
}

// Round 7
// 346.473 us; speedup vs baseline: 1.3761x; 1.0169x over previous
//
#include <hip/hip_runtime.h>

#define NB   4
#define SXX  4096
#define SLL  256
#define DD   1024
#define HH   16
#define DHH  64
#define SKV  4352      // SX + SL
#define MKV  17408     // NB * SKV
#define NSPLIT 8

typedef __attribute__((ext_vector_type(8))) short bfrag;   // 8 bf16 (4 VGPRs), MFMA A/B frag
typedef __attribute__((ext_vector_type(4))) float facc;    // MFMA 16x16 C/D frag

__device__ __forceinline__ unsigned short f2bf(float f){
  unsigned u = __builtin_bit_cast(unsigned, f);
  u = (u + 0x7fffu + ((u >> 16) & 1u)) >> 16;   // RNE
  return (unsigned short)u;
}
__device__ __forceinline__ float bf2f(unsigned short h){
  unsigned u = ((unsigned)h) << 16;
  return __builtin_bit_cast(float, u);
}

#define GLOAD_LDS16(g, lds) __builtin_amdgcn_global_load_lds( \
    (const __attribute__((address_space(1))) unsigned int*)(const void*)(g), \
    (__attribute__((address_space(3))) unsigned int*)(void*)(lds), 16, 0, 0)

// ---- weights: in[K][N] f32 -> out[N][K] bf16 ; all three in one launch (grid.z)
__global__ void wtrans3(const float* __restrict__ Wq, const float* __restrict__ Wkv,
                        const float* __restrict__ Wo, unsigned short* __restrict__ wqt,
                        unsigned short* __restrict__ wkvt, unsigned short* __restrict__ wot){
  __shared__ float t[32][33];
  int z = blockIdx.z;
  const float* in; unsigned short* out; int N;
  if (z == 0){ in = Wq;  out = wqt;  N = DD;   }
  else if (z == 1){ in = Wkv; out = wkvt; N = 2*DD; }
  else { in = Wo;  out = wot;  N = DD;   }
  int n0 = blockIdx.x * 32, k0 = blockIdx.y * 32;
  if (n0 >= N) return;
  int tx = threadIdx.x, ty = threadIdx.y;
  #pragma unroll
  for (int i = 0; i < 4; i++)
    t[ty + 8*i][tx] = in[(size_t)(k0 + ty + 8*i) * N + n0 + tx];
  __syncthreads();
  #pragma unroll
  for (int i = 0; i < 4; i++)
    out[(size_t)(n0 + ty + 8*i) * DD + k0 + tx] = f2bf(t[tx][ty + 8*i]);
}

// ---- layernorm one row (D=1024) -> bf16 into kvin (+ optional second copy)
__global__ void lnorm(const float* __restrict__ src, const float* __restrict__ g,
                      const float* __restrict__ bt, unsigned short* __restrict__ kvin,
                      unsigned short* __restrict__ dst2, int seq, int off){
  int row = blockIdx.x;
  int b = row / seq, s = row - b*seq;
  int t = threadIdx.x;
  const float4* rp = (const float4*)(src + (size_t)row * DD);
  float4 v = rp[t];
  float sum = v.x + v.y + v.z + v.w;
  float sq  = v.x*v.x + v.y*v.y + v.z*v.z + v.w*v.w;
  #pragma unroll
  for (int o = 32; o > 0; o >>= 1){ sum += __shfl_down(sum, o); sq += __shfl_down(sq, o); }
  __shared__ float ls[8];
  int w = t >> 6, l = t & 63;
  if (l == 0){ ls[w] = sum; ls[4 + w] = sq; }
  __syncthreads();
  sum = ls[0] + ls[1] + ls[2] + ls[3];
  sq  = ls[4] + ls[5] + ls[6] + ls[7];
  float mu  = sum * (1.f/DD);
  float var = sq * (1.f/DD) - mu*mu;
  float rs  = rsqrtf(var + 1e-5f);
  float4 gv = ((const float4*)g)[t];
  float4 bv = ((const float4*)bt)[t];
  ushort4 o4;
  o4.x = f2bf((v.x - mu)*rs*gv.x + bv.x);
  o4.y = f2bf((v.y - mu)*rs*gv.y + bv.y);
  o4.z = f2bf((v.z - mu)*rs*gv.z + bv.z);
  o4.w = f2bf((v.w - mu)*rs*gv.w + bv.w);
  *(ushort4*)(kvin + (size_t)(b*SKV + off + s) * DD + t*4) = o4;
  if (dst2) *(ushort4*)(dst2 + (size_t)row * DD + t*4) = o4;
}

// ---- small GEMM (o projection): 64x64 tile, 4 waves. A[M][K], Bt[N][K] bf16 -> C f32
__global__ __launch_bounds__(256) void gemm64(const unsigned short* __restrict__ A,
    const unsigned short* __restrict__ Bt, int M, int N, int K, float* __restrict__ outF){
  __shared__ unsigned short lA[64][72];
  __shared__ unsigned short lB[64][72];
  int n0 = blockIdx.x * 64, m0 = blockIdx.y * 64;
  int t = threadIdx.x, w = t >> 6, l = t & 63;
  int wr = (w >> 1) * 32, wc = (w & 1) * 32;
  int lr = l & 15, kq = (l >> 4) * 8;
  facc acc00 = (facc)0.f, acc01 = (facc)0.f, acc10 = (facc)0.f, acc11 = (facc)0.f;
  for (int k0 = 0; k0 < K; k0 += 64){
    #pragma unroll
    for (int cc = 0; cc < 2; cc++){
      int ch = t + cc*256;
      int row = ch >> 3, cg = (ch & 7) * 8;
      *(bfrag*)&lA[row][cg] = *(const bfrag*)&A[(size_t)(m0 + row) * K + k0 + cg];
      *(bfrag*)&lB[row][cg] = *(const bfrag*)&Bt[(size_t)(n0 + row) * K + k0 + cg];
    }
    __syncthreads();
    #pragma unroll
    for (int ks = 0; ks < 2; ks++){
      bfrag a0 = *(const bfrag*)&lA[wr + lr][ks*32 + kq];
      bfrag a1 = *(const bfrag*)&lA[wr + 16 + lr][ks*32 + kq];
      bfrag b0 = *(const bfrag*)&lB[wc + lr][ks*32 + kq];
      bfrag b1 = *(const bfrag*)&lB[wc + 16 + lr][ks*32 + kq];
      acc00 = __builtin_amdgcn_mfma_f32_16x16x32_bf16(a0, b0, acc00, 0, 0, 0);
      acc01 = __builtin_amdgcn_mfma_f32_16x16x32_bf16(a0, b1, acc01, 0, 0, 0);
      acc10 = __builtin_amdgcn_mfma_f32_16x16x32_bf16(a1, b0, acc10, 0, 0, 0);
      acc11 = __builtin_amdgcn_mfma_f32_16x16x32_bf16(a1, b1, acc11, 0, 0, 0);
    }
    __syncthreads();
  }
  int rl = (l >> 4) * 4, cl = l & 15;
  facc accs[2][2] = {{acc00, acc01},{acc10, acc11}};
  #pragma unroll
  for (int mt = 0; mt < 2; mt++)
  #pragma unroll
  for (int nt = 0; nt < 2; nt++)
  #pragma unroll
  for (int j = 0; j < 4; j++){
    int r = m0 + wr + mt*16 + rl + j;
    int c = n0 + wc + nt*16 + cl;
    outF[(size_t)r * N + c] = accs[mt][nt][j];
  }
}

// ---- q GEMM with FUSED rmsnorm+gamma^2+1/8 epilogue -> qnb bf16 [B][H][SL][DH]
__global__ __launch_bounds__(256) void gemm_q(const unsigned short* __restrict__ A,
    const unsigned short* __restrict__ Bt, const float* __restrict__ gamma,
    unsigned short* __restrict__ qn){
  __shared__ char smemb[18432];          // lA/lB (2x 64x72 shorts) ; reused as Cf f32[64][66]
  unsigned short* lA = (unsigned short*)smemb;
  unsigned short* lB = lA + 64*72;
  float* Cf = (float*)smemb;             // 64*66*4 = 16896 <= 18432
  int h = blockIdx.x, n0 = h * 64, m0 = blockIdx.y * 64;
  int t = threadIdx.x, w = t >> 6, l = t & 63;
  int wr = (w >> 1) * 32, wc = (w & 1) * 32;
  int lr = l & 15, kq = (l >> 4) * 8;
  facc acc00 = (facc)0.f, acc01 = (facc)0.f, acc10 = (facc)0.f, acc11 = (facc)0.f;
  for (int k0 = 0; k0 < 1024; k0 += 64){
    #pragma unroll
    for (int cc = 0; cc < 2; cc++){
      int ch = t + cc*256;
      int row = ch >> 3, cg = (ch & 7) * 8;
      *(bfrag*)&lA[row*72 + cg] = *(const bfrag*)&A[(size_t)(m0 + row) * 1024 + k0 + cg];
      *(bfrag*)&lB[row*72 + cg] = *(const bfrag*)&Bt[(size_t)(n0 + row) * 1024 + k0 + cg];
    }
    __syncthreads();
    #pragma unroll
    for (int ks = 0; ks < 2; ks++){
      bfrag a0 = *(const bfrag*)&lA[(wr + lr)*72 + ks*32 + kq];
      bfrag a1 = *(const bfrag*)&lA[(wr + 16 + lr)*72 + ks*32 + kq];
      bfrag b0 = *(const bfrag*)&lB[(wc + lr)*72 + ks*32 + kq];
      bfrag b1 = *(const bfrag*)&lB[(wc + 16 + lr)*72 + ks*32 + kq];
      acc00 = __builtin_amdgcn_mfma_f32_16x16x32_bf16(a0, b0, acc00, 0, 0, 0);
      acc01 = __builtin_amdgcn_mfma_f32_16x16x32_bf16(a0, b1, acc01, 0, 0, 0);
      acc10 = __builtin_amdgcn_mfma_f32_16x16x32_bf16(a1, b0, acc10, 0, 0, 0);
      acc11 = __builtin_amdgcn_mfma_f32_16x16x32_bf16(a1, b1, acc11, 0, 0, 0);
    }
    __syncthreads();
  }
  int rl = (l >> 4) * 4, cl = l & 15;
  facc accs[2][2] = {{acc00, acc01},{acc10, acc11}};
  #pragma unroll
  for (int mt = 0; mt < 2; mt++)
  #pragma unroll
  for (int nt = 0; nt < 2; nt++)
  #pragma unroll
  for (int j = 0; j < 4; j++)
    Cf[(wr + mt*16 + rl + j)*66 + wc + nt*16 + cl] = accs[mt][nt][j];
  __syncthreads();
  if (t < 64){
    const float* src = &Cf[t*66];
    float ss = 0.f;
    #pragma unroll
    for (int d = 0; d < 64; d++){ float a = src[d]; ss = fmaf(a, a, ss); }
    float rv = 0.125f / fmaxf(sqrtf(ss) * 0.125f, 1e-8f);
    int r = m0 + t, b = r >> 8, sl = r & 255;
    unsigned short* dst = &qn[((size_t)(b*HH + h)*SLL + sl)*DHH];
    #pragma unroll
    for (int i = 0; i < 8; i++){
      ushort4 p; float g;
      g = gamma[i*8+0]; p.x = f2bf(src[i*8+0]*g*g*rv);
      g = gamma[i*8+1]; p.y = f2bf(src[i*8+1]*g*g*rv);
      g = gamma[i*8+2]; p.z = f2bf(src[i*8+2]*g*g*rv);
      g = gamma[i*8+3]; p.w = f2bf(src[i*8+3]*g*g*rv);
      ushort4 q;
      g = gamma[i*8+4]; q.x = f2bf(src[i*8+4]*g*g*rv);
      g = gamma[i*8+5]; q.y = f2bf(src[i*8+5]*g*g*rv);
      g = gamma[i*8+6]; q.z = f2bf(src[i*8+6]*g*g*rv);
      g = gamma[i*8+7]; q.w = f2bf(src[i*8+7]*g*g*rv);
      *(ushort4*)&dst[i*8]     = p;
      *(ushort4*)&dst[i*8 + 4] = q;
    }
  }
}

// ---- kv GEMM, R16 = R15 + B-fragment HOLD. R15 post-mortem: 544 blocks @1/CU ->
// 3-round wall over 2.125 rounds of work (packing 71%), but active rate 937 TF.
// R15's phases re-read the same B frags for mh0 and mh1 (64KB/tile redundant LDS
// reads): ds_read 256 instr (3072cy) > MFMA 2483cy -> LDS-issue-bound. Fix: load
// bv0(ks0)+bv1(ks1) ONCE per tile at p0 (+32 VGPR), phases p1..p3 load only A frags.
// ds drops to 192 instr (2304cy) < MFMA -> MFMA-bound. Barriers/staging/vmcnt and
// accumulation order are bitwise-identical to R15 (verified).
__global__ __launch_bounds__(512, 2) void gemm_kv(const unsigned short* __restrict__ A,
    const unsigned short* __restrict__ Bt,
    const float* __restrict__ mask_x, const float* __restrict__ mask_lat,
    unsigned short* __restrict__ outK, unsigned short* __restrict__ outV,
    float* __restrict__ rkm){
  __shared__ alignas(16) unsigned short lds[65536];      // 131072 B: 2 bufs x (A 16384 + B 16384 shorts)
  int bid = blockIdx.x;
  int wg = (bid & 7) * 68 + (bid >> 3);                  // 544 = 8 * 68: bijective XCD swizzle
  int m0 = (wg >> 3) * 256, n0 = (wg & 7) * 256;
  int t = threadIdx.x, w = t >> 6, l = t & 63;
  int wm = w >> 2, wn = w & 3;                           // 2M x 4N waves
  int lr = l & 15, q2 = l >> 4;
  int r8 = l >> 3, u = l & 7;
  int swz = (u ^ r8) * 8;                                // pre-swizzled global source (rule #21)
  const unsigned short* Ag = A  + (size_t)(m0 + w*8 + r8) * 1024 + swz;
  const unsigned short* Bg = Bt + (size_t)(n0 + w*8 + r8) * 1024 + swz;

  facc acc[8][4];
  #pragma unroll
  for (int mt = 0; mt < 8; mt++)
  #pragma unroll
  for (int nt = 0; nt < 4; nt++) acc[mt][nt] = (facc)0.f;

#define SBAR __builtin_amdgcn_sched_barrier(0)
#define BAR  __builtin_amdgcn_s_barrier()
// stage one half (128 rows x 128 B) of A or B of tile tj: 2 sweeps x (512 thr x 16 B)
#define ST_A(tj, h, sw) GLOAD_LDS16(Ag + (size_t)((h)*128 + (sw)*64)*1024 + (tj)*64, \
    &lds[((tj)&1)*32768 + ((h)*128 + (sw)*64 + w*8)*64])
#define ST_B(tj, h, sw) GLOAD_LDS16(Bg + (size_t)((h)*128 + (sw)*64)*1024 + (tj)*64, \
    &lds[((tj)&1)*32768 + 16384 + ((h)*128 + (sw)*64 + w*8)*64])
#define ST_AH(tj, h) do{ ST_A(tj, h, 0); ST_A(tj, h, 1); }while(0)
#define ST_BH(tj, h) do{ ST_B(tj, h, 0); ST_B(tj, h, 1); }while(0)
// A fragments for phase (mh, ks): 4 frags at rows mh*128 + i*32 + wm*16
#define LDA(tj, mh, ks) { \
    int cs = (((ks)*4 + q2) ^ (lr & 7)) * 8; \
    const unsigned short* pA = &lds[((tj)&1)*32768 + ((mh)*128 + wm*16 + lr)*64 + cs]; \
    av[0] = *(const bfrag*)(pA);        av[1] = *(const bfrag*)(pA + 2048); \
    av[2] = *(const bfrag*)(pA + 4096); av[3] = *(const bfrag*)(pA + 6144); }
// B fragments for BOTH ks halves, loaded once per tile (held in regs across phases)
#define LDB(tj) { \
    int cs0 = ((q2) ^ (lr & 7)) * 8; \
    int cs1 = ((4 + q2) ^ (lr & 7)) * 8; \
    const unsigned short* pB0 = &lds[((tj)&1)*32768 + 16384 + (wn*16 + lr)*64 + cs0]; \
    const unsigned short* pB1 = &lds[((tj)&1)*32768 + 16384 + (wn*16 + lr)*64 + cs1]; \
    bv0[0] = *(const bfrag*)(pB0);        bv0[1] = *(const bfrag*)(pB0 + 4096); \
    bv0[2] = *(const bfrag*)(pB0 + 8192); bv0[3] = *(const bfrag*)(pB0 + 12288); \
    bv1[0] = *(const bfrag*)(pB1);        bv1[1] = *(const bfrag*)(pB1 + 4096); \
    bv1[2] = *(const bfrag*)(pB1 + 8192); bv1[3] = *(const bfrag*)(pB1 + 12288); }
#define MFMA_Q(mh, BV) do { \
    __builtin_amdgcn_s_setprio(1); \
    _Pragma("unroll") \
    for (int i = 0; i < 4; i++){ \
      _Pragma("unroll") \
      for (int nt = 0; nt < 4; nt++) \
        acc[(mh)*4 + i][nt] = __builtin_amdgcn_mfma_f32_16x16x32_bf16(av[i], BV[nt], acc[(mh)*4 + i][nt], 0, 0, 0); } \
    __builtin_amdgcn_s_setprio(0); } while(0)
#define LGKM0 do{ __asm__ volatile("s_waitcnt lgkmcnt(0)" ::: "memory"); SBAR; }while(0)

  // prologue: tile 0 fully + Ah0(1); vmcnt(2) -> tile 0 landed, Ah0(1) in flight
  ST_AH(0,0); ST_AH(0,1); ST_BH(0,0); ST_BH(0,1); ST_AH(1,0);
  __asm__ volatile("s_waitcnt vmcnt(2)" ::: "memory");
  BAR;

  bfrag av[4], bv0[4], bv1[4];
  #pragma unroll
  for (int tj = 0; tj < 16; tj++){
    // p0: (mh0, ks0) — also load both B halves for the whole tile
    LDA(tj, 0, 0);
    LDB(tj);
    if (tj + 1 < 16) ST_AH(tj+1, 1);
    BAR; LGKM0;
    MFMA_Q(0, bv0);
    BAR;
    // p1: (mh1, ks0) — A only, B held
    LDA(tj, 1, 0);
    if (tj + 1 < 16) ST_BH(tj+1, 0);
    BAR; LGKM0;
    MFMA_Q(1, bv0);
    BAR;
    // p2: (mh0, ks1)
    LDA(tj, 0, 1);
    if (tj + 1 < 16) ST_BH(tj+1, 1);
    BAR; LGKM0;
    MFMA_Q(0, bv1);
    BAR;
    // p3: (mh1, ks1) ; stage Ah0(tj+2) into same buf (Ah0's last read was p2)
    LDA(tj, 1, 1);
    if (tj + 2 < 16) ST_AH(tj+2, 0);
    BAR; LGKM0;
    MFMA_Q(1, bv1);
    if (tj <= 13)      { __asm__ volatile("s_waitcnt vmcnt(2)" ::: "memory"); }
    else if (tj == 14) { __asm__ volatile("s_waitcnt vmcnt(0)" ::: "memory"); }
    BAR;
  }
#undef ST_A
#undef ST_B
#undef ST_AH
#undef ST_BH
#undef LDA
#undef LDB
#undef MFMA_Q
#undef LGKM0

  // epilogue: out rows m0 + mt*32 + wm*16 + q2*4 + j ; cols n0 + nt*64 + wn*16 + lr.
  // Two 128-col passes (LDS can't hold padded 256x256). Tiles never span batches.
  int b = m0 / SKV, s0 = m0 - b*SKV;
  if (n0 < DD){
    // K half: per pass stage [s][c] pitch 136; rms over each 64-col head seg; rkm sentinel
    #pragma unroll
    for (int ch = 0; ch < 2; ch++){
      if (ch) __syncthreads();
      #pragma unroll
      for (int mt = 0; mt < 8; mt++)
      #pragma unroll
      for (int k = 0; k < 2; k++){
        int nt = ch*2 + k;
        #pragma unroll
        for (int j = 0; j < 4; j++)
          lds[(mt*32 + wm*16 + q2*4 + j)*136 + k*64 + wn*16 + lr] = f2bf(acc[mt][nt][j]);
      }
      __syncthreads();
      int s = t >> 1, hf = t & 1;
      int srow = s0 + s;
      float cm = (srow < SXX) ? mask_x[b*SXX + srow] : mask_lat[b*SLL + srow - SXX];
      const unsigned short* src = &lds[s*136 + hf*64];
      uint4 wv[8];
      #pragma unroll
      for (int i = 0; i < 8; i++) wv[i] = *(const uint4*)&src[i*8];
      float ss0 = 0.f, ss1 = 0.f;
      #pragma unroll
      for (int i = 0; i < 8; i++){
        const unsigned short* pp = (const unsigned short*)&wv[i];
        #pragma unroll
        for (int e = 0; e < 4; e++){
          float a = bf2f(pp[e]);     ss0 = fmaf(a, a, ss0);
          float c = bf2f(pp[e + 4]); ss1 = fmaf(c, c, ss1);
        }
      }
      float rv = 1.f / fmaxf(sqrtf(ss0 + ss1) * 0.125f, 1e-8f);
      int h = (n0 >> 6) + ch*2 + hf;
      unsigned short* dst = &outK[((size_t)(b*HH + h)*SKV + srow)*DHH];
      #pragma unroll
      for (int i = 0; i < 8; i++)
        *(uint4*)&dst[i*8] = wv[i];
      rkm[((size_t)(b*HH + h))*SKV + srow] = (cm != 0.f) ? rv : -1.f;
    }
  } else {
    // V half: per pass stage transposed [c][s] pitch 264; 128B lines to vT
    #pragma unroll
    for (int ch = 0; ch < 2; ch++){
      if (ch) __syncthreads();
      #pragma unroll
      for (int mt = 0; mt < 8; mt++)
      #pragma unroll
      for (int k = 0; k < 2; k++){
        int nt = ch*2 + k;
        ushort4 p;
        p.x = f2bf(acc[mt][nt][0]); p.y = f2bf(acc[mt][nt][1]);
        p.z = f2bf(acc[mt][nt][2]); p.w = f2bf(acc[mt][nt][3]);
        *(ushort4*)&lds[(k*64 + wn*16 + lr)*264 + mt*32 + wm*16 + q2*4] = p;
      }
      __syncthreads();
      int c = t >> 2, sq = t & 3;
      int gcol = (n0 - DD) + ch*128 + c;
      int hh = gcol >> 6, d = gcol & 63;
      const unsigned short* src = &lds[c*264 + sq*64];
      unsigned short* dst = &outV[((size_t)(b*HH + hh)*DHH + d)*SKV + s0 + sq*64];
      #pragma unroll
      for (int i = 0; i < 8; i++)
        *(uint4*)&dst[i*8] = *(const uint4*)&src[i*8];
    }
  }
}

// ---- flash attention, R14: FUSED q-tiles — one block covers all SL=256 q-rows
// (tt=0..3 sub-tiles of 64), so each K/V slice is fetched ONCE instead of twice.
// split-KV over NSPLIT=8; fixed-max softmax (s in [-8,8]); rkm mask sentinel.
__global__ __launch_bounds__(256) void attn(const unsigned short* __restrict__ qn,
    const unsigned short* __restrict__ kbuf, const unsigned short* __restrict__ vT,
    const float* __restrict__ rkm, const float* __restrict__ mask_lat,
    float* __restrict__ Opart, float* __restrict__ lpart){
  int bh = blockIdx.y, split = blockIdx.z;
  int b = bh >> 4;
  __shared__ unsigned short lP[4][4][16][68];   // per-wave, per-tt P staging (34816 B)
  int t = threadIdx.x, w = t >> 6, l = t & 63;
  int lr = l & 15, q2 = l >> 4, kq = q2 * 8;
  bfrag aq0[4], aq1[4];
  float rm[4][4];
  #pragma unroll
  for (int tt = 0; tt < 4; tt++){
    const unsigned short* qbase = qn + ((size_t)bh * SLL + tt*64 + w*16 + lr) * DHH;
    aq0[tt] = *(const bfrag*)&qbase[kq];
    aq1[tt] = *(const bfrag*)&qbase[32 + kq];
    #pragma unroll
    for (int j = 0; j < 4; j++) rm[tt][j] = mask_lat[b*SLL + tt*64 + w*16 + q2*4 + j];
  }
  facc O[4][4];
  #pragma unroll
  for (int tt = 0; tt < 4; tt++)
  #pragma unroll
  for (int nt = 0; nt < 4; nt++) O[tt][nt] = (facc)0.f;
  float lsum[4][4];
  #pragma unroll
  for (int tt = 0; tt < 4; tt++)
  #pragma unroll
  for (int j = 0; j < 4; j++) lsum[tt][j] = 0.f;

  int t0 = (split * 68) / NSPLIT, t1 = ((split + 1) * 68) / NSPLIT;
  for (int kt = t0; kt < t1; kt++){
    int key0 = kt * 64;
    const unsigned short* kb = kbuf + ((size_t)bh * SKV + key0) * DHH;
    bfrag bk0[4], bk1[4]; float rk[4];
    #pragma unroll
    for (int nt = 0; nt < 4; nt++){
      bk0[nt] = *(const bfrag*)&kb[(nt*16 + lr)*DHH + kq];
      bk1[nt] = *(const bfrag*)&kb[(nt*16 + lr)*DHH + 32 + kq];
      rk[nt]  = rkm[(size_t)bh*SKV + key0 + nt*16 + lr];   // <0 => masked key
    }
    // V fragments: independent of P -> issue now, consumed after softmax
    const unsigned short* vb = vT + (size_t)bh * DHH * SKV + key0;
    bfrag bv0[4], bv1[4];
    #pragma unroll
    for (int nt = 0; nt < 4; nt++){
      bv0[nt] = *(const bfrag*)&vb[(size_t)(nt*16 + lr)*SKV + kq];
      bv1[nt] = *(const bfrag*)&vb[(size_t)(nt*16 + lr)*SKV + 32 + kq];
    }
    // per-tt: QK MFMAs -> softmax -> stage P (sequential tt keeps VGPR peak low)
    #pragma unroll
    for (int tt = 0; tt < 4; tt++){
      facc S[4];
      #pragma unroll
      for (int nt = 0; nt < 4; nt++){
        S[nt] = (facc)0.f;
        S[nt] = __builtin_amdgcn_mfma_f32_16x16x32_bf16(aq0[tt], bk0[nt], S[nt], 0, 0, 0);
        S[nt] = __builtin_amdgcn_mfma_f32_16x16x32_bf16(aq1[tt], bk1[nt], S[nt], 0, 0, 0);
      }
      #pragma unroll
      for (int j = 0; j < 4; j++){
        float rs_ = 0.f;
        #pragma unroll
        for (int nt = 0; nt < 4; nt++){
          float x = S[nt][j] * rk[nt];
          float sv = (rk[nt] >= 0.f && rm[tt][j] != 0.f) ? x : -3.0e38f;
          float p = __expf(sv - 8.0f);
          rs_ += p;
          lP[w][tt][q2*4 + j][nt*16 + lr] = f2bf(p);
        }
        lsum[tt][j] += rs_;   // per-lane partial (16-lane reduce deferred)
      }
    }
    __asm__ volatile("s_waitcnt lgkmcnt(0)" ::: "memory");   // wave-private LDS round trip
    #pragma unroll
    for (int tt = 0; tt < 4; tt++){
      bfrag ap0 = *(const bfrag*)&lP[w][tt][lr][kq];
      bfrag ap1 = *(const bfrag*)&lP[w][tt][lr][32 + kq];
      #pragma unroll
      for (int nt = 0; nt < 4; nt++){
        O[tt][nt] = __builtin_amdgcn_mfma_f32_16x16x32_bf16(ap0, bv0[nt], O[tt][nt], 0, 0, 0);
        O[tt][nt] = __builtin_amdgcn_mfma_f32_16x16x32_bf16(ap1, bv1[nt], O[tt][nt], 0, 0, 0);
      }
    }
  }
  #pragma unroll
  for (int tt = 0; tt < 4; tt++)
  #pragma unroll
  for (int j = 0; j < 4; j++){
    float L = lsum[tt][j];
    L += __shfl_xor(L, 1); L += __shfl_xor(L, 2);
    L += __shfl_xor(L, 4); L += __shfl_xor(L, 8);
    int srow = tt*64 + w*16 + q2*4 + j;
    size_t obase = (((size_t)split*64 + bh)*SLL + srow)*DHH;
    #pragma unroll
    for (int nt = 0; nt < 4; nt++)
      Opart[obase + nt*16 + lr] = O[tt][nt][j];
    if (lr == 0)
      lpart[((size_t)split*64 + bh)*SLL + srow] = L;
  }
}

// ---- combine partials across splits (fixed-max: plain sums) -> ybuf bf16 [B][SL][D]
__global__ __launch_bounds__(256) void attn_combine(const float* __restrict__ Opart,
    const float* __restrict__ lpart, unsigned short* __restrict__ ybuf){
  int t = threadIdx.x, w = t >> 6, l = t & 63;
  int idx = blockIdx.x * 4 + w;
  int bh = idx >> 8, srow = idx & 255;
  int b = bh >> 4, h = bh & 15;
  float L = 0.f, acc = 0.f;
  #pragma unroll
  for (int s = 0; s < NSPLIT; s++){
    L   += lpart[((size_t)s*64 + bh)*SLL + srow];
    acc += Opart[(((size_t)s*64 + bh)*SLL + srow)*DHH + l];
  }
  ybuf[((size_t)b*SLL + srow)*DD + h*DHH + l] = f2bf(acc / L);
}

extern "C" void kernel_launch(void* const* d_in, const int* in_sizes, int n_in,
                              void* d_out, int out_size, void* d_ws, size_t ws_size,
                              hipStream_t stream) {
  const float* x        = (const float*)d_in[0];
  const float* latents  = (const float*)d_in[1];
  const float* mask_x   = (const float*)d_in[2];
  const float* mask_lat = (const float*)d_in[3];
  const float* ln_x_g   = (const float*)d_in[4];
  const float* ln_x_b   = (const float*)d_in[5];
  const float* ln_l_g   = (const float*)d_in[6];
  const float* ln_l_b   = (const float*)d_in[7];
  const float* Wq       = (const float*)d_in[8];
  const float* Wkv      = (const float*)d_in[9];
  const float* qk_gamma = (const float*)d_in[10];
  const float* Wo       = (const float*)d_in[11];
  float* out = (float*)d_out;

  // ws layout (~127 MB). Opart/lpart ALIAS kvin/lnlat (dead once attn runs).
  char* wsb = (char*)d_ws;
  unsigned short* kvin  = (unsigned short*)(wsb + 0);          // [MKV][D] bf16       35651584
  unsigned short* lnlat = (unsigned short*)(wsb + 35651584);   // [B*SL][D] bf16       2097152
  unsigned short* wqt   = (unsigned short*)(wsb + 37748736);   // [D][D] bf16          2097152
  unsigned short* wkvt  = (unsigned short*)(wsb + 39845888);   // [2D][D] bf16         4194304
  unsigned short* wot   = (unsigned short*)(wsb + 44040192);   // [D][D] bf16          2097152
  unsigned short* qnb   = (unsigned short*)(wsb + 50331648);   // [B][H][SL][DH]       2097152
  unsigned short* kbuf  = (unsigned short*)(wsb + 52428800);   // [B][H][SKV][DH]     35651584
  unsigned short* vT    = (unsigned short*)(wsb + 88080384);   // [B][H][DH][SKV]     35651584
  float*          rkm   = (float*)(wsb + 123731968);           // [B*H*SKV] f32        1114112
  unsigned short* ybuf  = (unsigned short*)(wsb + 124846080);  // [B*SL][D] bf16       2097152
  float*          Opart = (float*)(wsb + 0);                   // [8][64][256][64] f32 33554432 (alias kvin)
  float*          lpart = (float*)(wsb + 35651584);            // [8][64][256] f32      524288 (alias lnlat)

  wtrans3<<<dim3(64, 32, 3), dim3(32, 8), 0, stream>>>(Wq, Wkv, Wo, wqt, wkvt, wot);

  lnorm<<<NB*SXX, 256, 0, stream>>>(x,       ln_x_g, ln_x_b, kvin, nullptr, SXX, 0);
  lnorm<<<NB*SLL, 256, 0, stream>>>(latents, ln_l_g, ln_l_b, kvin, lnlat,   SLL, SXX);

  gemm_q<<<dim3(16, 16), 256, 0, stream>>>(lnlat, wqt, qk_gamma, qnb);
  gemm_kv<<<dim3(544), 512, 0, stream>>>(kvin, wkvt, mask_x, mask_lat, kbuf, vT, rkm);

  attn<<<dim3(1, NB*HH, NSPLIT), 256, 0, stream>>>(qnb, kbuf, vT, rkm, mask_lat, Opart, lpart);
  attn_combine<<<(NB*HH*SLL)/4, 256, 0, stream>>>(Opart, lpart, ybuf);

  gemm64<<<dim3(DD/64, (NB*SLL)/64), 256, 0, stream>>>(ybuf, wot, NB*SLL, DD, DD, out);
}

// Round 8
// 336.009 us; speedup vs baseline: 1.4189x; 1.0311x over previous
//
#include <hip/hip_runtime.h>

#define NB   4
#define SXX  4096
#define SLL  256
#define DD   1024
#define HH   16
#define DHH  64
#define SKV  4352      // SX + SL
#define MKV  17408     // NB * SKV
#define NSPLIT 8

typedef __attribute__((ext_vector_type(8))) short bfrag;   // 8 bf16 (4 VGPRs), MFMA A/B frag
typedef __attribute__((ext_vector_type(4))) float facc;    // MFMA 16x16 C/D frag

__device__ __forceinline__ unsigned short f2bf(float f){
  unsigned u = __builtin_bit_cast(unsigned, f);
  u = (u + 0x7fffu + ((u >> 16) & 1u)) >> 16;   // RNE
  return (unsigned short)u;
}
__device__ __forceinline__ float bf2f(unsigned short h){
  unsigned u = ((unsigned)h) << 16;
  return __builtin_bit_cast(float, u);
}

#define GLOAD_LDS16(g, lds) __builtin_amdgcn_global_load_lds( \
    (const __attribute__((address_space(1))) unsigned int*)(const void*)(g), \
    (__attribute__((address_space(3))) unsigned int*)(void*)(lds), 16, 0, 0)

// ---- weights: in[K][N] f32 -> out[N][K] bf16 ; all three in one launch (grid.z)
__global__ void wtrans3(const float* __restrict__ Wq, const float* __restrict__ Wkv,
                        const float* __restrict__ Wo, unsigned short* __restrict__ wqt,
                        unsigned short* __restrict__ wkvt, unsigned short* __restrict__ wot){
  __shared__ float t[32][33];
  int z = blockIdx.z;
  const float* in; unsigned short* out; int N;
  if (z == 0){ in = Wq;  out = wqt;  N = DD;   }
  else if (z == 1){ in = Wkv; out = wkvt; N = 2*DD; }
  else { in = Wo;  out = wot;  N = DD;   }
  int n0 = blockIdx.x * 32, k0 = blockIdx.y * 32;
  if (n0 >= N) return;
  int tx = threadIdx.x, ty = threadIdx.y;
  #pragma unroll
  for (int i = 0; i < 4; i++)
    t[ty + 8*i][tx] = in[(size_t)(k0 + ty + 8*i) * N + n0 + tx];
  __syncthreads();
  #pragma unroll
  for (int i = 0; i < 4; i++)
    out[(size_t)(n0 + ty + 8*i) * DD + k0 + tx] = f2bf(t[tx][ty + 8*i]);
}

// ---- layernorm, R17: ONE launch for x + latents; wave-per-row (64 lanes x 4 float4),
// shuffle-only reduce, zero LDS/barriers (old version: 4-wave LDS reduce + 2 barriers).
// 4 rows per 256-thr block; x/latents boundary is block-aligned (16384 = 4096 blocks).
__global__ __launch_bounds__(256) void lnorm2(const float* __restrict__ x,
    const float* __restrict__ lat,
    const float* __restrict__ gx, const float* __restrict__ bx,
    const float* __restrict__ gl, const float* __restrict__ bl,
    unsigned short* __restrict__ kvin, unsigned short* __restrict__ lnlat){
  int t = threadIdx.x, w = t >> 6, l = t & 63;
  int gr = blockIdx.x * 4 + w;
  const float* src; const float* g; const float* bt;
  unsigned short* d2 = nullptr;
  int b, s, off;
  if (gr < NB*SXX){
    b = gr >> 12; s = gr & 4095; off = 0;
    src = x + (size_t)gr * DD; g = gx; bt = bx;
  } else {
    int r = gr - NB*SXX;
    b = r >> 8; s = r & 255; off = SXX;
    src = lat + (size_t)r * DD; g = gl; bt = bl;
    d2 = lnlat + (size_t)r * DD;
  }
  const float4* rp = (const float4*)src;
  float4 v[4];
  float sum = 0.f, sq = 0.f;
  #pragma unroll
  for (int i = 0; i < 4; i++){
    v[i] = rp[l + i*64];
    sum += v[i].x + v[i].y + v[i].z + v[i].w;
    sq  += v[i].x*v[i].x + v[i].y*v[i].y + v[i].z*v[i].z + v[i].w*v[i].w;
  }
  #pragma unroll
  for (int o = 1; o < 64; o <<= 1){ sum += __shfl_xor(sum, o); sq += __shfl_xor(sq, o); }
  float mu = sum * (1.f/DD);
  float rs = rsqrtf(sq*(1.f/DD) - mu*mu + 1e-5f);
  unsigned short* dst = kvin + (size_t)(b*SKV + off + s) * DD;
  #pragma unroll
  for (int i = 0; i < 4; i++){
    float4 gv = ((const float4*)g)[l + i*64];
    float4 bv = ((const float4*)bt)[l + i*64];
    ushort4 o4;
    o4.x = f2bf((v[i].x - mu)*rs*gv.x + bv.x);
    o4.y = f2bf((v[i].y - mu)*rs*gv.y + bv.y);
    o4.z = f2bf((v[i].z - mu)*rs*gv.z + bv.z);
    o4.w = f2bf((v[i].w - mu)*rs*gv.w + bv.w);
    *(ushort4*)(dst + (size_t)(l + i*64)*4) = o4;
    if (d2) *(ushort4*)(d2 + (size_t)(l + i*64)*4) = o4;
  }
}

// ---- small GEMM (o projection), R17: gload_lds16 staging (pre-swizzled source +
// XOR-swizzled frag reads, gemm_kv recipe). 64x64 tile, 4 waves, single-buffer.
__global__ __launch_bounds__(256) void gemm64(const unsigned short* __restrict__ A,
    const unsigned short* __restrict__ Bt, int M, int N, int K, float* __restrict__ outF){
  __shared__ alignas(16) unsigned short lA[64*64];
  __shared__ alignas(16) unsigned short lB[64*64];
  int n0 = blockIdx.x * 64, m0 = blockIdx.y * 64;
  int t = threadIdx.x, w = t >> 6, l = t & 63;
  int wr = (w >> 1) * 32, wc = (w & 1) * 32;
  int lr = l & 15, q2 = l >> 4;
  int rA = w*8 + (l >> 3), u = l & 7;
  int swz = (u ^ (rA & 7)) * 8;                  // pre-swizzled global col-group
  const unsigned short* Ag = A  + (size_t)(m0 + rA) * K + swz;
  const unsigned short* Bg = Bt + (size_t)(n0 + rA) * K + swz;
  facc acc00 = (facc)0.f, acc01 = (facc)0.f, acc10 = (facc)0.f, acc11 = (facc)0.f;
  for (int k0 = 0; k0 < K; k0 += 64){
    GLOAD_LDS16(Ag + k0,                 &lA[(w*8)*64]);
    GLOAD_LDS16(Ag + (size_t)32*K + k0,  &lA[(32 + w*8)*64]);
    GLOAD_LDS16(Bg + k0,                 &lB[(w*8)*64]);
    GLOAD_LDS16(Bg + (size_t)32*K + k0,  &lB[(32 + w*8)*64]);
    __syncthreads();
    #pragma unroll
    for (int ks = 0; ks < 2; ks++){
      int cs = ((ks*4 + q2) ^ (lr & 7)) * 8;
      bfrag a0 = *(const bfrag*)&lA[(wr + lr)*64 + cs];
      bfrag a1 = *(const bfrag*)&lA[(wr + 16 + lr)*64 + cs];
      bfrag b0 = *(const bfrag*)&lB[(wc + lr)*64 + cs];
      bfrag b1 = *(const bfrag*)&lB[(wc + 16 + lr)*64 + cs];
      acc00 = __builtin_amdgcn_mfma_f32_16x16x32_bf16(a0, b0, acc00, 0, 0, 0);
      acc01 = __builtin_amdgcn_mfma_f32_16x16x32_bf16(a0, b1, acc01, 0, 0, 0);
      acc10 = __builtin_amdgcn_mfma_f32_16x16x32_bf16(a1, b0, acc10, 0, 0, 0);
      acc11 = __builtin_amdgcn_mfma_f32_16x16x32_bf16(a1, b1, acc11, 0, 0, 0);
    }
    __syncthreads();
  }
  int rl = (l >> 4) * 4, cl = l & 15;
  facc accs[2][2] = {{acc00, acc01},{acc10, acc11}};
  #pragma unroll
  for (int mt = 0; mt < 2; mt++)
  #pragma unroll
  for (int nt = 0; nt < 2; nt++)
  #pragma unroll
  for (int j = 0; j < 4; j++){
    int r = m0 + wr + mt*16 + rl + j;
    int c = n0 + wc + nt*16 + cl;
    outF[(size_t)r * N + c] = accs[mt][nt][j];
  }
}

// ---- q GEMM, R17: gload_lds16 staging (same recipe); FUSED rmsnorm epilogue kept.
__global__ __launch_bounds__(256) void gemm_q(const unsigned short* __restrict__ A,
    const unsigned short* __restrict__ Bt, const float* __restrict__ gamma,
    unsigned short* __restrict__ qn){
  __shared__ alignas(16) char smemb[18432];      // lA/lB (2x 64x64 shorts = 16KB) ; Cf f32[64][66]
  unsigned short* lA = (unsigned short*)smemb;
  unsigned short* lB = lA + 64*64;
  float* Cf = (float*)smemb;                     // 64*66*4 = 16896 <= 18432
  int h = blockIdx.x, n0 = h * 64, m0 = blockIdx.y * 64;
  int t = threadIdx.x, w = t >> 6, l = t & 63;
  int wr = (w >> 1) * 32, wc = (w & 1) * 32;
  int lr = l & 15, q2 = l >> 4;
  int rA = w*8 + (l >> 3), u = l & 7;
  int swz = (u ^ (rA & 7)) * 8;
  const unsigned short* Ag = A  + (size_t)(m0 + rA) * 1024 + swz;
  const unsigned short* Bg = Bt + (size_t)(n0 + rA) * 1024 + swz;
  facc acc00 = (facc)0.f, acc01 = (facc)0.f, acc10 = (facc)0.f, acc11 = (facc)0.f;
  for (int k0 = 0; k0 < 1024; k0 += 64){
    GLOAD_LDS16(Ag + k0,          &lA[(w*8)*64]);
    GLOAD_LDS16(Ag + 32768 + k0,  &lA[(32 + w*8)*64]);   // 32*1024
    GLOAD_LDS16(Bg + k0,          &lB[(w*8)*64]);
    GLOAD_LDS16(Bg + 32768 + k0,  &lB[(32 + w*8)*64]);
    __syncthreads();
    #pragma unroll
    for (int ks = 0; ks < 2; ks++){
      int cs = ((ks*4 + q2) ^ (lr & 7)) * 8;
      bfrag a0 = *(const bfrag*)&lA[(wr + lr)*64 + cs];
      bfrag a1 = *(const bfrag*)&lA[(wr + 16 + lr)*64 + cs];
      bfrag b0 = *(const bfrag*)&lB[(wc + lr)*64 + cs];
      bfrag b1 = *(const bfrag*)&lB[(wc + 16 + lr)*64 + cs];
      acc00 = __builtin_amdgcn_mfma_f32_16x16x32_bf16(a0, b0, acc00, 0, 0, 0);
      acc01 = __builtin_amdgcn_mfma_f32_16x16x32_bf16(a0, b1, acc01, 0, 0, 0);
      acc10 = __builtin_amdgcn_mfma_f32_16x16x32_bf16(a1, b0, acc10, 0, 0, 0);
      acc11 = __builtin_amdgcn_mfma_f32_16x16x32_bf16(a1, b1, acc11, 0, 0, 0);
    }
    __syncthreads();
  }
  int rl = (l >> 4) * 4, cl = l & 15;
  facc accs[2][2] = {{acc00, acc01},{acc10, acc11}};
  #pragma unroll
  for (int mt = 0; mt < 2; mt++)
  #pragma unroll
  for (int nt = 0; nt < 2; nt++)
  #pragma unroll
  for (int j = 0; j < 4; j++)
    Cf[(wr + mt*16 + rl + j)*66 + wc + nt*16 + cl] = accs[mt][nt][j];
  __syncthreads();
  if (t < 64){
    const float* src = &Cf[t*66];
    float ss = 0.f;
    #pragma unroll
    for (int d = 0; d < 64; d++){ float a = src[d]; ss = fmaf(a, a, ss); }
    float rv = 0.125f / fmaxf(sqrtf(ss) * 0.125f, 1e-8f);
    int r = m0 + t, b = r >> 8, sl = r & 255;
    unsigned short* dst = &qn[((size_t)(b*HH + h)*SLL + sl)*DHH];
    #pragma unroll
    for (int i = 0; i < 8; i++){
      ushort4 p; float g;
      g = gamma[i*8+0]; p.x = f2bf(src[i*8+0]*g*g*rv);
      g = gamma[i*8+1]; p.y = f2bf(src[i*8+1]*g*g*rv);
      g = gamma[i*8+2]; p.z = f2bf(src[i*8+2]*g*g*rv);
      g = gamma[i*8+3]; p.w = f2bf(src[i*8+3]*g*g*rv);
      ushort4 q;
      g = gamma[i*8+4]; q.x = f2bf(src[i*8+4]*g*g*rv);
      g = gamma[i*8+5]; q.y = f2bf(src[i*8+5]*g*g*rv);
      g = gamma[i*8+6]; q.z = f2bf(src[i*8+6]*g*g*rv);
      g = gamma[i*8+7]; q.w = f2bf(src[i*8+7]*g*g*rv);
      *(ushort4*)&dst[i*8]     = p;
      *(ushort4*)&dst[i*8 + 4] = q;
    }
  }
}

// ---- kv GEMM, R12 (measured best of 4 schedule variants: 97us; R15/R16 256x256
// 8-phase = 104.8 at pack 0.71; design space converges 97-105 — locked).
// 256x128 tile, ring-of-3 LDS, ONE barrier + ONE counted vmcnt per K-tile;
// wave-skew overlaps LDS reads of one wave with MFMAs of another (m114).
__global__ __launch_bounds__(512, 2) void gemm_kv(const unsigned short* __restrict__ A,
    const unsigned short* __restrict__ Bt,
    const float* __restrict__ mask_x, const float* __restrict__ mask_lat,
    unsigned short* __restrict__ outK, unsigned short* __restrict__ outV,
    float* __restrict__ rkm){
  __shared__ alignas(16) unsigned short lds[3 * 24576];  // 147456 B: 3 slots (A 16384 + B 8192 shorts)
  int bid = blockIdx.x;
  int wg = (bid & 7) * 136 + (bid >> 3);                 // 1088 = 8 * 136: bijective XCD swizzle
  int m0 = (wg >> 4) * 256, n0 = (wg & 15) * 128;
  int t = threadIdx.x, w = t >> 6, l = t & 63;
  int wm = w >> 1, wn = w & 1;                           // 4M x 2N waves, 64x64 out each
  int lr = l & 15, q2 = l >> 4;
  int r8 = l >> 3, u = l & 7;
  int swz = (u ^ (r8 & 7)) * 8;                          // pre-swizzled global source (rule #21)
  const unsigned short* Ag = A  + (size_t)(m0 + w*8 + r8) * 1024 + swz;
  const unsigned short* Bg = Bt + (size_t)(n0 + w*8 + r8) * 1024 + swz;

  facc acc[4][4];
  #pragma unroll
  for (int mt = 0; mt < 4; mt++)
  #pragma unroll
  for (int nt = 0; nt < 4; nt++) acc[mt][nt] = (facc)0.f;

#define SBAR __builtin_amdgcn_sched_barrier(0)
#define KV_BARRIER do { SBAR; __builtin_amdgcn_s_barrier(); SBAR; } while(0)
#define KV_STA(j, i) GLOAD_LDS16(Ag + (size_t)(i)*65536 + (j)*64, \
    &lds[((j) % 3)*24576 + (i)*4096 + w*512])
#define KV_STB(j, i) GLOAD_LDS16(Bg + (size_t)(i)*65536 + (j)*64, \
    &lds[((j) % 3)*24576 + 16384 + (i)*4096 + w*512])
#define KV_LDF(va, vb, j, ks) { \
    const unsigned short* pA = &lds[((j) % 3)*24576 + (wm*64 + lr)*64 + (((ks)*4 + q2) ^ (lr & 7))*8]; \
    const unsigned short* pB = &lds[((j) % 3)*24576 + 16384 + (wn*64 + lr)*64 + (((ks)*4 + q2) ^ (lr & 7))*8]; \
    va[0] = *(const bfrag*)(pA);        va[1] = *(const bfrag*)(pA + 1024); \
    va[2] = *(const bfrag*)(pA + 2048); va[3] = *(const bfrag*)(pA + 3072); \
    vb[0] = *(const bfrag*)(pB);        vb[1] = *(const bfrag*)(pB + 1024); \
    vb[2] = *(const bfrag*)(pB + 2048); vb[3] = *(const bfrag*)(pB + 3072); }
#define KV_MFMA(va, vb) do { \
    __builtin_amdgcn_s_setprio(1); \
    _Pragma("unroll") \
    for (int mt = 0; mt < 4; mt++){ \
      _Pragma("unroll") \
      for (int nt = 0; nt < 4; nt++) \
        acc[mt][nt] = __builtin_amdgcn_mfma_f32_16x16x32_bf16(va[mt], vb[nt], acc[mt][nt], 0, 0, 0); } \
    __builtin_amdgcn_s_setprio(0); } while(0)

  // prologue: stage tiles 0,1 (6 loads each); wait tile 0, keep tile 1 in flight
  KV_STA(0,0); KV_STA(0,1); KV_STA(0,2); KV_STA(0,3); KV_STB(0,0); KV_STB(0,1);
  KV_STA(1,0); KV_STA(1,1); KV_STA(1,2); KV_STA(1,3); KV_STB(1,0); KV_STB(1,1);
  __asm__ volatile("s_waitcnt vmcnt(6)" ::: "memory");
  KV_BARRIER;

  bfrag av[4], bv[4];
  #pragma unroll
  for (int j = 0; j < 16; j++){
    // half 1: ks=0 fragments + first half of tile j+2 staging + MFMA cluster
    KV_LDF(av, bv, j, 0);
    if (j < 14){ KV_STA(j+2, 0); KV_STA(j+2, 1); KV_STB(j+2, 0); }
    KV_MFMA(av, bv);
    // half 2: ks=1 fragments + second half of tile j+2 staging + MFMA cluster
    KV_LDF(av, bv, j, 1);
    if (j < 14){ KV_STA(j+2, 2); KV_STA(j+2, 3); KV_STB(j+2, 1); }
    KV_MFMA(av, bv);
    // single boundary: tile j+1 guaranteed in LDS (6 in flight = tile j+2's)
    if (j < 14)       { __asm__ volatile("s_waitcnt vmcnt(6)" ::: "memory"); }
    else if (j == 14) { __asm__ volatile("s_waitcnt vmcnt(0)" ::: "memory"); }
    KV_BARRIER;
  }
#undef KV_STA
#undef KV_STB
#undef KV_LDF
#undef KV_MFMA

  // epilogue: tiles never span batches (SKV = 17*256)
  int b = m0 / SKV, s0 = m0 - b*SKV;
  if (n0 < DD){
    // K half: stage [s][c] pitch 136; per-thread one (row,head) 128B line; rkm sentinel
    #pragma unroll
    for (int mt = 0; mt < 4; mt++)
    #pragma unroll
    for (int nt = 0; nt < 4; nt++)
    #pragma unroll
    for (int j = 0; j < 4; j++)
      lds[(wm*64 + mt*16 + q2*4 + j)*136 + wn*64 + nt*16 + lr] = f2bf(acc[mt][nt][j]);
    __syncthreads();
    int s = t >> 1, hf = t & 1;
    int srow = s0 + s;
    float cm = (srow < SXX) ? mask_x[b*SXX + srow] : mask_lat[b*SLL + srow - SXX];
    const unsigned short* src = &lds[s*136 + hf*64];
    uint4 wv[8];
    #pragma unroll
    for (int i = 0; i < 8; i++) wv[i] = *(const uint4*)&src[i*8];
    float ss0 = 0.f, ss1 = 0.f;
    #pragma unroll
    for (int i = 0; i < 8; i++){
      const unsigned short* pp = (const unsigned short*)&wv[i];
      #pragma unroll
      for (int e = 0; e < 4; e++){
        float a = bf2f(pp[e]);     ss0 = fmaf(a, a, ss0);
        float c = bf2f(pp[e + 4]); ss1 = fmaf(c, c, ss1);
      }
    }
    float rv = 1.f / fmaxf(sqrtf(ss0 + ss1) * 0.125f, 1e-8f);
    int h = (n0 >> 6) + hf;
    unsigned short* dst = &outK[((size_t)(b*HH + h)*SKV + srow)*DHH];
    #pragma unroll
    for (int i = 0; i < 8; i++)
      *(uint4*)&dst[i*8] = wv[i];
    rkm[((size_t)(b*HH + h))*SKV + srow] = (cm != 0.f) ? rv : -1.f;
  } else {
    // V half: stage [c][s] pitch 264 (j contiguous -> ushort4 writes), 128B lines to vT
    #pragma unroll
    for (int mt = 0; mt < 4; mt++)
    #pragma unroll
    for (int nt = 0; nt < 4; nt++){
      ushort4 p;
      p.x = f2bf(acc[mt][nt][0]); p.y = f2bf(acc[mt][nt][1]);
      p.z = f2bf(acc[mt][nt][2]); p.w = f2bf(acc[mt][nt][3]);
      *(ushort4*)&lds[(wn*64 + nt*16 + lr)*264 + wm*64 + mt*16 + q2*4] = p;
    }
    __syncthreads();
    int c = t >> 2, sq = t & 3;
    int hh = ((n0 - DD) >> 6) + (c >> 6), d = c & 63;
    const unsigned short* src = &lds[c*264 + sq*64];
    unsigned short* dst = &outV[((size_t)(b*HH + hh)*DHH + d)*SKV + s0 + sq*64];
    #pragma unroll
    for (int i = 0; i < 8; i++)
      *(uint4*)&dst[i*8] = *(const uint4*)&src[i*8];
  }
}

// ---- flash attention, R14: FUSED q-tiles — one block covers all SL=256 q-rows
// (tt=0..3 sub-tiles of 64), so each K/V slice is fetched ONCE instead of twice.
// split-KV over NSPLIT=8; fixed-max softmax (s in [-8,8]); rkm mask sentinel.
__global__ __launch_bounds__(256) void attn(const unsigned short* __restrict__ qn,
    const unsigned short* __restrict__ kbuf, const unsigned short* __restrict__ vT,
    const float* __restrict__ rkm, const float* __restrict__ mask_lat,
    float* __restrict__ Opart, float* __restrict__ lpart){
  int bh = blockIdx.y, split = blockIdx.z;
  int b = bh >> 4;
  __shared__ unsigned short lP[4][4][16][68];   // per-wave, per-tt P staging (34816 B)
  int t = threadIdx.x, w = t >> 6, l = t & 63;
  int lr = l & 15, q2 = l >> 4, kq = q2 * 8;
  bfrag aq0[4], aq1[4];
  float rm[4][4];
  #pragma unroll
  for (int tt = 0; tt < 4; tt++){
    const unsigned short* qbase = qn + ((size_t)bh * SLL + tt*64 + w*16 + lr) * DHH;
    aq0[tt] = *(const bfrag*)&qbase[kq];
    aq1[tt] = *(const bfrag*)&qbase[32 + kq];
    #pragma unroll
    for (int j = 0; j < 4; j++) rm[tt][j] = mask_lat[b*SLL + tt*64 + w*16 + q2*4 + j];
  }
  facc O[4][4];
  #pragma unroll
  for (int tt = 0; tt < 4; tt++)
  #pragma unroll
  for (int nt = 0; nt < 4; nt++) O[tt][nt] = (facc)0.f;
  float lsum[4][4];
  #pragma unroll
  for (int tt = 0; tt < 4; tt++)
  #pragma unroll
  for (int j = 0; j < 4; j++) lsum[tt][j] = 0.f;

  int t0 = (split * 68) / NSPLIT, t1 = ((split + 1) * 68) / NSPLIT;
  for (int kt = t0; kt < t1; kt++){
    int key0 = kt * 64;
    const unsigned short* kb = kbuf + ((size_t)bh * SKV + key0) * DHH;
    bfrag bk0[4], bk1[4]; float rk[4];
    #pragma unroll
    for (int nt = 0; nt < 4; nt++){
      bk0[nt] = *(const bfrag*)&kb[(nt*16 + lr)*DHH + kq];
      bk1[nt] = *(const bfrag*)&kb[(nt*16 + lr)*DHH + 32 + kq];
      rk[nt]  = rkm[(size_t)bh*SKV + key0 + nt*16 + lr];   // <0 => masked key
    }
    // V fragments: independent of P -> issue now, consumed after softmax
    const unsigned short* vb = vT + (size_t)bh * DHH * SKV + key0;
    bfrag bv0[4], bv1[4];
    #pragma unroll
    for (int nt = 0; nt < 4; nt++){
      bv0[nt] = *(const bfrag*)&vb[(size_t)(nt*16 + lr)*SKV + kq];
      bv1[nt] = *(const bfrag*)&vb[(size_t)(nt*16 + lr)*SKV + 32 + kq];
    }
    // per-tt: QK MFMAs -> softmax -> stage P (sequential tt keeps VGPR peak low)
    #pragma unroll
    for (int tt = 0; tt < 4; tt++){
      facc S[4];
      #pragma unroll
      for (int nt = 0; nt < 4; nt++){
        S[nt] = (facc)0.f;
        S[nt] = __builtin_amdgcn_mfma_f32_16x16x32_bf16(aq0[tt], bk0[nt], S[nt], 0, 0, 0);
        S[nt] = __builtin_amdgcn_mfma_f32_16x16x32_bf16(aq1[tt], bk1[nt], S[nt], 0, 0, 0);
      }
      #pragma unroll
      for (int j = 0; j < 4; j++){
        float rs_ = 0.f;
        #pragma unroll
        for (int nt = 0; nt < 4; nt++){
          float x = S[nt][j] * rk[nt];
          float sv = (rk[nt] >= 0.f && rm[tt][j] != 0.f) ? x : -3.0e38f;
          float p = __expf(sv - 8.0f);
          rs_ += p;
          lP[w][tt][q2*4 + j][nt*16 + lr] = f2bf(p);
        }
        lsum[tt][j] += rs_;   // per-lane partial (16-lane reduce deferred)
      }
    }
    __asm__ volatile("s_waitcnt lgkmcnt(0)" ::: "memory");   // wave-private LDS round trip
    #pragma unroll
    for (int tt = 0; tt < 4; tt++){
      bfrag ap0 = *(const bfrag*)&lP[w][tt][lr][kq];
      bfrag ap1 = *(const bfrag*)&lP[w][tt][lr][32 + kq];
      #pragma unroll
      for (int nt = 0; nt < 4; nt++){
        O[tt][nt] = __builtin_amdgcn_mfma_f32_16x16x32_bf16(ap0, bv0[nt], O[tt][nt], 0, 0, 0);
        O[tt][nt] = __builtin_amdgcn_mfma_f32_16x16x32_bf16(ap1, bv1[nt], O[tt][nt], 0, 0, 0);
      }
    }
  }
  #pragma unroll
  for (int tt = 0; tt < 4; tt++)
  #pragma unroll
  for (int j = 0; j < 4; j++){
    float L = lsum[tt][j];
    L += __shfl_xor(L, 1); L += __shfl_xor(L, 2);
    L += __shfl_xor(L, 4); L += __shfl_xor(L, 8);
    int srow = tt*64 + w*16 + q2*4 + j;
    size_t obase = (((size_t)split*64 + bh)*SLL + srow)*DHH;
    #pragma unroll
    for (int nt = 0; nt < 4; nt++)
      Opart[obase + nt*16 + lr] = O[tt][nt][j];
    if (lr == 0)
      lpart[((size_t)split*64 + bh)*SLL + srow] = L;
  }
}

// ---- combine partials across splits (fixed-max: plain sums) -> ybuf bf16 [B][SL][D]
__global__ __launch_bounds__(256) void attn_combine(const float* __restrict__ Opart,
    const float* __restrict__ lpart, unsigned short* __restrict__ ybuf){
  int t = threadIdx.x, w = t >> 6, l = t & 63;
  int idx = blockIdx.x * 4 + w;
  int bh = idx >> 8, srow = idx & 255;
  int b = bh >> 4, h = bh & 15;
  float L = 0.f, acc = 0.f;
  #pragma unroll
  for (int s = 0; s < NSPLIT; s++){
    L   += lpart[((size_t)s*64 + bh)*SLL + srow];
    acc += Opart[(((size_t)s*64 + bh)*SLL + srow)*DHH + l];
  }
  ybuf[((size_t)b*SLL + srow)*DD + h*DHH + l] = f2bf(acc / L);
}

extern "C" void kernel_launch(void* const* d_in, const int* in_sizes, int n_in,
                              void* d_out, int out_size, void* d_ws, size_t ws_size,
                              hipStream_t stream) {
  const float* x        = (const float*)d_in[0];
  const float* latents  = (const float*)d_in[1];
  const float* mask_x   = (const float*)d_in[2];
  const float* mask_lat = (const float*)d_in[3];
  const float* ln_x_g   = (const float*)d_in[4];
  const float* ln_x_b   = (const float*)d_in[5];
  const float* ln_l_g   = (const float*)d_in[6];
  const float* ln_l_b   = (const float*)d_in[7];
  const float* Wq       = (const float*)d_in[8];
  const float* Wkv      = (const float*)d_in[9];
  const float* qk_gamma = (const float*)d_in[10];
  const float* Wo       = (const float*)d_in[11];
  float* out = (float*)d_out;

  // ws layout (~127 MB). Opart/lpart ALIAS kvin/lnlat (dead once attn runs).
  char* wsb = (char*)d_ws;
  unsigned short* kvin  = (unsigned short*)(wsb + 0);          // [MKV][D] bf16       35651584
  unsigned short* lnlat = (unsigned short*)(wsb + 35651584);   // [B*SL][D] bf16       2097152
  unsigned short* wqt   = (unsigned short*)(wsb + 37748736);   // [D][D] bf16          2097152
  unsigned short* wkvt  = (unsigned short*)(wsb + 39845888);   // [2D][D] bf16         4194304
  unsigned short* wot   = (unsigned short*)(wsb + 44040192);   // [D][D] bf16          2097152
  unsigned short* qnb   = (unsigned short*)(wsb + 50331648);   // [B][H][SL][DH]       2097152
  unsigned short* kbuf  = (unsigned short*)(wsb + 52428800);   // [B][H][SKV][DH]     35651584
  unsigned short* vT    = (unsigned short*)(wsb + 88080384);   // [B][H][DH][SKV]     35651584
  float*          rkm   = (float*)(wsb + 123731968);           // [B*H*SKV] f32        1114112
  unsigned short* ybuf  = (unsigned short*)(wsb + 124846080);  // [B*SL][D] bf16       2097152
  float*          Opart = (float*)(wsb + 0);                   // [8][64][256][64] f32 33554432 (alias kvin)
  float*          lpart = (float*)(wsb + 35651584);            // [8][64][256] f32      524288 (alias lnlat)

  wtrans3<<<dim3(64, 32, 3), dim3(32, 8), 0, stream>>>(Wq, Wkv, Wo, wqt, wkvt, wot);

  lnorm2<<<(NB*SXX + NB*SLL)/4, 256, 0, stream>>>(x, latents, ln_x_g, ln_x_b,
                                                  ln_l_g, ln_l_b, kvin, lnlat);

  gemm_q<<<dim3(16, 16), 256, 0, stream>>>(lnlat, wqt, qk_gamma, qnb);
  gemm_kv<<<dim3(1088), 512, 0, stream>>>(kvin, wkvt, mask_x, mask_lat, kbuf, vT, rkm);

  attn<<<dim3(1, NB*HH, NSPLIT), 256, 0, stream>>>(qnb, kbuf, vT, rkm, mask_lat, Opart, lpart);
  attn_combine<<<(NB*HH*SLL)/4, 256, 0, stream>>>(Opart, lpart, ybuf);

  gemm64<<<dim3(DD/64, (NB*SLL)/64), 256, 0, stream>>>(ybuf, wot, NB*SLL, DD, DD, out);
}

// Round 9
// 318.349 us; speedup vs baseline: 1.4976x; 1.0555x over previous
//
#include <hip/hip_runtime.h>

#define NB   4
#define SXX  4096
#define SLL  256
#define DD   1024
#define HH   16
#define DHH  64
#define SKV  4352      // SX + SL
#define MKV  17408     // NB * SKV
#define NSPLIT 8

typedef __attribute__((ext_vector_type(8))) short bfrag;   // 8 bf16 (4 VGPRs), MFMA A/B frag
typedef __attribute__((ext_vector_type(4))) float facc;    // MFMA 16x16 C/D frag

__device__ __forceinline__ unsigned short f2bf(float f){
  unsigned u = __builtin_bit_cast(unsigned, f);
  u = (u + 0x7fffu + ((u >> 16) & 1u)) >> 16;   // RNE
  return (unsigned short)u;
}
__device__ __forceinline__ float bf2f(unsigned short h){
  unsigned u = ((unsigned)h) << 16;
  return __builtin_bit_cast(float, u);
}

#define GLOAD_LDS16(g, lds) __builtin_amdgcn_global_load_lds( \
    (const __attribute__((address_space(1))) unsigned int*)(const void*)(g), \
    (__attribute__((address_space(3))) unsigned int*)(void*)(lds), 16, 0, 0)

// ---- weights: in[K][N] f32 -> out[N][K] bf16 ; all three in one launch (grid.z)
__global__ void wtrans3(const float* __restrict__ Wq, const float* __restrict__ Wkv,
                        const float* __restrict__ Wo, unsigned short* __restrict__ wqt,
                        unsigned short* __restrict__ wkvt, unsigned short* __restrict__ wot){
  __shared__ float t[32][33];
  int z = blockIdx.z;
  const float* in; unsigned short* out; int N;
  if (z == 0){ in = Wq;  out = wqt;  N = DD;   }
  else if (z == 1){ in = Wkv; out = wkvt; N = 2*DD; }
  else { in = Wo;  out = wot;  N = DD;   }
  int n0 = blockIdx.x * 32, k0 = blockIdx.y * 32;
  if (n0 >= N) return;
  int tx = threadIdx.x, ty = threadIdx.y;
  #pragma unroll
  for (int i = 0; i < 4; i++)
    t[ty + 8*i][tx] = in[(size_t)(k0 + ty + 8*i) * N + n0 + tx];
  __syncthreads();
  #pragma unroll
  for (int i = 0; i < 4; i++)
    out[(size_t)(n0 + ty + 8*i) * DD + k0 + tx] = f2bf(t[tx][ty + 8*i]);
}

// ---- layernorm, R17: ONE launch for x + latents; wave-per-row (64 lanes x 4 float4),
// shuffle-only reduce, zero LDS/barriers.
__global__ __launch_bounds__(256) void lnorm2(const float* __restrict__ x,
    const float* __restrict__ lat,
    const float* __restrict__ gx, const float* __restrict__ bx,
    const float* __restrict__ gl, const float* __restrict__ bl,
    unsigned short* __restrict__ kvin, unsigned short* __restrict__ lnlat){
  int t = threadIdx.x, w = t >> 6, l = t & 63;
  int gr = blockIdx.x * 4 + w;
  const float* src; const float* g; const float* bt;
  unsigned short* d2 = nullptr;
  int b, s, off;
  if (gr < NB*SXX){
    b = gr >> 12; s = gr & 4095; off = 0;
    src = x + (size_t)gr * DD; g = gx; bt = bx;
  } else {
    int r = gr - NB*SXX;
    b = r >> 8; s = r & 255; off = SXX;
    src = lat + (size_t)r * DD; g = gl; bt = bl;
    d2 = lnlat + (size_t)r * DD;
  }
  const float4* rp = (const float4*)src;
  float4 v[4];
  float sum = 0.f, sq = 0.f;
  #pragma unroll
  for (int i = 0; i < 4; i++){
    v[i] = rp[l + i*64];
    sum += v[i].x + v[i].y + v[i].z + v[i].w;
    sq  += v[i].x*v[i].x + v[i].y*v[i].y + v[i].z*v[i].z + v[i].w*v[i].w;
  }
  #pragma unroll
  for (int o = 1; o < 64; o <<= 1){ sum += __shfl_xor(sum, o); sq += __shfl_xor(sq, o); }
  float mu = sum * (1.f/DD);
  float rs = rsqrtf(sq*(1.f/DD) - mu*mu + 1e-5f);
  unsigned short* dst = kvin + (size_t)(b*SKV + off + s) * DD;
  #pragma unroll
  for (int i = 0; i < 4; i++){
    float4 gv = ((const float4*)g)[l + i*64];
    float4 bv = ((const float4*)bt)[l + i*64];
    ushort4 o4;
    o4.x = f2bf((v[i].x - mu)*rs*gv.x + bv.x);
    o4.y = f2bf((v[i].y - mu)*rs*gv.y + bv.y);
    o4.z = f2bf((v[i].z - mu)*rs*gv.z + bv.z);
    o4.w = f2bf((v[i].w - mu)*rs*gv.w + bv.w);
    *(ushort4*)(dst + (size_t)(l + i*64)*4) = o4;
    if (d2) *(ushort4*)(d2 + (size_t)(l + i*64)*4) = o4;
  }
}

// ---- small GEMM (o projection), R17: gload_lds16 staging. 64x64 tile, 4 waves.
__global__ __launch_bounds__(256) void gemm64(const unsigned short* __restrict__ A,
    const unsigned short* __restrict__ Bt, int M, int N, int K, float* __restrict__ outF){
  __shared__ alignas(16) unsigned short lA[64*64];
  __shared__ alignas(16) unsigned short lB[64*64];
  int n0 = blockIdx.x * 64, m0 = blockIdx.y * 64;
  int t = threadIdx.x, w = t >> 6, l = t & 63;
  int wr = (w >> 1) * 32, wc = (w & 1) * 32;
  int lr = l & 15, q2 = l >> 4;
  int rA = w*8 + (l >> 3), u = l & 7;
  int swz = (u ^ (rA & 7)) * 8;                  // pre-swizzled global col-group
  const unsigned short* Ag = A  + (size_t)(m0 + rA) * K + swz;
  const unsigned short* Bg = Bt + (size_t)(n0 + rA) * K + swz;
  facc acc00 = (facc)0.f, acc01 = (facc)0.f, acc10 = (facc)0.f, acc11 = (facc)0.f;
  for (int k0 = 0; k0 < K; k0 += 64){
    GLOAD_LDS16(Ag + k0,                 &lA[(w*8)*64]);
    GLOAD_LDS16(Ag + (size_t)32*K + k0,  &lA[(32 + w*8)*64]);
    GLOAD_LDS16(Bg + k0,                 &lB[(w*8)*64]);
    GLOAD_LDS16(Bg + (size_t)32*K + k0,  &lB[(32 + w*8)*64]);
    __syncthreads();
    #pragma unroll
    for (int ks = 0; ks < 2; ks++){
      int cs = ((ks*4 + q2) ^ (lr & 7)) * 8;
      bfrag a0 = *(const bfrag*)&lA[(wr + lr)*64 + cs];
      bfrag a1 = *(const bfrag*)&lA[(wr + 16 + lr)*64 + cs];
      bfrag b0 = *(const bfrag*)&lB[(wc + lr)*64 + cs];
      bfrag b1 = *(const bfrag*)&lB[(wc + 16 + lr)*64 + cs];
      acc00 = __builtin_amdgcn_mfma_f32_16x16x32_bf16(a0, b0, acc00, 0, 0, 0);
      acc01 = __builtin_amdgcn_mfma_f32_16x16x32_bf16(a0, b1, acc01, 0, 0, 0);
      acc10 = __builtin_amdgcn_mfma_f32_16x16x32_bf16(a1, b0, acc10, 0, 0, 0);
      acc11 = __builtin_amdgcn_mfma_f32_16x16x32_bf16(a1, b1, acc11, 0, 0, 0);
    }
    __syncthreads();
  }
  int rl = (l >> 4) * 4, cl = l & 15;
  facc accs[2][2] = {{acc00, acc01},{acc10, acc11}};
  #pragma unroll
  for (int mt = 0; mt < 2; mt++)
  #pragma unroll
  for (int nt = 0; nt < 2; nt++)
  #pragma unroll
  for (int j = 0; j < 4; j++){
    int r = m0 + wr + mt*16 + rl + j;
    int c = n0 + wc + nt*16 + cl;
    outF[(size_t)r * N + c] = accs[mt][nt][j];
  }
}

// ---- q GEMM, R17: gload_lds16 staging; FUSED rmsnorm epilogue kept.
__global__ __launch_bounds__(256) void gemm_q(const unsigned short* __restrict__ A,
    const unsigned short* __restrict__ Bt, const float* __restrict__ gamma,
    unsigned short* __restrict__ qn){
  __shared__ alignas(16) char smemb[18432];      // lA/lB (2x 64x64 shorts = 16KB) ; Cf f32[64][66]
  unsigned short* lA = (unsigned short*)smemb;
  unsigned short* lB = lA + 64*64;
  float* Cf = (float*)smemb;                     // 64*66*4 = 16896 <= 18432
  int h = blockIdx.x, n0 = h * 64, m0 = blockIdx.y * 64;
  int t = threadIdx.x, w = t >> 6, l = t & 63;
  int wr = (w >> 1) * 32, wc = (w & 1) * 32;
  int lr = l & 15, q2 = l >> 4;
  int rA = w*8 + (l >> 3), u = l & 7;
  int swz = (u ^ (rA & 7)) * 8;
  const unsigned short* Ag = A  + (size_t)(m0 + rA) * 1024 + swz;
  const unsigned short* Bg = Bt + (size_t)(n0 + rA) * 1024 + swz;
  facc acc00 = (facc)0.f, acc01 = (facc)0.f, acc10 = (facc)0.f, acc11 = (facc)0.f;
  for (int k0 = 0; k0 < 1024; k0 += 64){
    GLOAD_LDS16(Ag + k0,          &lA[(w*8)*64]);
    GLOAD_LDS16(Ag + 32768 + k0,  &lA[(32 + w*8)*64]);   // 32*1024
    GLOAD_LDS16(Bg + k0,          &lB[(w*8)*64]);
    GLOAD_LDS16(Bg + 32768 + k0,  &lB[(32 + w*8)*64]);
    __syncthreads();
    #pragma unroll
    for (int ks = 0; ks < 2; ks++){
      int cs = ((ks*4 + q2) ^ (lr & 7)) * 8;
      bfrag a0 = *(const bfrag*)&lA[(wr + lr)*64 + cs];
      bfrag a1 = *(const bfrag*)&lA[(wr + 16 + lr)*64 + cs];
      bfrag b0 = *(const bfrag*)&lB[(wc + lr)*64 + cs];
      bfrag b1 = *(const bfrag*)&lB[(wc + 16 + lr)*64 + cs];
      acc00 = __builtin_amdgcn_mfma_f32_16x16x32_bf16(a0, b0, acc00, 0, 0, 0);
      acc01 = __builtin_amdgcn_mfma_f32_16x16x32_bf16(a0, b1, acc01, 0, 0, 0);
      acc10 = __builtin_amdgcn_mfma_f32_16x16x32_bf16(a1, b0, acc10, 0, 0, 0);
      acc11 = __builtin_amdgcn_mfma_f32_16x16x32_bf16(a1, b1, acc11, 0, 0, 0);
    }
    __syncthreads();
  }
  int rl = (l >> 4) * 4, cl = l & 15;
  facc accs[2][2] = {{acc00, acc01},{acc10, acc11}};
  #pragma unroll
  for (int mt = 0; mt < 2; mt++)
  #pragma unroll
  for (int nt = 0; nt < 2; nt++)
  #pragma unroll
  for (int j = 0; j < 4; j++)
    Cf[(wr + mt*16 + rl + j)*66 + wc + nt*16 + cl] = accs[mt][nt][j];
  __syncthreads();
  if (t < 64){
    const float* src = &Cf[t*66];
    float ss = 0.f;
    #pragma unroll
    for (int d = 0; d < 64; d++){ float a = src[d]; ss = fmaf(a, a, ss); }
    float rv = 0.125f / fmaxf(sqrtf(ss) * 0.125f, 1e-8f);
    int r = m0 + t, b = r >> 8, sl = r & 255;
    unsigned short* dst = &qn[((size_t)(b*HH + h)*SLL + sl)*DHH];
    #pragma unroll
    for (int i = 0; i < 8; i++){
      ushort4 p; float g;
      g = gamma[i*8+0]; p.x = f2bf(src[i*8+0]*g*g*rv);
      g = gamma[i*8+1]; p.y = f2bf(src[i*8+1]*g*g*rv);
      g = gamma[i*8+2]; p.z = f2bf(src[i*8+2]*g*g*rv);
      g = gamma[i*8+3]; p.w = f2bf(src[i*8+3]*g*g*rv);
      ushort4 q;
      g = gamma[i*8+4]; q.x = f2bf(src[i*8+4]*g*g*rv);
      g = gamma[i*8+5]; q.y = f2bf(src[i*8+5]*g*g*rv);
      g = gamma[i*8+6]; q.z = f2bf(src[i*8+6]*g*g*rv);
      g = gamma[i*8+7]; q.w = f2bf(src[i*8+7]*g*g*rv);
      *(ushort4*)&dst[i*8]     = p;
      *(ushort4*)&dst[i*8 + 4] = q;
    }
  }
}

// ---- kv GEMM, R12 (measured best of 4 schedule variants: ~98us — locked).
__global__ __launch_bounds__(512, 2) void gemm_kv(const unsigned short* __restrict__ A,
    const unsigned short* __restrict__ Bt,
    const float* __restrict__ mask_x, const float* __restrict__ mask_lat,
    unsigned short* __restrict__ outK, unsigned short* __restrict__ outV,
    float* __restrict__ rkm){
  __shared__ alignas(16) unsigned short lds[3 * 24576];  // 147456 B: 3 slots (A 16384 + B 8192 shorts)
  int bid = blockIdx.x;
  int wg = (bid & 7) * 136 + (bid >> 3);                 // 1088 = 8 * 136: bijective XCD swizzle
  int m0 = (wg >> 4) * 256, n0 = (wg & 15) * 128;
  int t = threadIdx.x, w = t >> 6, l = t & 63;
  int wm = w >> 1, wn = w & 1;                           // 4M x 2N waves, 64x64 out each
  int lr = l & 15, q2 = l >> 4;
  int r8 = l >> 3, u = l & 7;
  int swz = (u ^ (r8 & 7)) * 8;                          // pre-swizzled global source (rule #21)
  const unsigned short* Ag = A  + (size_t)(m0 + w*8 + r8) * 1024 + swz;
  const unsigned short* Bg = Bt + (size_t)(n0 + w*8 + r8) * 1024 + swz;

  facc acc[4][4];
  #pragma unroll
  for (int mt = 0; mt < 4; mt++)
  #pragma unroll
  for (int nt = 0; nt < 4; nt++) acc[mt][nt] = (facc)0.f;

#define SBAR __builtin_amdgcn_sched_barrier(0)
#define KV_BARRIER do { SBAR; __builtin_amdgcn_s_barrier(); SBAR; } while(0)
#define KV_STA(j, i) GLOAD_LDS16(Ag + (size_t)(i)*65536 + (j)*64, \
    &lds[((j) % 3)*24576 + (i)*4096 + w*512])
#define KV_STB(j, i) GLOAD_LDS16(Bg + (size_t)(i)*65536 + (j)*64, \
    &lds[((j) % 3)*24576 + 16384 + (i)*4096 + w*512])
#define KV_LDF(va, vb, j, ks) { \
    const unsigned short* pA = &lds[((j) % 3)*24576 + (wm*64 + lr)*64 + (((ks)*4 + q2) ^ (lr & 7))*8]; \
    const unsigned short* pB = &lds[((j) % 3)*24576 + 16384 + (wn*64 + lr)*64 + (((ks)*4 + q2) ^ (lr & 7))*8]; \
    va[0] = *(const bfrag*)(pA);        va[1] = *(const bfrag*)(pA + 1024); \
    va[2] = *(const bfrag*)(pA + 2048); va[3] = *(const bfrag*)(pA + 3072); \
    vb[0] = *(const bfrag*)(pB);        vb[1] = *(const bfrag*)(pB + 1024); \
    vb[2] = *(const bfrag*)(pB + 2048); vb[3] = *(const bfrag*)(pB + 3072); }
#define KV_MFMA(va, vb) do { \
    __builtin_amdgcn_s_setprio(1); \
    _Pragma("unroll") \
    for (int mt = 0; mt < 4; mt++){ \
      _Pragma("unroll") \
      for (int nt = 0; nt < 4; nt++) \
        acc[mt][nt] = __builtin_amdgcn_mfma_f32_16x16x32_bf16(va[mt], vb[nt], acc[mt][nt], 0, 0, 0); } \
    __builtin_amdgcn_s_setprio(0); } while(0)

  // prologue: stage tiles 0,1 (6 loads each); wait tile 0, keep tile 1 in flight
  KV_STA(0,0); KV_STA(0,1); KV_STA(0,2); KV_STA(0,3); KV_STB(0,0); KV_STB(0,1);
  KV_STA(1,0); KV_STA(1,1); KV_STA(1,2); KV_STA(1,3); KV_STB(1,0); KV_STB(1,1);
  __asm__ volatile("s_waitcnt vmcnt(6)" ::: "memory");
  KV_BARRIER;

  bfrag av[4], bv[4];
  #pragma unroll
  for (int j = 0; j < 16; j++){
    KV_LDF(av, bv, j, 0);
    if (j < 14){ KV_STA(j+2, 0); KV_STA(j+2, 1); KV_STB(j+2, 0); }
    KV_MFMA(av, bv);
    KV_LDF(av, bv, j, 1);
    if (j < 14){ KV_STA(j+2, 2); KV_STA(j+2, 3); KV_STB(j+2, 1); }
    KV_MFMA(av, bv);
    if (j < 14)       { __asm__ volatile("s_waitcnt vmcnt(6)" ::: "memory"); }
    else if (j == 14) { __asm__ volatile("s_waitcnt vmcnt(0)" ::: "memory"); }
    KV_BARRIER;
  }
#undef KV_STA
#undef KV_STB
#undef KV_LDF
#undef KV_MFMA

  // epilogue: tiles never span batches (SKV = 17*256)
  int b = m0 / SKV, s0 = m0 - b*SKV;
  if (n0 < DD){
    #pragma unroll
    for (int mt = 0; mt < 4; mt++)
    #pragma unroll
    for (int nt = 0; nt < 4; nt++)
    #pragma unroll
    for (int j = 0; j < 4; j++)
      lds[(wm*64 + mt*16 + q2*4 + j)*136 + wn*64 + nt*16 + lr] = f2bf(acc[mt][nt][j]);
    __syncthreads();
    int s = t >> 1, hf = t & 1;
    int srow = s0 + s;
    float cm = (srow < SXX) ? mask_x[b*SXX + srow] : mask_lat[b*SLL + srow - SXX];
    const unsigned short* src = &lds[s*136 + hf*64];
    uint4 wv[8];
    #pragma unroll
    for (int i = 0; i < 8; i++) wv[i] = *(const uint4*)&src[i*8];
    float ss0 = 0.f, ss1 = 0.f;
    #pragma unroll
    for (int i = 0; i < 8; i++){
      const unsigned short* pp = (const unsigned short*)&wv[i];
      #pragma unroll
      for (int e = 0; e < 4; e++){
        float a = bf2f(pp[e]);     ss0 = fmaf(a, a, ss0);
        float c = bf2f(pp[e + 4]); ss1 = fmaf(c, c, ss1);
      }
    }
    float rv = 1.f / fmaxf(sqrtf(ss0 + ss1) * 0.125f, 1e-8f);
    int h = (n0 >> 6) + hf;
    unsigned short* dst = &outK[((size_t)(b*HH + h)*SKV + srow)*DHH];
    #pragma unroll
    for (int i = 0; i < 8; i++)
      *(uint4*)&dst[i*8] = wv[i];
    rkm[((size_t)(b*HH + h))*SKV + srow] = (cm != 0.f) ? rv : -1.f;
  } else {
    #pragma unroll
    for (int mt = 0; mt < 4; mt++)
    #pragma unroll
    for (int nt = 0; nt < 4; nt++){
      ushort4 p;
      p.x = f2bf(acc[mt][nt][0]); p.y = f2bf(acc[mt][nt][1]);
      p.z = f2bf(acc[mt][nt][2]); p.w = f2bf(acc[mt][nt][3]);
      *(ushort4*)&lds[(wn*64 + nt*16 + lr)*264 + wm*64 + mt*16 + q2*4] = p;
    }
    __syncthreads();
    int c = t >> 2, sq = t & 3;
    int hh = ((n0 - DD) >> 6) + (c >> 6), d = c & 63;
    const unsigned short* src = &lds[c*264 + sq*64];
    unsigned short* dst = &outV[((size_t)(b*HH + hh)*DHH + d)*SKV + s0 + sq*64];
    #pragma unroll
    for (int i = 0; i < 8; i++)
      *(uint4*)&dst[i*8] = *(const uint4*)&src[i*8];
  }
}

// ---- flash attention, R18: K/V tiles STAGED THROUGH LDS (gemm_kv recipe).
// R8 theory: old per-wave fragment loads were 16-line gathers x16/kt/wave, duplicated
// across all 4 waves (~1000 TA segments/kt/block vs 310cy MFMA) + dependent-load
// latency exposed at each kt. Now: 4 gload_lds per wave per kt (coalesced 1KB DMA,
// pre-swizzled source), ring-2 LDS buffer, next tile staged at top of current tile
// (~2000cy lookahead -> boundary vmcnt(0) free). Fragments via conflict-free swizzled
// ds_read_b128. Math bitwise-identical (absmax canary: 0.0004882812).
// LDS: 2x(8KB K + 8KB V) + 34.8KB lP = 67.6KB -> 2 blocks/CU kept.
__global__ __launch_bounds__(256) void attn(const unsigned short* __restrict__ qn,
    const unsigned short* __restrict__ kbuf, const unsigned short* __restrict__ vT,
    const float* __restrict__ rkm, const float* __restrict__ mask_lat,
    float* __restrict__ Opart, float* __restrict__ lpart){
  int bh = blockIdx.y, split = blockIdx.z;
  int b = bh >> 4;
  __shared__ alignas(16) unsigned short lK[2][4096];   // [buf][64 key-rows x 64 d] swizzled
  __shared__ alignas(16) unsigned short lV[2][4096];   // [buf][64 d-rows x 64 key] swizzled
  __shared__ unsigned short lP[4][4][16][68];          // per-wave, per-tt P staging
  int t = threadIdx.x, w = t >> 6, l = t & 63;
  int lr = l & 15, q2 = l >> 4, kq = q2 * 8;
  int r8 = l >> 3, u = l & 7;
  int swz8 = (u ^ (r8 & 7)) * 8;                       // staging source pre-swizzle
  int cs0 = (q2 ^ (lr & 7)) * 8;                       // frag-read swizzled chunks
  int cs1 = ((4 + q2) ^ (lr & 7)) * 8;
  // per-lane staging source bases (row w*8+r8 of the 64-row tile; +32 rows on sweep 1)
  const unsigned short* Kg = kbuf + ((size_t)bh*SKV + w*8 + r8)*DHH + swz8;
  const unsigned short* Vg = vT + (size_t)bh*DHH*SKV + (size_t)(w*8 + r8)*SKV + swz8;

  bfrag aq0[4], aq1[4];
  float rm[4][4];
  #pragma unroll
  for (int tt = 0; tt < 4; tt++){
    const unsigned short* qbase = qn + ((size_t)bh * SLL + tt*64 + w*16 + lr) * DHH;
    aq0[tt] = *(const bfrag*)&qbase[kq];
    aq1[tt] = *(const bfrag*)&qbase[32 + kq];
    #pragma unroll
    for (int j = 0; j < 4; j++) rm[tt][j] = mask_lat[b*SLL + tt*64 + w*16 + q2*4 + j];
  }
  facc O[4][4];
  #pragma unroll
  for (int tt = 0; tt < 4; tt++)
  #pragma unroll
  for (int nt = 0; nt < 4; nt++) O[tt][nt] = (facc)0.f;
  float lsum[4][4];
  #pragma unroll
  for (int tt = 0; tt < 4; tt++)
  #pragma unroll
  for (int j = 0; j < 4; j++) lsum[tt][j] = 0.f;

  int t0 = (split * 68) / NSPLIT, t1 = ((split + 1) * 68) / NSPLIT;
  // prologue: stage tile t0 into buf 0 (4 DMA per wave: K s0/s1, V s0/s1)
  {
    int key0 = t0 * 64;
    GLOAD_LDS16(Kg + (size_t)key0*DHH,          &lK[0][(w*8)*64]);
    GLOAD_LDS16(Kg + (size_t)(key0+32)*DHH,     &lK[0][(w*8 + 32)*64]);
    GLOAD_LDS16(Vg + key0,                      &lV[0][(w*8)*64]);
    GLOAD_LDS16(Vg + (size_t)32*SKV + key0,     &lV[0][(w*8 + 32)*64]);
  }
  __asm__ volatile("s_waitcnt vmcnt(0)" ::: "memory");
  __builtin_amdgcn_s_barrier();

  int p = 0;
  for (int kt = t0; kt < t1; kt++){
    int key0 = kt * 64;
    // fragment reads from staged tile (swizzled ds_read_b128, conflict-free)
    bfrag bk0[4], bk1[4], bv0[4], bv1[4]; float rk[4];
    #pragma unroll
    for (int nt = 0; nt < 4; nt++){
      const unsigned short* kr = &lK[p][(nt*16 + lr)*64];
      const unsigned short* vr = &lV[p][(nt*16 + lr)*64];
      bk0[nt] = *(const bfrag*)&kr[cs0];
      bk1[nt] = *(const bfrag*)&kr[cs1];
      bv0[nt] = *(const bfrag*)&vr[cs0];
      bv1[nt] = *(const bfrag*)&vr[cs1];
      rk[nt]  = rkm[(size_t)bh*SKV + key0 + nt*16 + lr];   // <0 => masked key
    }
    // stage next tile early: full kt compute (~2000cy) hides the DMA latency
    if (kt + 1 < t1){
      int kn = key0 + 64;
      GLOAD_LDS16(Kg + (size_t)kn*DHH,        &lK[p^1][(w*8)*64]);
      GLOAD_LDS16(Kg + (size_t)(kn+32)*DHH,   &lK[p^1][(w*8 + 32)*64]);
      GLOAD_LDS16(Vg + kn,                    &lV[p^1][(w*8)*64]);
      GLOAD_LDS16(Vg + (size_t)32*SKV + kn,   &lV[p^1][(w*8 + 32)*64]);
    }
    // per-tt: QK MFMAs -> softmax -> stage P (sequential tt keeps VGPR peak low)
    #pragma unroll
    for (int tt = 0; tt < 4; tt++){
      facc S[4];
      #pragma unroll
      for (int nt = 0; nt < 4; nt++){
        S[nt] = (facc)0.f;
        S[nt] = __builtin_amdgcn_mfma_f32_16x16x32_bf16(aq0[tt], bk0[nt], S[nt], 0, 0, 0);
        S[nt] = __builtin_amdgcn_mfma_f32_16x16x32_bf16(aq1[tt], bk1[nt], S[nt], 0, 0, 0);
      }
      #pragma unroll
      for (int j = 0; j < 4; j++){
        float rs_ = 0.f;
        #pragma unroll
        for (int nt = 0; nt < 4; nt++){
          float x = S[nt][j] * rk[nt];
          float sv = (rk[nt] >= 0.f && rm[tt][j] != 0.f) ? x : -3.0e38f;
          float pz = __expf(sv - 8.0f);
          rs_ += pz;
          lP[w][tt][q2*4 + j][nt*16 + lr] = f2bf(pz);
        }
        lsum[tt][j] += rs_;   // per-lane partial (16-lane reduce deferred)
      }
    }
    __asm__ volatile("s_waitcnt lgkmcnt(0)" ::: "memory");   // wave-private LDS round trip
    #pragma unroll
    for (int tt = 0; tt < 4; tt++){
      bfrag ap0 = *(const bfrag*)&lP[w][tt][lr][kq];
      bfrag ap1 = *(const bfrag*)&lP[w][tt][lr][32 + kq];
      #pragma unroll
      for (int nt = 0; nt < 4; nt++){
        O[tt][nt] = __builtin_amdgcn_mfma_f32_16x16x32_bf16(ap0, bv0[nt], O[tt][nt], 0, 0, 0);
        O[tt][nt] = __builtin_amdgcn_mfma_f32_16x16x32_bf16(ap1, bv1[nt], O[tt][nt], 0, 0, 0);
      }
    }
    // boundary: next tile landed (issued ~full-kt ago); all waves past reads of buf p
    __asm__ volatile("s_waitcnt vmcnt(0)" ::: "memory");
    __builtin_amdgcn_s_barrier();
    p ^= 1;
  }
  #pragma unroll
  for (int tt = 0; tt < 4; tt++)
  #pragma unroll
  for (int j = 0; j < 4; j++){
    float L = lsum[tt][j];
    L += __shfl_xor(L, 1); L += __shfl_xor(L, 2);
    L += __shfl_xor(L, 4); L += __shfl_xor(L, 8);
    int srow = tt*64 + w*16 + q2*4 + j;
    size_t obase = (((size_t)split*64 + bh)*SLL + srow)*DHH;
    #pragma unroll
    for (int nt = 0; nt < 4; nt++)
      Opart[obase + nt*16 + lr] = O[tt][nt][j];
    if (lr == 0)
      lpart[((size_t)split*64 + bh)*SLL + srow] = L;
  }
}

// ---- combine partials across splits (fixed-max: plain sums) -> ybuf bf16 [B][SL][D]
__global__ __launch_bounds__(256) void attn_combine(const float* __restrict__ Opart,
    const float* __restrict__ lpart, unsigned short* __restrict__ ybuf){
  int t = threadIdx.x, w = t >> 6, l = t & 63;
  int idx = blockIdx.x * 4 + w;
  int bh = idx >> 8, srow = idx & 255;
  int b = bh >> 4, h = bh & 15;
  float L = 0.f, acc = 0.f;
  #pragma unroll
  for (int s = 0; s < NSPLIT; s++){
    L   += lpart[((size_t)s*64 + bh)*SLL + srow];
    acc += Opart[(((size_t)s*64 + bh)*SLL + srow)*DHH + l];
  }
  ybuf[((size_t)b*SLL + srow)*DD + h*DHH + l] = f2bf(acc / L);
}

extern "C" void kernel_launch(void* const* d_in, const int* in_sizes, int n_in,
                              void* d_out, int out_size, void* d_ws, size_t ws_size,
                              hipStream_t stream) {
  const float* x        = (const float*)d_in[0];
  const float* latents  = (const float*)d_in[1];
  const float* mask_x   = (const float*)d_in[2];
  const float* mask_lat = (const float*)d_in[3];
  const float* ln_x_g   = (const float*)d_in[4];
  const float* ln_x_b   = (const float*)d_in[5];
  const float* ln_l_g   = (const float*)d_in[6];
  const float* ln_l_b   = (const float*)d_in[7];
  const float* Wq       = (const float*)d_in[8];
  const float* Wkv      = (const float*)d_in[9];
  const float* qk_gamma = (const float*)d_in[10];
  const float* Wo       = (const float*)d_in[11];
  float* out = (float*)d_out;

  // ws layout (~127 MB). Opart/lpart ALIAS kvin/lnlat (dead once attn runs).
  char* wsb = (char*)d_ws;
  unsigned short* kvin  = (unsigned short*)(wsb + 0);          // [MKV][D] bf16       35651584
  unsigned short* lnlat = (unsigned short*)(wsb + 35651584);   // [B*SL][D] bf16       2097152
  unsigned short* wqt   = (unsigned short*)(wsb + 37748736);   // [D][D] bf16          2097152
  unsigned short* wkvt  = (unsigned short*)(wsb + 39845888);   // [2D][D] bf16         4194304
  unsigned short* wot   = (unsigned short*)(wsb + 44040192);   // [D][D] bf16          2097152
  unsigned short* qnb   = (unsigned short*)(wsb + 50331648);   // [B][H][SL][DH]       2097152
  unsigned short* kbuf  = (unsigned short*)(wsb + 52428800);   // [B][H][SKV][DH]     35651584
  unsigned short* vT    = (unsigned short*)(wsb + 88080384);   // [B][H][DH][SKV]     35651584
  float*          rkm   = (float*)(wsb + 123731968);           // [B*H*SKV] f32        1114112
  unsigned short* ybuf  = (unsigned short*)(wsb + 124846080);  // [B*SL][D] bf16       2097152
  float*          Opart = (float*)(wsb + 0);                   // [8][64][256][64] f32 33554432 (alias kvin)
  float*          lpart = (float*)(wsb + 35651584);            // [8][64][256] f32      524288 (alias lnlat)

  wtrans3<<<dim3(64, 32, 3), dim3(32, 8), 0, stream>>>(Wq, Wkv, Wo, wqt, wkvt, wot);

  lnorm2<<<(NB*SXX + NB*SLL)/4, 256, 0, stream>>>(x, latents, ln_x_g, ln_x_b,
                                                  ln_l_g, ln_l_b, kvin, lnlat);

  gemm_q<<<dim3(16, 16), 256, 0, stream>>>(lnlat, wqt, qk_gamma, qnb);
  gemm_kv<<<dim3(1088), 512, 0, stream>>>(kvin, wkvt, mask_x, mask_lat, kbuf, vT, rkm);

  attn<<<dim3(1, NB*HH, NSPLIT), 256, 0, stream>>>(qnb, kbuf, vT, rkm, mask_lat, Opart, lpart);
  attn_combine<<<(NB*HH*SLL)/4, 256, 0, stream>>>(Opart, lpart, ybuf);

  gemm64<<<dim3(DD/64, (NB*SLL)/64), 256, 0, stream>>>(ybuf, wot, NB*SLL, DD, DD, out);
}

// Round 10
// 306.217 us; speedup vs baseline: 1.5570x; 1.0396x over previous
//
#include <hip/hip_runtime.h>

#define NB   4
#define SXX  4096
#define SLL  256
#define DD   1024
#define HH   16
#define DHH  64
#define SKV  4352      // SX + SL
#define MKV  17408     // NB * SKV
#define NSPLIT 8

typedef __attribute__((ext_vector_type(8))) short bfrag;   // 8 bf16 (4 VGPRs), MFMA A/B frag
typedef __attribute__((ext_vector_type(4))) float facc;    // MFMA 16x16 C/D frag

__device__ __forceinline__ unsigned short f2bf(float f){
  unsigned u = __builtin_bit_cast(unsigned, f);
  u = (u + 0x7fffu + ((u >> 16) & 1u)) >> 16;   // RNE
  return (unsigned short)u;
}
__device__ __forceinline__ float bf2f(unsigned short h){
  unsigned u = ((unsigned)h) << 16;
  return __builtin_bit_cast(float, u);
}

#define GLOAD_LDS16(g, lds) __builtin_amdgcn_global_load_lds( \
    (const __attribute__((address_space(1))) unsigned int*)(const void*)(g), \
    (__attribute__((address_space(3))) unsigned int*)(void*)(lds), 16, 0, 0)

// ---- prep, R19: wtrans3 + lnorm2 MERGED into one launch (independent pre-passes;
// saves a launch boundary, overlaps their memory streams). Blocks 0..4095 transpose
// weights (flattened useful grid: 1024 Wq + 2048 Wkv + 1024 Wo); blocks 4096+ are
// wave-per-row layernorm (shuffle-only reduce). lnlat is DEAD (q reads kvin directly
// in the fused gemm_kv) — its writes dropped.
__global__ __launch_bounds__(256) void prep(const float* __restrict__ Wq,
    const float* __restrict__ Wkv, const float* __restrict__ Wo,
    unsigned short* __restrict__ wqt, unsigned short* __restrict__ wkvt,
    unsigned short* __restrict__ wot,
    const float* __restrict__ x, const float* __restrict__ lat,
    const float* __restrict__ gx, const float* __restrict__ bx,
    const float* __restrict__ gl, const float* __restrict__ bl,
    unsigned short* __restrict__ kvin){
  __shared__ float tsh[32][33];
  int bId = blockIdx.x;
  int t = threadIdx.x;
  if (bId < 4096){
    const float* in; unsigned short* out; int N, n0, k0;
    if (bId < 1024){ in = Wq;  out = wqt;  N = DD;   n0 = (bId & 31)*32; k0 = (bId >> 5)*32; }
    else if (bId < 3072){ int b2 = bId - 1024; in = Wkv; out = wkvt; N = 2*DD; n0 = (b2 & 63)*32; k0 = (b2 >> 6)*32; }
    else { int b3 = bId - 3072; in = Wo;  out = wot;  N = DD;   n0 = (b3 & 31)*32; k0 = (b3 >> 5)*32; }
    int tx = t & 31, ty = t >> 5;
    #pragma unroll
    for (int i = 0; i < 4; i++)
      tsh[ty + 8*i][tx] = in[(size_t)(k0 + ty + 8*i) * N + n0 + tx];
    __syncthreads();
    #pragma unroll
    for (int i = 0; i < 4; i++)
      out[(size_t)(n0 + ty + 8*i) * DD + k0 + tx] = f2bf(tsh[tx][ty + 8*i]);
  } else {
    int w = t >> 6, l = t & 63;
    int gr = (bId - 4096) * 4 + w;
    const float* src; const float* g; const float* bt;
    int b, s, off;
    if (gr < NB*SXX){
      b = gr >> 12; s = gr & 4095; off = 0;
      src = x + (size_t)gr * DD; g = gx; bt = bx;
    } else {
      int r = gr - NB*SXX;
      b = r >> 8; s = r & 255; off = SXX;
      src = lat + (size_t)r * DD; g = gl; bt = bl;
    }
    const float4* rp = (const float4*)src;
    float4 v[4];
    float sum = 0.f, sq = 0.f;
    #pragma unroll
    for (int i = 0; i < 4; i++){
      v[i] = rp[l + i*64];
      sum += v[i].x + v[i].y + v[i].z + v[i].w;
      sq  += v[i].x*v[i].x + v[i].y*v[i].y + v[i].z*v[i].z + v[i].w*v[i].w;
    }
    #pragma unroll
    for (int o = 1; o < 64; o <<= 1){ sum += __shfl_xor(sum, o); sq += __shfl_xor(sq, o); }
    float mu = sum * (1.f/DD);
    float rs = rsqrtf(sq*(1.f/DD) - mu*mu + 1e-5f);
    unsigned short* dst = kvin + (size_t)(b*SKV + off + s) * DD;
    #pragma unroll
    for (int i = 0; i < 4; i++){
      float4 gv = ((const float4*)g)[l + i*64];
      float4 bv = ((const float4*)bt)[l + i*64];
      ushort4 o4;
      o4.x = f2bf((v[i].x - mu)*rs*gv.x + bv.x);
      o4.y = f2bf((v[i].y - mu)*rs*gv.y + bv.y);
      o4.z = f2bf((v[i].z - mu)*rs*gv.z + bv.z);
      o4.w = f2bf((v[i].w - mu)*rs*gv.w + bv.w);
      *(ushort4*)(dst + (size_t)(l + i*64)*4) = o4;
    }
  }
}

// ---- small GEMM (o projection), R17: gload_lds16 staging. 64x64 tile, 4 waves.
__global__ __launch_bounds__(256) void gemm64(const unsigned short* __restrict__ A,
    const unsigned short* __restrict__ Bt, int M, int N, int K, float* __restrict__ outF){
  __shared__ alignas(16) unsigned short lA[64*64];
  __shared__ alignas(16) unsigned short lB[64*64];
  int n0 = blockIdx.x * 64, m0 = blockIdx.y * 64;
  int t = threadIdx.x, w = t >> 6, l = t & 63;
  int wr = (w >> 1) * 32, wc = (w & 1) * 32;
  int lr = l & 15, q2 = l >> 4;
  int rA = w*8 + (l >> 3), u = l & 7;
  int swz = (u ^ (rA & 7)) * 8;                  // pre-swizzled global col-group
  const unsigned short* Ag = A  + (size_t)(m0 + rA) * K + swz;
  const unsigned short* Bg = Bt + (size_t)(n0 + rA) * K + swz;
  facc acc00 = (facc)0.f, acc01 = (facc)0.f, acc10 = (facc)0.f, acc11 = (facc)0.f;
  for (int k0 = 0; k0 < K; k0 += 64){
    GLOAD_LDS16(Ag + k0,                 &lA[(w*8)*64]);
    GLOAD_LDS16(Ag + (size_t)32*K + k0,  &lA[(32 + w*8)*64]);
    GLOAD_LDS16(Bg + k0,                 &lB[(w*8)*64]);
    GLOAD_LDS16(Bg + (size_t)32*K + k0,  &lB[(32 + w*8)*64]);
    __syncthreads();
    #pragma unroll
    for (int ks = 0; ks < 2; ks++){
      int cs = ((ks*4 + q2) ^ (lr & 7)) * 8;
      bfrag a0 = *(const bfrag*)&lA[(wr + lr)*64 + cs];
      bfrag a1 = *(const bfrag*)&lA[(wr + 16 + lr)*64 + cs];
      bfrag b0 = *(const bfrag*)&lB[(wc + lr)*64 + cs];
      bfrag b1 = *(const bfrag*)&lB[(wc + 16 + lr)*64 + cs];
      acc00 = __builtin_amdgcn_mfma_f32_16x16x32_bf16(a0, b0, acc00, 0, 0, 0);
      acc01 = __builtin_amdgcn_mfma_f32_16x16x32_bf16(a0, b1, acc01, 0, 0, 0);
      acc10 = __builtin_amdgcn_mfma_f32_16x16x32_bf16(a1, b0, acc10, 0, 0, 0);
      acc11 = __builtin_amdgcn_mfma_f32_16x16x32_bf16(a1, b1, acc11, 0, 0, 0);
    }
    __syncthreads();
  }
  int rl = (l >> 4) * 4, cl = l & 15;
  facc accs[2][2] = {{acc00, acc01},{acc10, acc11}};
  #pragma unroll
  for (int mt = 0; mt < 2; mt++)
  #pragma unroll
  for (int nt = 0; nt < 2; nt++)
  #pragma unroll
  for (int j = 0; j < 4; j++){
    int r = m0 + wr + mt*16 + rl + j;
    int c = n0 + wc + nt*16 + cl;
    outF[(size_t)r * N + c] = accs[mt][nt][j];
  }
}

// ---- kv GEMM, R19: R12 schedule (locked) + gemm_q FUSED as 32 extra tail blocks.
// gemm_q's A rows (normalized latents) are ALREADY in kvin (rows b*SKV+SXX..+255) and
// its tile shape (256x128, K=1024) is identical — blocks 1088..1119 run the same
// K-loop against wqt and a q-epilogue (f32 LDS staging -> per-64-col rms -> gamma^2*rv/8,
// lifted from gemm_q to preserve numerics). They ride the 4.25-round grid's tail
// round (64->96 of 256 CUs) -> gemm_q's entire launch is free.
__global__ __launch_bounds__(512, 2) void gemm_kv(const unsigned short* __restrict__ A,
    const unsigned short* __restrict__ Bt, const unsigned short* __restrict__ Wqt,
    const float* __restrict__ gamma,
    const float* __restrict__ mask_x, const float* __restrict__ mask_lat,
    unsigned short* __restrict__ outK, unsigned short* __restrict__ outV,
    float* __restrict__ rkm, unsigned short* __restrict__ qn){
  __shared__ alignas(16) unsigned short lds[3 * 24576];  // 147456 B: 3 slots (A 16384 + B 8192 shorts)
  int bid = blockIdx.x;
  int m0, n0;
  const unsigned short* Bbase;
  bool isQ = bid >= 1088;
  if (!isQ){
    int wg = (bid & 7) * 136 + (bid >> 3);               // 1088 = 8 * 136: bijective XCD swizzle
    m0 = (wg >> 4) * 256; n0 = (wg & 15) * 128;
    Bbase = Bt;
  } else {
    int i = bid - 1088;                                  // 32 q-blocks: 4 batches x 8 n-tiles
    m0 = (i >> 3) * SKV + SXX;                           // latent rows of batch i>>3
    n0 = (i & 7) * 128;
    Bbase = Wqt;
  }
  int t = threadIdx.x, w = t >> 6, l = t & 63;
  int wm = w >> 1, wn = w & 1;                           // 4M x 2N waves, 64x64 out each
  int lr = l & 15, q2 = l >> 4;
  int r8 = l >> 3, u = l & 7;
  int swz = (u ^ (r8 & 7)) * 8;                          // pre-swizzled global source (rule #21)
  const unsigned short* Ag = A     + (size_t)(m0 + w*8 + r8) * 1024 + swz;
  const unsigned short* Bg = Bbase + (size_t)(n0 + w*8 + r8) * 1024 + swz;

  facc acc[4][4];
  #pragma unroll
  for (int mt = 0; mt < 4; mt++)
  #pragma unroll
  for (int nt = 0; nt < 4; nt++) acc[mt][nt] = (facc)0.f;

#define SBAR __builtin_amdgcn_sched_barrier(0)
#define KV_BARRIER do { SBAR; __builtin_amdgcn_s_barrier(); SBAR; } while(0)
#define KV_STA(j, i) GLOAD_LDS16(Ag + (size_t)(i)*65536 + (j)*64, \
    &lds[((j) % 3)*24576 + (i)*4096 + w*512])
#define KV_STB(j, i) GLOAD_LDS16(Bg + (size_t)(i)*65536 + (j)*64, \
    &lds[((j) % 3)*24576 + 16384 + (i)*4096 + w*512])
#define KV_LDF(va, vb, j, ks) { \
    const unsigned short* pA = &lds[((j) % 3)*24576 + (wm*64 + lr)*64 + (((ks)*4 + q2) ^ (lr & 7))*8]; \
    const unsigned short* pB = &lds[((j) % 3)*24576 + 16384 + (wn*64 + lr)*64 + (((ks)*4 + q2) ^ (lr & 7))*8]; \
    va[0] = *(const bfrag*)(pA);        va[1] = *(const bfrag*)(pA + 1024); \
    va[2] = *(const bfrag*)(pA + 2048); va[3] = *(const bfrag*)(pA + 3072); \
    vb[0] = *(const bfrag*)(pB);        vb[1] = *(const bfrag*)(pB + 1024); \
    vb[2] = *(const bfrag*)(pB + 2048); vb[3] = *(const bfrag*)(pB + 3072); }
#define KV_MFMA(va, vb) do { \
    __builtin_amdgcn_s_setprio(1); \
    _Pragma("unroll") \
    for (int mt = 0; mt < 4; mt++){ \
      _Pragma("unroll") \
      for (int nt = 0; nt < 4; nt++) \
        acc[mt][nt] = __builtin_amdgcn_mfma_f32_16x16x32_bf16(va[mt], vb[nt], acc[mt][nt], 0, 0, 0); } \
    __builtin_amdgcn_s_setprio(0); } while(0)

  // prologue: stage tiles 0,1 (6 loads each); wait tile 0, keep tile 1 in flight
  KV_STA(0,0); KV_STA(0,1); KV_STA(0,2); KV_STA(0,3); KV_STB(0,0); KV_STB(0,1);
  KV_STA(1,0); KV_STA(1,1); KV_STA(1,2); KV_STA(1,3); KV_STB(1,0); KV_STB(1,1);
  __asm__ volatile("s_waitcnt vmcnt(6)" ::: "memory");
  KV_BARRIER;

  bfrag av[4], bv[4];
  #pragma unroll
  for (int j = 0; j < 16; j++){
    KV_LDF(av, bv, j, 0);
    if (j < 14){ KV_STA(j+2, 0); KV_STA(j+2, 1); KV_STB(j+2, 0); }
    KV_MFMA(av, bv);
    KV_LDF(av, bv, j, 1);
    if (j < 14){ KV_STA(j+2, 2); KV_STA(j+2, 3); KV_STB(j+2, 1); }
    KV_MFMA(av, bv);
    if (j < 14)       { __asm__ volatile("s_waitcnt vmcnt(6)" ::: "memory"); }
    else if (j == 14) { __asm__ volatile("s_waitcnt vmcnt(0)" ::: "memory"); }
    KV_BARRIER;
  }
#undef KV_STA
#undef KV_STB
#undef KV_LDF
#undef KV_MFMA

  if (isQ){
    // q epilogue: f32 staging (256x132 pitch = 135KB <= 147KB), per-64-col rms,
    // out = C * gamma^2 * rv with rv = 0.125/max(sqrt(ss)/8, 1e-8)  (gemm_q math)
    int qb = (bid - 1088) >> 3;
    float* ldsF = (float*)lds;
    #pragma unroll
    for (int mt = 0; mt < 4; mt++)
    #pragma unroll
    for (int nt = 0; nt < 4; nt++)
    #pragma unroll
    for (int j = 0; j < 4; j++)
      ldsF[(wm*64 + mt*16 + q2*4 + j)*132 + wn*64 + nt*16 + lr] = acc[mt][nt][j];
    __syncthreads();
    int s = t >> 1, hf = t & 1;
    const float* src = &ldsF[s*132 + hf*64];
    float ss = 0.f;
    #pragma unroll
    for (int d = 0; d < 64; d++){ float a = src[d]; ss = fmaf(a, a, ss); }
    float rv = 0.125f / fmaxf(sqrtf(ss) * 0.125f, 1e-8f);
    int h = (n0 >> 6) + hf;
    unsigned short* dst = &qn[((size_t)(qb*HH + h)*SLL + s)*DHH];
    #pragma unroll
    for (int i = 0; i < 8; i++){
      ushort4 p; float g;
      g = gamma[i*8+0]; p.x = f2bf(src[i*8+0]*g*g*rv);
      g = gamma[i*8+1]; p.y = f2bf(src[i*8+1]*g*g*rv);
      g = gamma[i*8+2]; p.z = f2bf(src[i*8+2]*g*g*rv);
      g = gamma[i*8+3]; p.w = f2bf(src[i*8+3]*g*g*rv);
      ushort4 q;
      g = gamma[i*8+4]; q.x = f2bf(src[i*8+4]*g*g*rv);
      g = gamma[i*8+5]; q.y = f2bf(src[i*8+5]*g*g*rv);
      g = gamma[i*8+6]; q.z = f2bf(src[i*8+6]*g*g*rv);
      g = gamma[i*8+7]; q.w = f2bf(src[i*8+7]*g*g*rv);
      *(ushort4*)&dst[i*8]     = p;
      *(ushort4*)&dst[i*8 + 4] = q;
    }
    return;
  }

  // kv epilogue: tiles never span batches (SKV = 17*256)
  int b = m0 / SKV, s0 = m0 - b*SKV;
  if (n0 < DD){
    #pragma unroll
    for (int mt = 0; mt < 4; mt++)
    #pragma unroll
    for (int nt = 0; nt < 4; nt++)
    #pragma unroll
    for (int j = 0; j < 4; j++)
      lds[(wm*64 + mt*16 + q2*4 + j)*136 + wn*64 + nt*16 + lr] = f2bf(acc[mt][nt][j]);
    __syncthreads();
    int s = t >> 1, hf = t & 1;
    int srow = s0 + s;
    float cm = (srow < SXX) ? mask_x[b*SXX + srow] : mask_lat[b*SLL + srow - SXX];
    const unsigned short* src = &lds[s*136 + hf*64];
    uint4 wv[8];
    #pragma unroll
    for (int i = 0; i < 8; i++) wv[i] = *(const uint4*)&src[i*8];
    float ss0 = 0.f, ss1 = 0.f;
    #pragma unroll
    for (int i = 0; i < 8; i++){
      const unsigned short* pp = (const unsigned short*)&wv[i];
      #pragma unroll
      for (int e = 0; e < 4; e++){
        float a = bf2f(pp[e]);     ss0 = fmaf(a, a, ss0);
        float c = bf2f(pp[e + 4]); ss1 = fmaf(c, c, ss1);
      }
    }
    float rv = 1.f / fmaxf(sqrtf(ss0 + ss1) * 0.125f, 1e-8f);
    int h = (n0 >> 6) + hf;
    unsigned short* dst = &outK[((size_t)(b*HH + h)*SKV + srow)*DHH];
    #pragma unroll
    for (int i = 0; i < 8; i++)
      *(uint4*)&dst[i*8] = wv[i];
    rkm[((size_t)(b*HH + h))*SKV + srow] = (cm != 0.f) ? rv : -1.f;
  } else {
    #pragma unroll
    for (int mt = 0; mt < 4; mt++)
    #pragma unroll
    for (int nt = 0; nt < 4; nt++){
      ushort4 p;
      p.x = f2bf(acc[mt][nt][0]); p.y = f2bf(acc[mt][nt][1]);
      p.z = f2bf(acc[mt][nt][2]); p.w = f2bf(acc[mt][nt][3]);
      *(ushort4*)&lds[(wn*64 + nt*16 + lr)*264 + wm*64 + mt*16 + q2*4] = p;
    }
    __syncthreads();
    int c = t >> 2, sq = t & 3;
    int hh = ((n0 - DD) >> 6) + (c >> 6), d = c & 63;
    const unsigned short* src = &lds[c*264 + sq*64];
    unsigned short* dst = &outV[((size_t)(b*HH + hh)*DHH + d)*SKV + s0 + sq*64];
    #pragma unroll
    for (int i = 0; i < 8; i++)
      *(uint4*)&dst[i*8] = *(const uint4*)&src[i*8];
  }
}

// ---- flash attention, R18: K/V tiles staged through LDS (gemm_kv recipe), ring-2,
// next tile staged at top of current tile. Math bitwise-stable (absmax canary).
__global__ __launch_bounds__(256) void attn(const unsigned short* __restrict__ qn,
    const unsigned short* __restrict__ kbuf, const unsigned short* __restrict__ vT,
    const float* __restrict__ rkm, const float* __restrict__ mask_lat,
    float* __restrict__ Opart, float* __restrict__ lpart){
  int bh = blockIdx.y, split = blockIdx.z;
  int b = bh >> 4;
  __shared__ alignas(16) unsigned short lK[2][4096];   // [buf][64 key-rows x 64 d] swizzled
  __shared__ alignas(16) unsigned short lV[2][4096];   // [buf][64 d-rows x 64 key] swizzled
  __shared__ unsigned short lP[4][4][16][68];          // per-wave, per-tt P staging
  int t = threadIdx.x, w = t >> 6, l = t & 63;
  int lr = l & 15, q2 = l >> 4, kq = q2 * 8;
  int r8 = l >> 3, u = l & 7;
  int swz8 = (u ^ (r8 & 7)) * 8;                       // staging source pre-swizzle
  int cs0 = (q2 ^ (lr & 7)) * 8;                       // frag-read swizzled chunks
  int cs1 = ((4 + q2) ^ (lr & 7)) * 8;
  const unsigned short* Kg = kbuf + ((size_t)bh*SKV + w*8 + r8)*DHH + swz8;
  const unsigned short* Vg = vT + (size_t)bh*DHH*SKV + (size_t)(w*8 + r8)*SKV + swz8;

  bfrag aq0[4], aq1[4];
  float rm[4][4];
  #pragma unroll
  for (int tt = 0; tt < 4; tt++){
    const unsigned short* qbase = qn + ((size_t)bh * SLL + tt*64 + w*16 + lr) * DHH;
    aq0[tt] = *(const bfrag*)&qbase[kq];
    aq1[tt] = *(const bfrag*)&qbase[32 + kq];
    #pragma unroll
    for (int j = 0; j < 4; j++) rm[tt][j] = mask_lat[b*SLL + tt*64 + w*16 + q2*4 + j];
  }
  facc O[4][4];
  #pragma unroll
  for (int tt = 0; tt < 4; tt++)
  #pragma unroll
  for (int nt = 0; nt < 4; nt++) O[tt][nt] = (facc)0.f;
  float lsum[4][4];
  #pragma unroll
  for (int tt = 0; tt < 4; tt++)
  #pragma unroll
  for (int j = 0; j < 4; j++) lsum[tt][j] = 0.f;

  int t0 = (split * 68) / NSPLIT, t1 = ((split + 1) * 68) / NSPLIT;
  {
    int key0 = t0 * 64;
    GLOAD_LDS16(Kg + (size_t)key0*DHH,          &lK[0][(w*8)*64]);
    GLOAD_LDS16(Kg + (size_t)(key0+32)*DHH,     &lK[0][(w*8 + 32)*64]);
    GLOAD_LDS16(Vg + key0,                      &lV[0][(w*8)*64]);
    GLOAD_LDS16(Vg + (size_t)32*SKV + key0,     &lV[0][(w*8 + 32)*64]);
  }
  __asm__ volatile("s_waitcnt vmcnt(0)" ::: "memory");
  __builtin_amdgcn_s_barrier();

  int p = 0;
  for (int kt = t0; kt < t1; kt++){
    int key0 = kt * 64;
    bfrag bk0[4], bk1[4], bv0[4], bv1[4]; float rk[4];
    #pragma unroll
    for (int nt = 0; nt < 4; nt++){
      const unsigned short* kr = &lK[p][(nt*16 + lr)*64];
      const unsigned short* vr = &lV[p][(nt*16 + lr)*64];
      bk0[nt] = *(const bfrag*)&kr[cs0];
      bk1[nt] = *(const bfrag*)&kr[cs1];
      bv0[nt] = *(const bfrag*)&vr[cs0];
      bv1[nt] = *(const bfrag*)&vr[cs1];
      rk[nt]  = rkm[(size_t)bh*SKV + key0 + nt*16 + lr];   // <0 => masked key
    }
    if (kt + 1 < t1){
      int kn = key0 + 64;
      GLOAD_LDS16(Kg + (size_t)kn*DHH,        &lK[p^1][(w*8)*64]);
      GLOAD_LDS16(Kg + (size_t)(kn+32)*DHH,   &lK[p^1][(w*8 + 32)*64]);
      GLOAD_LDS16(Vg + kn,                    &lV[p^1][(w*8)*64]);
      GLOAD_LDS16(Vg + (size_t)32*SKV + kn,   &lV[p^1][(w*8 + 32)*64]);
    }
    #pragma unroll
    for (int tt = 0; tt < 4; tt++){
      facc S[4];
      #pragma unroll
      for (int nt = 0; nt < 4; nt++){
        S[nt] = (facc)0.f;
        S[nt] = __builtin_amdgcn_mfma_f32_16x16x32_bf16(aq0[tt], bk0[nt], S[nt], 0, 0, 0);
        S[nt] = __builtin_amdgcn_mfma_f32_16x16x32_bf16(aq1[tt], bk1[nt], S[nt], 0, 0, 0);
      }
      #pragma unroll
      for (int j = 0; j < 4; j++){
        float rs_ = 0.f;
        #pragma unroll
        for (int nt = 0; nt < 4; nt++){
          float x = S[nt][j] * rk[nt];
          float sv = (rk[nt] >= 0.f && rm[tt][j] != 0.f) ? x : -3.0e38f;
          float pz = __expf(sv - 8.0f);
          rs_ += pz;
          lP[w][tt][q2*4 + j][nt*16 + lr] = f2bf(pz);
        }
        lsum[tt][j] += rs_;   // per-lane partial (16-lane reduce deferred)
      }
    }
    __asm__ volatile("s_waitcnt lgkmcnt(0)" ::: "memory");   // wave-private LDS round trip
    #pragma unroll
    for (int tt = 0; tt < 4; tt++){
      bfrag ap0 = *(const bfrag*)&lP[w][tt][lr][kq];
      bfrag ap1 = *(const bfrag*)&lP[w][tt][lr][32 + kq];
      #pragma unroll
      for (int nt = 0; nt < 4; nt++){
        O[tt][nt] = __builtin_amdgcn_mfma_f32_16x16x32_bf16(ap0, bv0[nt], O[tt][nt], 0, 0, 0);
        O[tt][nt] = __builtin_amdgcn_mfma_f32_16x16x32_bf16(ap1, bv1[nt], O[tt][nt], 0, 0, 0);
      }
    }
    __asm__ volatile("s_waitcnt vmcnt(0)" ::: "memory");
    __builtin_amdgcn_s_barrier();
    p ^= 1;
  }
  #pragma unroll
  for (int tt = 0; tt < 4; tt++)
  #pragma unroll
  for (int j = 0; j < 4; j++){
    float L = lsum[tt][j];
    L += __shfl_xor(L, 1); L += __shfl_xor(L, 2);
    L += __shfl_xor(L, 4); L += __shfl_xor(L, 8);
    int srow = tt*64 + w*16 + q2*4 + j;
    size_t obase = (((size_t)split*64 + bh)*SLL + srow)*DHH;
    #pragma unroll
    for (int nt = 0; nt < 4; nt++)
      Opart[obase + nt*16 + lr] = O[tt][nt][j];
    if (lr == 0)
      lpart[((size_t)split*64 + bh)*SLL + srow] = L;
  }
}

// ---- combine partials across splits (fixed-max: plain sums) -> ybuf bf16 [B][SL][D]
__global__ __launch_bounds__(256) void attn_combine(const float* __restrict__ Opart,
    const float* __restrict__ lpart, unsigned short* __restrict__ ybuf){
  int t = threadIdx.x, w = t >> 6, l = t & 63;
  int idx = blockIdx.x * 4 + w;
  int bh = idx >> 8, srow = idx & 255;
  int b = bh >> 4, h = bh & 15;
  float L = 0.f, acc = 0.f;
  #pragma unroll
  for (int s = 0; s < NSPLIT; s++){
    L   += lpart[((size_t)s*64 + bh)*SLL + srow];
    acc += Opart[(((size_t)s*64 + bh)*SLL + srow)*DHH + l];
  }
  ybuf[((size_t)b*SLL + srow)*DD + h*DHH + l] = f2bf(acc / L);
}

extern "C" void kernel_launch(void* const* d_in, const int* in_sizes, int n_in,
                              void* d_out, int out_size, void* d_ws, size_t ws_size,
                              hipStream_t stream) {
  const float* x        = (const float*)d_in[0];
  const float* latents  = (const float*)d_in[1];
  const float* mask_x   = (const float*)d_in[2];
  const float* mask_lat = (const float*)d_in[3];
  const float* ln_x_g   = (const float*)d_in[4];
  const float* ln_x_b   = (const float*)d_in[5];
  const float* ln_l_g   = (const float*)d_in[6];
  const float* ln_l_b   = (const float*)d_in[7];
  const float* Wq       = (const float*)d_in[8];
  const float* Wkv      = (const float*)d_in[9];
  const float* qk_gamma = (const float*)d_in[10];
  const float* Wo       = (const float*)d_in[11];
  float* out = (float*)d_out;

  // ws layout (~127 MB). Opart/lpart ALIAS kvin/lnlat-slot (dead once attn runs).
  char* wsb = (char*)d_ws;
  unsigned short* kvin  = (unsigned short*)(wsb + 0);          // [MKV][D] bf16       35651584
  unsigned short* wqt   = (unsigned short*)(wsb + 37748736);   // [D][D] bf16          2097152
  unsigned short* wkvt  = (unsigned short*)(wsb + 39845888);   // [2D][D] bf16         4194304
  unsigned short* wot   = (unsigned short*)(wsb + 44040192);   // [D][D] bf16          2097152
  unsigned short* qnb   = (unsigned short*)(wsb + 50331648);   // [B][H][SL][DH]       2097152
  unsigned short* kbuf  = (unsigned short*)(wsb + 52428800);   // [B][H][SKV][DH]     35651584
  unsigned short* vT    = (unsigned short*)(wsb + 88080384);   // [B][H][DH][SKV]     35651584
  float*          rkm   = (float*)(wsb + 123731968);           // [B*H*SKV] f32        1114112
  unsigned short* ybuf  = (unsigned short*)(wsb + 124846080);  // [B*SL][D] bf16       2097152
  float*          Opart = (float*)(wsb + 0);                   // [8][64][256][64] f32 33554432 (alias kvin)
  float*          lpart = (float*)(wsb + 35651584);            // [8][64][256] f32      524288

  prep<<<8448, 256, 0, stream>>>(Wq, Wkv, Wo, wqt, wkvt, wot,
                                 x, latents, ln_x_g, ln_x_b, ln_l_g, ln_l_b, kvin);

  gemm_kv<<<dim3(1120), 512, 0, stream>>>(kvin, wkvt, wqt, qk_gamma,
                                          mask_x, mask_lat, kbuf, vT, rkm, qnb);

  attn<<<dim3(1, NB*HH, NSPLIT), 256, 0, stream>>>(qnb, kbuf, vT, rkm, mask_lat, Opart, lpart);
  attn_combine<<<(NB*HH*SLL)/4, 256, 0, stream>>>(Opart, lpart, ybuf);

  gemm64<<<dim3(DD/64, (NB*SLL)/64), 256, 0, stream>>>(ybuf, wot, NB*SLL, DD, DD, out);
}